// Round 1
// baseline (700.769 us; speedup 1.0000x reference)
//
#include <hip/hip_runtime.h>
#include <math.h>

#define B_ 2
#define H_ 128
#define W_ 128
#define C_ 96
#define L_ (H_*W_)
#define BL_ (B_*L_)
#define NH_ 6
#define NPROJ_ 38
#define MLPH_ 384
#define NCH_ 256
#define CHL_ (L_/NCH_)
#define KVCH_ 64

__device__ __forceinline__ float siluf(float x){ return x / (1.f + __expf(-x)); }

// ---------------- K1: LayerNorm + in_proj (96 -> 288), 8 rows/block ----------------
__global__ __launch_bounds__(288) void k_ln_inproj(const float* __restrict__ hs,
    const float* __restrict__ gg, const float* __restrict__ bb,
    const float* __restrict__ wmat, float* __restrict__ xzw)
{
    __shared__ float ln[8][C_];
    __shared__ float mstat[8], rstat[8];
    int t = threadIdx.x;
    size_t row0 = (size_t)blockIdx.x * 8;
    for (int i = t; i < 8*C_; i += 288) ln[i/C_][i%C_] = hs[row0*C_ + i];
    __syncthreads();
    if (t < 8){
        float s=0.f, s2=0.f;
        for (int kk=0; kk<C_; kk++){ float v=ln[t][kk]; s+=v; s2+=v*v; }
        float m = s*(1.f/C_);
        mstat[t]=m; rstat[t]=rsqrtf(s2*(1.f/C_)-m*m+1e-5f);
    }
    __syncthreads();
    for (int i=t;i<8*C_;i+=288){
        int r=i/C_, c=i%C_;
        ln[r][c] = (ln[r][c]-mstat[r])*rstat[r]*gg[c]+bb[c];
    }
    __syncthreads();
    float acc[8];
    #pragma unroll
    for (int r=0;r<8;r++) acc[r]=0.f;
    for (int kk=0;kk<C_;kk++){
        float wv = wmat[kk*288 + t];
        #pragma unroll
        for (int r=0;r<8;r++) acc[r] += ln[r][kk]*wv;
    }
    #pragma unroll
    for (int r=0;r<8;r++) xzw[(row0+r)*288 + t] = acc[r];
}

// ---------------- K2: depthwise 3x3 conv + silu on w_ (cols 192..287) ----------------
__global__ __launch_bounds__(384) void k_dwconv2d(const float* __restrict__ xzw,
    const float* __restrict__ dww, const float* __restrict__ dwb,
    float* __restrict__ out)
{
    int t = threadIdx.x;
    int r = t / C_, c = t % C_;
    size_t row = (size_t)blockIdx.x*4 + r;
    int b = (int)(row / L_);
    int l = (int)(row % L_);
    int h = l >> 7, wq = l & 127;
    float acc = 0.f;
    #pragma unroll
    for (int kh=0; kh<3; kh++){
        int hh = h + kh - 1;
        if ((unsigned)hh < 128u){
            #pragma unroll
            for (int kw=0; kw<3; kw++){
                int ww = wq + kw - 1;
                if ((unsigned)ww < 128u)
                    acc += xzw[((size_t)b*L_ + (hh<<7) + ww)*288 + 192 + c] * dww[c*9 + kh*3 + kw];
            }
        }
    }
    acc += dwb[c];
    out[row*C_ + c] = siluf(acc);
}

// ---------------- K3: 1d conv (pad 1,2, taps 4) + silu on x and z ----------------
__global__ __launch_bounds__(384) void k_conv1d(const float* __restrict__ xzw,
    const float* __restrict__ wx, const float* __restrict__ wz,
    float* __restrict__ xs, float* __restrict__ zs)
{
    int t=threadIdx.x; int r=t/C_, c=t%C_;
    size_t row = (size_t)blockIdx.x*4 + r;
    int b = (int)(row / L_); int l = (int)(row % L_);
    float ax=0.f, az=0.f;
    #pragma unroll
    for (int j=0;j<4;j++){
        int ll = l - 1 + j;
        if ((unsigned)ll < (unsigned)L_){
            const float* p = &xzw[((size_t)b*L_ + ll)*288];
            ax += p[c]    * wx[c*4+j];
            az += p[96+c] * wz[c*4+j];
        }
    }
    xs[row*C_+c]=siluf(ax);
    zs[row*C_+c]=siluf(az);
}

// ---------------- K4: qk projection (96 -> 192) + elu+1, 8 rows/block ----------------
__global__ __launch_bounds__(192) void k_qk(const float* __restrict__ lin,
    const float* __restrict__ qkw, const float* __restrict__ qkb,
    float* __restrict__ qo, float* __restrict__ ko)
{
    __shared__ float in[8][C_];
    int t=threadIdx.x;
    size_t row0 = (size_t)blockIdx.x*8;
    for (int i=t;i<8*C_;i+=192) in[i/C_][i%C_] = lin[row0*C_ + i];
    __syncthreads();
    float acc[8];
    #pragma unroll
    for(int r=0;r<8;r++) acc[r]=qkb[t];
    for(int kk=0;kk<C_;kk++){
        float wv=qkw[kk*192+t];
        #pragma unroll
        for(int r=0;r<8;r++) acc[r]+=in[r][kk]*wv;
    }
    float* dst = (t<96)? qo : ko;
    int c = (t<96)? t : t-96;
    #pragma unroll
    for(int r=0;r<8;r++){
        float v=acc[r];
        v = (v>0.f)? v+1.f : __expf(v);
        dst[(row0+r)*C_+c]=v;
    }
}

// ---------------- K5: per-(b,head) partial reduction: kv (16x16, roped k) and kmean ----------------
__global__ __launch_bounds__(256) void k_kvred(const float* __restrict__ kbuf,
    const float* __restrict__ vbuf, float* __restrict__ part)
{
    __shared__ float th[24];
    __shared__ float kr[8][16], ku[8][16], vv[8][16];
    int t=threadIdx.x;
    int chunk=blockIdx.x; int bh=blockIdx.y; int b=bh/NH_, head=bh%NH_;
    if (t<24) th[t]=powf(10000.f, -(float)t/24.f);
    __syncthreads();
    int d=t>>4, e=t&15;
    float akv=0.f, akm=0.f;
    for(int g0=0; g0<32; g0++){
        int base = chunk*256 + g0*8;
        if (t<64){
            int pr=t&7, r=t>>3;
            int n=base+r;
            size_t off=((size_t)b*L_+n)*C_ + head*16 + 2*pr;
            float k0=kbuf[off], k1=kbuf[off+1];
            float v0=vbuf[off], v1=vbuf[off+1];
            int gp=head*8+pr;
            int hpos=n>>7, wpos=n&127;
            float ang = (gp<24)? hpos*th[gp] : wpos*th[gp-24];
            float sn, cs; sincosf(ang,&sn,&cs);
            kr[r][2*pr]=k0*cs-k1*sn; kr[r][2*pr+1]=k0*sn+k1*cs;
            ku[r][2*pr]=k0; ku[r][2*pr+1]=k1;
            vv[r][2*pr]=v0; vv[r][2*pr+1]=v1;
        }
        __syncthreads();
        #pragma unroll
        for(int r=0;r<8;r++) akv += kr[r][d]*vv[r][e];
        if (e==0){
            #pragma unroll
            for(int r=0;r<8;r++) akm += ku[r][d];
        }
        __syncthreads();
    }
    float* p = &part[((size_t)bh*KVCH_+chunk)*272];
    p[t]=akv;
    if(e==0) p[256+d]=akm;
}

// ---------------- K6: finalize kv / kmean ----------------
__global__ __launch_bounds__(272) void k_kvfin(const float* __restrict__ part,
    float* __restrict__ kvf, float* __restrict__ kmf)
{
    int bh=blockIdx.x, t=threadIdx.x;
    float acc=0.f;
    for(int ch=0;ch<KVCH_;ch++) acc += part[((size_t)bh*KVCH_+ch)*272 + t];
    if (t<256) kvf[bh*256+t] = acc*(1.f/16384.f);   // scale^2 = 1/L
    else       kmf[bh*16 + (t-256)] = acc*(1.f/16384.f); // mean over L
}

// ---------------- K7: attention output (rope(q) @ kv * zden) + lepe conv ----------------
__global__ __launch_bounds__(384) void k_attnout(const float* __restrict__ qbuf,
    const float* __restrict__ vbuf, const float* __restrict__ kvf,
    const float* __restrict__ kmf, const float* __restrict__ lw,
    const float* __restrict__ lb, float* __restrict__ aout)
{
    __shared__ float th[24];
    __shared__ float qraw[4][C_], qr[4][C_];
    int t=threadIdx.x; int r=t/C_, c=t%C_;
    size_t row0=(size_t)blockIdx.x*4;
    if(t<24) th[t]=powf(10000.f,-(float)t/24.f);
    for(int i=t;i<4*C_;i+=384) qraw[i/C_][i%C_]=qbuf[row0*C_+i];
    __syncthreads();
    size_t row=row0+r;
    int b=(int)(row/L_); int l=(int)(row%L_);
    int hpos=l>>7, wpos=l&127;
    {
        int p=c>>1;
        float ang=(p<24)? hpos*th[p] : wpos*th[p-24];
        float sn,cs; sincosf(ang,&sn,&cs);
        float x0=qraw[r][p*2], x1=qraw[r][p*2+1];
        qr[r][c] = (c&1)? (x0*sn+x1*cs) : (x0*cs-x1*sn);
    }
    __syncthreads();
    int head=c>>4, el=c&15;
    const float* km=&kmf[(b*NH_+head)*16];
    const float* kvp=&kvf[((size_t)(b*NH_+head))*256];
    float zd=1e-6f;
    #pragma unroll
    for(int d2=0;d2<16;d2++) zd += qraw[r][head*16+d2]*km[d2];
    zd = 1.f/zd;
    float o=0.f;
    #pragma unroll
    for(int d2=0;d2<16;d2++) o += qr[r][head*16+d2]*kvp[d2*16+el];
    o*=zd;
    float acc=lb[c];
    #pragma unroll
    for(int kh=0;kh<3;kh++){
        int hh=hpos+kh-1;
        if((unsigned)hh<128u){
            #pragma unroll
            for(int kw=0;kw<3;kw++){
                int ww=wpos+kw-1;
                if((unsigned)ww<128u)
                    acc += vbuf[((size_t)b*L_+(hh<<7)+ww)*C_+c]*lw[c*9+kh*3+kw];
            }
        }
    }
    aout[row*C_+c]=o+acc;
}

// ---------------- K8: x_proj (96->38) + dt_proj (6->96) + softplus ----------------
__global__ __launch_bounds__(384) void k_xdbl(const float* __restrict__ xs,
    const float* __restrict__ xpw, const float* __restrict__ dtw,
    const float* __restrict__ dtb, float* __restrict__ delta, float* __restrict__ BC)
{
    __shared__ float in[4][C_];
    __shared__ float xd[4][NPROJ_];
    int t=threadIdx.x;
    size_t row0=(size_t)blockIdx.x*4;
    for(int i=t;i<4*C_;i+=384) in[i/C_][i%C_]=xs[row0*C_+i];
    __syncthreads();
    if(t<4*NPROJ_){
        int r=t/NPROJ_, e=t%NPROJ_;
        float a=0.f;
        for(int kk=0;kk<C_;kk++) a+=in[r][kk]*xpw[kk*NPROJ_+e];
        xd[r][e]=a;
    }
    __syncthreads();
    {
        int r=t/C_, c=t%C_;
        float a=dtb[c];
        #pragma unroll
        for(int j=0;j<6;j++) a+=xd[r][j]*dtw[j*C_+c];
        float dl = (a>20.f)? a : log1pf(__expf(a));
        delta[(row0+r)*C_+c]=dl;
    }
    if(t<4*32){
        int r=t/32, j=t%32;
        BC[(row0+r)*32+j]=xd[r][6+j];
    }
}

// ---------------- K9a: scan pass1 — per-chunk (prod dA, local end-state) ----------------
__global__ __launch_bounds__(96) void k_scan1(const float* __restrict__ delta,
    const float* __restrict__ xs, const float* __restrict__ BC,
    const float* __restrict__ A_log, float* __restrict__ Ap, float* __restrict__ Be)
{
    int c=threadIdx.x;
    int blk=blockIdx.x; int b=blk/NCH_; int ch=blk%NCH_;
    float a[16];
    #pragma unroll
    for(int n=0;n<16;n++) a[n]=-__expf(A_log[c*16+n]);
    float ap[16], be[16];
    #pragma unroll
    for(int n=0;n<16;n++){ap[n]=1.f; be[n]=0.f;}
    int l0=ch*CHL_;
    for(int i=0;i<CHL_;i++){
        size_t row=(size_t)b*L_+l0+i;
        float dl=delta[row*C_+c];
        float u=xs[row*C_+c];
        float du=dl*u;
        const float* bcp=&BC[row*32];
        #pragma unroll
        for(int n=0;n<16;n++){
            float dA=__expf(dl*a[n]);
            ap[n]*=dA;
            be[n]=be[n]*dA + du*bcp[n];
        }
    }
    float* app=&Ap[((size_t)blk*C_+c)*16];
    float* bep=&Be[((size_t)blk*C_+c)*16];
    #pragma unroll
    for(int n=0;n<16;n++){app[n]=ap[n]; bep[n]=be[n];}
}

// ---------------- K9b: scan pass2 — sequential combine across chunks ----------------
__global__ __launch_bounds__(256) void k_scan2(const float* __restrict__ Ap,
    const float* __restrict__ Be, float* __restrict__ Hin)
{
    int t=blockIdx.x*256+threadIdx.x;  // 3072 = B*C*16
    int b=t/1536; int rem=t%1536;
    float h=0.f;
    for(int ch=0;ch<NCH_;ch++){
        size_t idx=((size_t)(b*NCH_+ch)*1536)+rem;
        Hin[idx]=h;
        h = Ap[idx]*h + Be[idx];
    }
}

// ---------------- K9c: scan pass3 — replay with incoming state, emit y ----------------
__global__ __launch_bounds__(96) void k_scan3(const float* __restrict__ delta,
    const float* __restrict__ xs, const float* __restrict__ BC,
    const float* __restrict__ A_log, const float* __restrict__ Dv,
    const float* __restrict__ Hin, float* __restrict__ y)
{
    int c=threadIdx.x;
    int blk=blockIdx.x; int b=blk/NCH_; int ch=blk%NCH_;
    float a[16];
    #pragma unroll
    for(int n=0;n<16;n++) a[n]=-__expf(A_log[c*16+n]);
    float h[16];
    const float* hp=&Hin[((size_t)blk*C_+c)*16];
    #pragma unroll
    for(int n=0;n<16;n++) h[n]=hp[n];
    float Dc=Dv[c];
    int l0=ch*CHL_;
    for(int i=0;i<CHL_;i++){
        size_t row=(size_t)b*L_+l0+i;
        float dl=delta[row*C_+c];
        float u=xs[row*C_+c];
        float du=dl*u;
        const float* bcp=&BC[row*32];
        float yv=0.f;
        #pragma unroll
        for(int n=0;n<16;n++){
            float dA=__expf(dl*a[n]);
            h[n]=h[n]*dA + du*bcp[n];
            yv += h[n]*bcp[16+n];
        }
        y[row*C_+c]=yv + Dc*u;
    }
}

// ---------------- K10: out1/out2/out_w + shortcut, 8 rows/block ----------------
__global__ __launch_bounds__(192) void k_combine(const float* __restrict__ y,
    const float* __restrict__ zs, const float* __restrict__ aout,
    const float* __restrict__ opw, const float* __restrict__ pow_,
    const float* __restrict__ pob, const float* __restrict__ outw,
    const float* __restrict__ outb, const float* __restrict__ shortcut,
    float* __restrict__ outr)
{
    __shared__ float ycat[8][192];
    __shared__ float azs[8][C_];
    __shared__ float cat2[8][192];
    int t=threadIdx.x;
    size_t row0=(size_t)blockIdx.x*8;
    for(int i=t;i<8*C_;i+=192){
        int r=i/C_, c=i%C_;
        float zv=zs[(row0+r)*C_+c];
        ycat[r][c]=y[(row0+r)*C_+c];
        ycat[r][96+c]=zv;
        azs[r][c]=aout[(row0+r)*C_+c]*zv;
    }
    __syncthreads();
    if(t<96){
        float acc[8];
        #pragma unroll
        for(int r=0;r<8;r++) acc[r]=0.f;
        for(int kk=0;kk<192;kk++){
            float wv=opw[kk*96+t];
            #pragma unroll
            for(int r=0;r<8;r++) acc[r]+=ycat[r][kk]*wv;
        }
        #pragma unroll
        for(int r=0;r<8;r++) cat2[r][t]=acc[r];
    } else {
        int j=t-96;
        float acc[8];
        #pragma unroll
        for(int r=0;r<8;r++) acc[r]=pob[j];
        for(int kk=0;kk<96;kk++){
            float wv=pow_[kk*96+j];
            #pragma unroll
            for(int r=0;r<8;r++) acc[r]+=azs[r][kk]*wv;
        }
        #pragma unroll
        for(int r=0;r<8;r++) cat2[r][96+j]=acc[r];
    }
    __syncthreads();
    if(t<96){
        float acc[8];
        #pragma unroll
        for(int r=0;r<8;r++) acc[r]=outb[t];
        for(int kk=0;kk<192;kk++){
            float wv=outw[kk*96+t];
            #pragma unroll
            for(int r=0;r<8;r++) acc[r]+=cat2[r][kk]*wv;
        }
        #pragma unroll
        for(int r=0;r<8;r++)
            outr[(row0+r)*C_+t]=acc[r]+shortcut[(row0+r)*C_+t];
    }
}

// ---------------- K11: LN + fc1 + gelu + fc2 + residual (in place on outr) ----------------
__global__ __launch_bounds__(384) void k_mlp(float* __restrict__ outr,
    const float* __restrict__ gg, const float* __restrict__ bb,
    const float* __restrict__ f1w, const float* __restrict__ f1b,
    const float* __restrict__ f2w, const float* __restrict__ f2b)
{
    __shared__ float raw[8][C_];
    __shared__ float ln[8][C_];
    __shared__ float hid[8][MLPH_];
    __shared__ float part[4][8][C_];
    __shared__ float mstat[8], rstat[8];
    int t=threadIdx.x;
    size_t row0=(size_t)blockIdx.x*8;
    for(int i=t;i<8*C_;i+=384) raw[i/C_][i%C_]=outr[row0*C_+i];
    __syncthreads();
    if(t<8){
        float s=0.f,s2=0.f;
        for(int kk=0;kk<C_;kk++){float v=raw[t][kk]; s+=v; s2+=v*v;}
        float m=s*(1.f/C_);
        mstat[t]=m; rstat[t]=rsqrtf(s2*(1.f/C_)-m*m+1e-5f);
    }
    __syncthreads();
    for(int i=t;i<8*C_;i+=384){
        int r=i/C_,c=i%C_;
        ln[r][c]=(raw[r][c]-mstat[r])*rstat[r]*gg[c]+bb[c];
    }
    __syncthreads();
    {
        float acc[8];
        #pragma unroll
        for(int r=0;r<8;r++) acc[r]=f1b[t];
        for(int kk=0;kk<C_;kk++){
            float wv=f1w[kk*MLPH_+t];
            #pragma unroll
            for(int r=0;r<8;r++) acc[r]+=ln[r][kk]*wv;
        }
        #pragma unroll
        for(int r=0;r<8;r++){
            float x=acc[r];
            hid[r][t]=0.5f*x*(1.f+erff(x*0.70710678f));
        }
    }
    __syncthreads();
    {
        int jj=t%C_, qq=t/C_;
        float acc[8];
        #pragma unroll
        for(int r=0;r<8;r++) acc[r]=0.f;
        for(int kk=qq*96;kk<qq*96+96;kk++){
            float wv=f2w[kk*C_+jj];
            #pragma unroll
            for(int r=0;r<8;r++) acc[r]+=hid[r][kk]*wv;
        }
        #pragma unroll
        for(int r=0;r<8;r++) part[qq][r][jj]=acc[r];
    }
    __syncthreads();
    for(int i=t;i<8*C_;i+=384){
        int r=i/C_,c=i%C_;
        float v=raw[r][c]+f2b[c]+part[0][r][c]+part[1][r][c]+part[2][r][c]+part[3][r][c];
        outr[(row0+r)*C_+c]=v;
    }
}

extern "C" void kernel_launch(void* const* d_in, const int* in_sizes, int n_in,
                              void* d_out, int out_size, void* d_ws, size_t ws_size,
                              hipStream_t stream)
{
    const float* hs        = (const float*)d_in[0];
    const float* norm_in_g = (const float*)d_in[1];
    const float* norm_in_b = (const float*)d_in[2];
    const float* in_proj_w = (const float*)d_in[3];
    const float* dw_w      = (const float*)d_in[4];
    const float* dw_b      = (const float*)d_in[5];
    const float* qk_w      = (const float*)d_in[6];
    const float* qk_b      = (const float*)d_in[7];
    const float* lepe_w    = (const float*)d_in[8];
    const float* lepe_b    = (const float*)d_in[9];
    const float* conv_x_w  = (const float*)d_in[10];
    const float* conv_z_w  = (const float*)d_in[11];
    const float* x_proj_w  = (const float*)d_in[12];
    const float* dt_proj_w = (const float*)d_in[13];
    const float* dt_proj_b = (const float*)d_in[14];
    const float* A_log     = (const float*)d_in[15];
    const float* Dv        = (const float*)d_in[16];
    const float* out_proj_w= (const float*)d_in[17];
    const float* proj_out_w= (const float*)d_in[18];
    const float* proj_out_b= (const float*)d_in[19];
    const float* out_w     = (const float*)d_in[20];
    const float* out_b     = (const float*)d_in[21];
    const float* norm_mlp_g= (const float*)d_in[22];
    const float* norm_mlp_b= (const float*)d_in[23];
    const float* fc1_w     = (const float*)d_in[24];
    const float* fc1_b     = (const float*)d_in[25];
    const float* fc2_w     = (const float*)d_in[26];
    const float* fc2_b     = (const float*)d_in[27];

    float* ws = (float*)d_ws;
    size_t o = 0;
    float* xzw   = ws + o; o += (size_t)BL_*288;   // 9,437,184 — reused for q/k/delta later
    float* lin_x = ws + o; o += (size_t)BL_*C_;
    float* aout  = ws + o; o += (size_t)BL_*C_;
    float* xs    = ws + o; o += (size_t)BL_*C_;
    float* zs    = ws + o; o += (size_t)BL_*C_;
    float* ybuf  = ws + o; o += (size_t)BL_*C_;
    float* BC    = ws + o; o += (size_t)BL_*32;
    float* kvpart= ws + o; o += (size_t)B_*NH_*KVCH_*272;
    float* kvf   = ws + o; o += (size_t)B_*NH_*256;
    float* kmf   = ws + o; o += (size_t)B_*NH_*16;
    float* Ap    = ws + o; o += (size_t)B_*NCH_*C_*16;
    float* Be    = ws + o; o += (size_t)B_*NCH_*C_*16;
    float* Hin   = ws + o; o += (size_t)B_*NCH_*C_*16;

    // aliases into the dead xzw region (xzw fully consumed after k_conv1d)
    float* qbuf  = xzw;
    float* kbuf  = xzw + (size_t)BL_*C_;
    float* delta = xzw + (size_t)2*BL_*C_;

    float* outr = (float*)d_out;

    k_ln_inproj<<<BL_/8, 288, 0, stream>>>(hs, norm_in_g, norm_in_b, in_proj_w, xzw);
    k_dwconv2d<<<BL_/4, 384, 0, stream>>>(xzw, dw_w, dw_b, lin_x);
    k_conv1d<<<BL_/4, 384, 0, stream>>>(xzw, conv_x_w, conv_z_w, xs, zs);
    k_qk<<<BL_/8, 192, 0, stream>>>(lin_x, qk_w, qk_b, qbuf, kbuf);
    k_kvred<<<dim3(KVCH_, B_*NH_), 256, 0, stream>>>(kbuf, lin_x, kvpart);
    k_kvfin<<<B_*NH_, 272, 0, stream>>>(kvpart, kvf, kmf);
    k_attnout<<<BL_/4, 384, 0, stream>>>(qbuf, lin_x, kvf, kmf, lepe_w, lepe_b, aout);
    k_xdbl<<<BL_/4, 384, 0, stream>>>(xs, x_proj_w, dt_proj_w, dt_proj_b, delta, BC);
    k_scan1<<<B_*NCH_, 96, 0, stream>>>(delta, xs, BC, A_log, Ap, Be);
    k_scan2<<<(B_*C_*16)/256, 256, 0, stream>>>(Ap, Be, Hin);
    k_scan3<<<B_*NCH_, 96, 0, stream>>>(delta, xs, BC, A_log, Dv, Hin, ybuf);
    k_combine<<<BL_/8, 192, 0, stream>>>(ybuf, zs, aout, out_proj_w, proj_out_w,
                                         proj_out_b, out_w, out_b, hs, outr);
    k_mlp<<<BL_/8, 384, 0, stream>>>(outr, norm_mlp_g, norm_mlp_b,
                                     fc1_w, fc1_b, fc2_w, fc2_b);
}

// Round 2
// 376.091 us; speedup vs baseline: 1.8633x; 1.8633x over previous
//
#include <hip/hip_runtime.h>
#include <hip/hip_bf16.h>
#include <math.h>

#define B_ 2
#define H_ 128
#define W_ 128
#define C_ 96
#define L_ (H_*W_)
#define BL_ (B_*L_)
#define NH_ 6
#define NPROJ_ 38
#define MLPH_ 384
#define NCH_ 256
#define CHL_ (L_/NCH_)
#define KVCH_ 64

typedef __attribute__((ext_vector_type(8))) short bf16x8;
typedef __attribute__((ext_vector_type(4))) float f32x4;

#define MFMA16(a,b,c) __builtin_amdgcn_mfma_f32_16x16x32_bf16(a,b,c,0,0,0)

// weight fragment table (each frag = 64 lanes * 8 bf16 = 512 elems)
#define WOFF1 0      // in_proj  96x288 : 3*18 = 54
#define WOFF2 54     // qk_w     96x192 : 3*12 = 36
#define WOFF3 90     // out_proj 192x96 : 6*6  = 36
#define WOFF4 126    // proj_out 96x96  : 3*6  = 18
#define WOFF5 144    // out_w    192x96 : 6*6  = 36
#define WOFF6 180    // fc1      96x384 : 3*24 = 72
#define WOFF7 252    // fc2      384x96 : 12*6 = 72
#define WFRAGS 324

__device__ __forceinline__ float siluf(float x){ return x / (1.f + __expf(-x)); }
__device__ __forceinline__ unsigned short f2bf(float x){
    __hip_bfloat16 h = __float2bfloat16(x);
    return *reinterpret_cast<unsigned short*>(&h);
}
__device__ __forceinline__ unsigned pack2(float a, float b){
    return (unsigned)f2bf(a) | ((unsigned)f2bf(b) << 16);
}

// ---------------- K0: weight fp32->bf16 conversion into frag-linear layout ----------------
__global__ __launch_bounds__(64) void k_wprep(const float* __restrict__ w1,
    const float* __restrict__ w2, const float* __restrict__ w3,
    const float* __restrict__ w4, const float* __restrict__ w5,
    const float* __restrict__ w6, const float* __restrict__ w7,
    unsigned short* __restrict__ dst)
{
    const float* srcs[7] = {w1,w2,w3,w4,w5,w6,w7};
    const int Ks[7]   = {96,96,192,96,192,96,384};
    const int Ns[7]   = {288,192,96,96,96,384,96};
    const int offs[7] = {WOFF1,WOFF2,WOFF3,WOFF4,WOFF5,WOFF6,WOFF7};
    int m = blockIdx.y, f = blockIdx.x;
    int nnt = Ns[m] >> 4, nkf = Ks[m] >> 5;
    if (f >= nnt*nkf) return;
    int kf = f / nnt, nt = f - kf*nnt;
    int l = threadIdx.x;
    const float* s = srcs[m];
    unsigned short* d = dst + ((size_t)(offs[m] + f)*64 + l)*8;
    int krow = kf*32 + (l>>4)*8;
    int col  = nt*16 + (l&15);
    #pragma unroll
    for (int j=0;j<8;j++) d[j] = f2bf(s[(size_t)(krow+j)*Ns[m] + col]);
}

// ---------------- K1: LayerNorm + in_proj (96 -> 288) MFMA, 64 rows/block ----------------
__global__ __launch_bounds__(256) void k_ln_inproj_m(const float* __restrict__ hs,
    const float* __restrict__ gg, const float* __restrict__ bb,
    const unsigned short* __restrict__ wbf, float* __restrict__ xzw)
{
    __shared__ unsigned short A[64*128];
    int t = threadIdx.x;
    size_t row0 = (size_t)blockIdx.x * 64;
    {
        int r = t >> 2, q = t & 3;
        const float* src = hs + (row0 + r)*C_ + q*24;
        float v[24];
        float s=0.f, s2=0.f;
        #pragma unroll
        for (int i=0;i<24;i++){ float x=src[i]; v[i]=x; s+=x; s2+=x*x; }
        s += __shfl_xor(s,1); s2 += __shfl_xor(s2,1);
        s += __shfl_xor(s,2); s2 += __shfl_xor(s2,2);
        float mn = s*(1.f/C_);
        float rs = rsqrtf(s2*(1.f/C_) - mn*mn + 1e-5f);
        int base = r*128, sw = (r&7)<<3;
        #pragma unroll
        for (int i=0;i<24;i+=2){
            int c = q*24 + i;
            float a0 = (v[i]  -mn)*rs*gg[c]   + bb[c];
            float a1 = (v[i+1]-mn)*rs*gg[c+1] + bb[c+1];
            *(unsigned*)&A[base + (c ^ sw)] = pack2(a0,a1);
        }
    }
    __syncthreads();
    int w = t>>6, l = t&63, lr = l&15, lh = l>>4;
    int arow = w*16 + lr;
    int abase = arow*128, asw = (arow&7)<<3;
    bf16x8 af[3];
    #pragma unroll
    for (int kf=0;kf<3;kf++)
        af[kf] = *(const bf16x8*)&A[abase + ((kf*32 + lh*8) ^ asw)];
    #pragma unroll 2
    for (int nt=0; nt<18; nt++){
        f32x4 acc = {0.f,0.f,0.f,0.f};
        #pragma unroll
        for (int kf=0;kf<3;kf++){
            bf16x8 bf_ = *(const bf16x8*)(wbf + ((size_t)((WOFF1 + kf*18 + nt)*64 + l))*8);
            acc = MFMA16(af[kf], bf_, acc);
        }
        float* dst = xzw + (row0 + w*16 + lh*4)*288 + nt*16 + lr;
        #pragma unroll
        for (int j=0;j<4;j++) dst[(size_t)j*288] = acc[j];
    }
}

// ---------------- K2: depthwise 3x3 conv + silu on w_ (cols 192..287) ----------------
__global__ __launch_bounds__(384) void k_dwconv2d(const float* __restrict__ xzw,
    const float* __restrict__ dww, const float* __restrict__ dwb,
    float* __restrict__ out)
{
    int t = threadIdx.x;
    int r = t / C_, c = t % C_;
    size_t row = (size_t)blockIdx.x*4 + r;
    int b = (int)(row / L_);
    int l = (int)(row % L_);
    int h = l >> 7, wq = l & 127;
    float acc = 0.f;
    #pragma unroll
    for (int kh=0; kh<3; kh++){
        int hh = h + kh - 1;
        if ((unsigned)hh < 128u){
            #pragma unroll
            for (int kw=0; kw<3; kw++){
                int ww = wq + kw - 1;
                if ((unsigned)ww < 128u)
                    acc += xzw[((size_t)b*L_ + (hh<<7) + ww)*288 + 192 + c] * dww[c*9 + kh*3 + kw];
            }
        }
    }
    acc += dwb[c];
    out[row*C_ + c] = siluf(acc);
}

// ---------------- K3: 1d conv (pad 1,2, taps 4) + silu on x and z ----------------
__global__ __launch_bounds__(384) void k_conv1d(const float* __restrict__ xzw,
    const float* __restrict__ wx, const float* __restrict__ wz,
    float* __restrict__ xs, float* __restrict__ zs)
{
    int t=threadIdx.x; int r=t/C_, c=t%C_;
    size_t row = (size_t)blockIdx.x*4 + r;
    int b = (int)(row / L_); int l = (int)(row % L_);
    float ax=0.f, az=0.f;
    #pragma unroll
    for (int j=0;j<4;j++){
        int ll = l - 1 + j;
        if ((unsigned)ll < (unsigned)L_){
            const float* p = &xzw[((size_t)b*L_ + ll)*288];
            ax += p[c]    * wx[c*4+j];
            az += p[96+c] * wz[c*4+j];
        }
    }
    xs[row*C_+c]=siluf(ax);
    zs[row*C_+c]=siluf(az);
}

// ---------------- K4: qk projection (96 -> 192) MFMA + elu+1 ----------------
__global__ __launch_bounds__(256) void k_qk_m(const float* __restrict__ lin,
    const unsigned short* __restrict__ wbf, const float* __restrict__ qkb,
    float* __restrict__ qo, float* __restrict__ ko)
{
    __shared__ unsigned short A[64*128];
    int t = threadIdx.x;
    size_t row0 = (size_t)blockIdx.x * 64;
    for (int p = t; p < 64*48; p += 256){
        int r = p/48, c = (p - r*48)*2;
        float2 xy = *(const float2*)&lin[(row0 + r)*C_ + c];
        *(unsigned*)&A[r*128 + (c ^ ((r&7)<<3))] = pack2(xy.x, xy.y);
    }
    __syncthreads();
    int w=t>>6, l=t&63, lr=l&15, lh=l>>4;
    int arow = w*16+lr; int asw=(arow&7)<<3;
    bf16x8 af[3];
    #pragma unroll
    for (int kf=0;kf<3;kf++)
        af[kf] = *(const bf16x8*)&A[arow*128 + ((kf*32 + lh*8) ^ asw)];
    #pragma unroll 2
    for (int nt=0; nt<12; nt++){
        f32x4 acc={0.f,0.f,0.f,0.f};
        #pragma unroll
        for (int kf=0;kf<3;kf++){
            bf16x8 b=*(const bf16x8*)(wbf + ((size_t)((WOFF2 + kf*12 + nt)*64 + l))*8);
            acc = MFMA16(af[kf], b, acc);
        }
        int col = nt*16 + lr;
        float bias = qkb[col];
        float* dst = (col<96)? qo : ko;
        int cc = (col<96)? col : col-96;
        float* dp = dst + (row0 + w*16 + lh*4)*C_ + cc;
        #pragma unroll
        for (int j=0;j<4;j++){
            float vv = acc[j] + bias;
            vv = (vv>0.f)? vv+1.f : __expf(vv);
            dp[(size_t)j*C_] = vv;
        }
    }
}

// ---------------- K5: per-(b,head) partial reduction: kv (16x16, roped k) and kmean ----------------
__global__ __launch_bounds__(256) void k_kvred(const float* __restrict__ kbuf,
    const float* __restrict__ vbuf, float* __restrict__ part)
{
    __shared__ float th[24];
    __shared__ float kr[8][16], ku[8][16], vv[8][16];
    int t=threadIdx.x;
    int chunk=blockIdx.x; int bh=blockIdx.y; int b=bh/NH_, head=bh%NH_;
    if (t<24) th[t]=powf(10000.f, -(float)t/24.f);
    __syncthreads();
    int d=t>>4, e=t&15;
    float akv=0.f, akm=0.f;
    for(int g0=0; g0<32; g0++){
        int base = chunk*256 + g0*8;
        if (t<64){
            int pr=t&7, r=t>>3;
            int n=base+r;
            size_t off=((size_t)b*L_+n)*C_ + head*16 + 2*pr;
            float k0=kbuf[off], k1=kbuf[off+1];
            float v0=vbuf[off], v1=vbuf[off+1];
            int gp=head*8+pr;
            int hpos=n>>7, wpos=n&127;
            float ang = (gp<24)? hpos*th[gp] : wpos*th[gp-24];
            float sn, cs; sincosf(ang,&sn,&cs);
            kr[r][2*pr]=k0*cs-k1*sn; kr[r][2*pr+1]=k0*sn+k1*cs;
            ku[r][2*pr]=k0; ku[r][2*pr+1]=k1;
            vv[r][2*pr]=v0; vv[r][2*pr+1]=v1;
        }
        __syncthreads();
        #pragma unroll
        for(int r=0;r<8;r++) akv += kr[r][d]*vv[r][e];
        if (e==0){
            #pragma unroll
            for(int r=0;r<8;r++) akm += ku[r][d];
        }
        __syncthreads();
    }
    float* p = &part[((size_t)bh*KVCH_+chunk)*272];
    p[t]=akv;
    if(e==0) p[256+d]=akm;
}

// ---------------- K6: finalize kv / kmean ----------------
__global__ __launch_bounds__(272) void k_kvfin(const float* __restrict__ part,
    float* __restrict__ kvf, float* __restrict__ kmf)
{
    int bh=blockIdx.x, t=threadIdx.x;
    float acc=0.f;
    for(int ch=0;ch<KVCH_;ch++) acc += part[((size_t)bh*KVCH_+ch)*272 + t];
    if (t<256) kvf[bh*256+t] = acc*(1.f/16384.f);
    else       kmf[bh*16 + (t-256)] = acc*(1.f/16384.f);
}

// ---------------- K7: attention output (rope(q) @ kv * zden) + lepe conv ----------------
__global__ __launch_bounds__(384) void k_attnout(const float* __restrict__ qbuf,
    const float* __restrict__ vbuf, const float* __restrict__ kvf,
    const float* __restrict__ kmf, const float* __restrict__ lw,
    const float* __restrict__ lb, float* __restrict__ aout)
{
    __shared__ float th[24];
    __shared__ float qraw[4][C_], qr[4][C_];
    int t=threadIdx.x; int r=t/C_, c=t%C_;
    size_t row0=(size_t)blockIdx.x*4;
    if(t<24) th[t]=powf(10000.f,-(float)t/24.f);
    for(int i=t;i<4*C_;i+=384) qraw[i/C_][i%C_]=qbuf[row0*C_+i];
    __syncthreads();
    size_t row=row0+r;
    int b=(int)(row/L_); int l=(int)(row%L_);
    int hpos=l>>7, wpos=l&127;
    {
        int p=c>>1;
        float ang=(p<24)? hpos*th[p] : wpos*th[p-24];
        float sn,cs; sincosf(ang,&sn,&cs);
        float x0=qraw[r][p*2], x1=qraw[r][p*2+1];
        qr[r][c] = (c&1)? (x0*sn+x1*cs) : (x0*cs-x1*sn);
    }
    __syncthreads();
    int head=c>>4, el=c&15;
    const float* km=&kmf[(b*NH_+head)*16];
    const float* kvp=&kvf[((size_t)(b*NH_+head))*256];
    float zd=1e-6f;
    #pragma unroll
    for(int d2=0;d2<16;d2++) zd += qraw[r][head*16+d2]*km[d2];
    zd = 1.f/zd;
    float o=0.f;
    #pragma unroll
    for(int d2=0;d2<16;d2++) o += qr[r][head*16+d2]*kvp[d2*16+el];
    o*=zd;
    float acc=lb[c];
    #pragma unroll
    for(int kh=0;kh<3;kh++){
        int hh=hpos+kh-1;
        if((unsigned)hh<128u){
            #pragma unroll
            for(int kw=0;kw<3;kw++){
                int ww=wpos+kw-1;
                if((unsigned)ww<128u)
                    acc += vbuf[((size_t)b*L_+(hh<<7)+ww)*C_+c]*lw[c*9+kh*3+kw];
            }
        }
    }
    aout[row*C_+c]=o+acc;
}

// ---------------- K8: x_proj (96->38) + dt_proj (6->96) + softplus ----------------
__global__ __launch_bounds__(384) void k_xdbl(const float* __restrict__ xs,
    const float* __restrict__ xpw, const float* __restrict__ dtw,
    const float* __restrict__ dtb, float* __restrict__ delta, float* __restrict__ BC)
{
    __shared__ float in[4][C_];
    __shared__ float xd[4][NPROJ_];
    int t=threadIdx.x;
    size_t row0=(size_t)blockIdx.x*4;
    for(int i=t;i<4*C_;i+=384) in[i/C_][i%C_]=xs[row0*C_+i];
    __syncthreads();
    if(t<4*NPROJ_){
        int r=t/NPROJ_, e=t%NPROJ_;
        float a=0.f;
        for(int kk=0;kk<C_;kk++) a+=in[r][kk]*xpw[kk*NPROJ_+e];
        xd[r][e]=a;
    }
    __syncthreads();
    {
        int r=t/C_, c=t%C_;
        float a=dtb[c];
        #pragma unroll
        for(int j=0;j<6;j++) a+=xd[r][j]*dtw[j*C_+c];
        float dl = (a>20.f)? a : log1pf(__expf(a));
        delta[(row0+r)*C_+c]=dl;
    }
    if(t<4*32){
        int r=t/32, j=t%32;
        BC[(row0+r)*32+j]=xd[r][6+j];
    }
}

// ---------------- K9a: scan pass1 ----------------
__global__ __launch_bounds__(96) void k_scan1(const float* __restrict__ delta,
    const float* __restrict__ xs, const float* __restrict__ BC,
    const float* __restrict__ A_log, float* __restrict__ Ap, float* __restrict__ Be)
{
    int c=threadIdx.x;
    int blk=blockIdx.x; int b=blk/NCH_; int ch=blk%NCH_;
    float a[16];
    #pragma unroll
    for(int n=0;n<16;n++) a[n]=-__expf(A_log[c*16+n]);
    float ap[16], be[16];
    #pragma unroll
    for(int n=0;n<16;n++){ap[n]=1.f; be[n]=0.f;}
    int l0=ch*CHL_;
    for(int i=0;i<CHL_;i++){
        size_t row=(size_t)b*L_+l0+i;
        float dl=delta[row*C_+c];
        float u=xs[row*C_+c];
        float du=dl*u;
        const float* bcp=&BC[row*32];
        #pragma unroll
        for(int n=0;n<16;n++){
            float dA=__expf(dl*a[n]);
            ap[n]*=dA;
            be[n]=be[n]*dA + du*bcp[n];
        }
    }
    float* app=&Ap[((size_t)blk*C_+c)*16];
    float* bep=&Be[((size_t)blk*C_+c)*16];
    #pragma unroll
    for(int n=0;n<16;n++){app[n]=ap[n]; bep[n]=be[n];}
}

// ---------------- K9b: scan pass2 ----------------
__global__ __launch_bounds__(256) void k_scan2(const float* __restrict__ Ap,
    const float* __restrict__ Be, float* __restrict__ Hin)
{
    int t=blockIdx.x*256+threadIdx.x;
    int b=t/1536; int rem=t%1536;
    float h=0.f;
    for(int ch=0;ch<NCH_;ch++){
        size_t idx=((size_t)(b*NCH_+ch)*1536)+rem;
        Hin[idx]=h;
        h = Ap[idx]*h + Be[idx];
    }
}

// ---------------- K9c: scan pass3 ----------------
__global__ __launch_bounds__(96) void k_scan3(const float* __restrict__ delta,
    const float* __restrict__ xs, const float* __restrict__ BC,
    const float* __restrict__ A_log, const float* __restrict__ Dv,
    const float* __restrict__ Hin, float* __restrict__ y)
{
    int c=threadIdx.x;
    int blk=blockIdx.x; int b=blk/NCH_; int ch=blk%NCH_;
    float a[16];
    #pragma unroll
    for(int n=0;n<16;n++) a[n]=-__expf(A_log[c*16+n]);
    float h[16];
    const float* hp=&Hin[((size_t)blk*C_+c)*16];
    #pragma unroll
    for(int n=0;n<16;n++) h[n]=hp[n];
    float Dc=Dv[c];
    int l0=ch*CHL_;
    for(int i=0;i<CHL_;i++){
        size_t row=(size_t)b*L_+l0+i;
        float dl=delta[row*C_+c];
        float u=xs[row*C_+c];
        float du=dl*u;
        const float* bcp=&BC[row*32];
        float yv=0.f;
        #pragma unroll
        for(int n=0;n<16;n++){
            float dA=__expf(dl*a[n]);
            h[n]=h[n]*dA + du*bcp[n];
            yv += h[n]*bcp[16+n];
        }
        y[row*C_+c]=yv + Dc*u;
    }
}

// ---------------- K10: combine (3 chained GEMMs) MFMA ----------------
__global__ __launch_bounds__(256) void k_combine_m(const float* __restrict__ y,
    const float* __restrict__ zs, const float* __restrict__ aout,
    const unsigned short* __restrict__ wbf, const float* __restrict__ pob,
    const float* __restrict__ outb, const float* __restrict__ hs,
    float* __restrict__ outr)
{
    __shared__ unsigned short Y[64*192];
    __shared__ unsigned short AZ[64*128];
    __shared__ unsigned short C2[64*192];
    int t=threadIdx.x;
    size_t row0=(size_t)blockIdx.x*64;
    for (int p=t;p<64*48;p+=256){
        int r=p/48, c=(p-r*48)*2;
        size_t g=(row0+r)*C_+c;
        float2 yv=*(const float2*)&y[g];
        float2 zv=*(const float2*)&zs[g];
        float2 av=*(const float2*)&aout[g];
        int sw=(r&7)<<3;
        *(unsigned*)&Y[r*192 + (c^sw)] = pack2(yv.x,yv.y);
        *(unsigned*)&Y[r*192 + ((96+c)^sw)] = pack2(zv.x,zv.y);
        *(unsigned*)&AZ[r*128 + (c^sw)] = pack2(av.x*zv.x, av.y*zv.y);
    }
    __syncthreads();
    int w=t>>6,l=t&63,lr=l&15,lh=l>>4;
    int arow=w*16+lr; int asw=(arow&7)<<3;
    bf16x8 af1[6], af2[3];
    #pragma unroll
    for (int kf=0;kf<6;kf++) af1[kf]=*(const bf16x8*)&Y[arow*192 + ((kf*32+lh*8)^asw)];
    #pragma unroll
    for (int kf=0;kf<3;kf++) af2[kf]=*(const bf16x8*)&AZ[arow*128 + ((kf*32+lh*8)^asw)];
    #pragma unroll 2
    for (int nt=0;nt<6;nt++){
        f32x4 a1={0.f,0.f,0.f,0.f}, a2={0.f,0.f,0.f,0.f};
        #pragma unroll
        for (int kf=0;kf<6;kf++){
            bf16x8 b=*(const bf16x8*)(wbf+((size_t)((WOFF3+kf*6+nt)*64+l))*8);
            a1=MFMA16(af1[kf],b,a1);
        }
        #pragma unroll
        for (int kf=0;kf<3;kf++){
            bf16x8 b=*(const bf16x8*)(wbf+((size_t)((WOFF4+kf*6+nt)*64+l))*8);
            a2=MFMA16(af2[kf],b,a2);
        }
        int col=nt*16+lr;
        float pb=pob[col];
        #pragma unroll
        for (int j=0;j<4;j++){
            int row=w*16+lh*4+j;
            int sw2=(row&7)<<3;
            C2[row*192 + (col^sw2)] = f2bf(a1[j]);
            C2[row*192 + ((96+col)^sw2)] = f2bf(a2[j]+pb);
        }
    }
    __syncthreads();
    bf16x8 af3[6];
    #pragma unroll
    for (int kf=0;kf<6;kf++) af3[kf]=*(const bf16x8*)&C2[arow*192 + ((kf*32+lh*8)^asw)];
    #pragma unroll 2
    for (int nt=0;nt<6;nt++){
        f32x4 acc={0.f,0.f,0.f,0.f};
        #pragma unroll
        for (int kf=0;kf<6;kf++){
            bf16x8 b=*(const bf16x8*)(wbf+((size_t)((WOFF5+kf*6+nt)*64+l))*8);
            acc=MFMA16(af3[kf],b,acc);
        }
        int col=nt*16+lr;
        float ob=outb[col];
        #pragma unroll
        for (int j=0;j<4;j++){
            size_t row=row0+w*16+lh*4+j;
            outr[row*C_+col] = acc[j] + ob + hs[row*C_+col];
        }
    }
}

// ---------------- K11: MLP (LN + fc1 + gelu + fc2 + residual) MFMA ----------------
__global__ __launch_bounds__(256) void k_mlp_m(float* __restrict__ outr,
    const float* __restrict__ gg, const float* __restrict__ bb,
    const unsigned short* __restrict__ wbf,
    const float* __restrict__ f1b, const float* __restrict__ f2b)
{
    __shared__ unsigned short A[64*128];
    __shared__ unsigned short HID[64*384];
    int t=threadIdx.x;
    size_t row0=(size_t)blockIdx.x*64;
    {
        int r=t>>2, q=t&3;
        const float* src = outr + (row0+r)*C_ + q*24;
        float v[24]; float s=0.f,s2=0.f;
        #pragma unroll
        for(int i=0;i<24;i++){float x=src[i];v[i]=x;s+=x;s2+=x*x;}
        s+=__shfl_xor(s,1); s2+=__shfl_xor(s2,1);
        s+=__shfl_xor(s,2); s2+=__shfl_xor(s2,2);
        float mn=s*(1.f/C_), rs=rsqrtf(s2*(1.f/C_)-mn*mn+1e-5f);
        int base=r*128, sw=(r&7)<<3;
        #pragma unroll
        for(int i=0;i<24;i+=2){
            int c=q*24+i;
            *(unsigned*)&A[base+(c^sw)] = pack2((v[i]  -mn)*rs*gg[c]  +bb[c],
                                               (v[i+1]-mn)*rs*gg[c+1]+bb[c+1]);
        }
    }
    __syncthreads();
    int w=t>>6,l=t&63,lr=l&15,lh=l>>4;
    int arow=w*16+lr, asw=(arow&7)<<3;
    {
        bf16x8 af[3];
        #pragma unroll
        for(int kf=0;kf<3;kf++) af[kf]=*(const bf16x8*)&A[arow*128+((kf*32+lh*8)^asw)];
        #pragma unroll 2
        for(int nt=0;nt<24;nt++){
            f32x4 acc={0.f,0.f,0.f,0.f};
            #pragma unroll
            for(int kf=0;kf<3;kf++){
                bf16x8 b=*(const bf16x8*)(wbf+((size_t)((WOFF6+kf*24+nt)*64+l))*8);
                acc=MFMA16(af[kf],b,acc);
            }
            int col=nt*16+lr;
            float bias=f1b[col];
            #pragma unroll
            for(int j=0;j<4;j++){
                int row=w*16+lh*4+j;
                float x=acc[j]+bias;
                float g=0.5f*x*(1.f+erff(x*0.70710678f));
                HID[row*384 + (col^((row&7)<<3))] = f2bf(g);
            }
        }
    }
    __syncthreads();
    {
        bf16x8 af2[12];
        #pragma unroll
        for(int kf=0;kf<12;kf++) af2[kf]=*(const bf16x8*)&HID[arow*384+((kf*32+lh*8)^asw)];
        #pragma unroll 2
        for(int nt=0;nt<6;nt++){
            f32x4 acc={0.f,0.f,0.f,0.f};
            #pragma unroll
            for(int kf=0;kf<12;kf++){
                bf16x8 b=*(const bf16x8*)(wbf+((size_t)((WOFF7+kf*6+nt)*64+l))*8);
                acc=MFMA16(af2[kf],b,acc);
            }
            int col=nt*16+lr;
            float bias=f2b[col];
            #pragma unroll
            for(int j=0;j<4;j++){
                size_t row=row0+w*16+lh*4+j;
                outr[row*C_+col] += acc[j]+bias;
            }
        }
    }
}

extern "C" void kernel_launch(void* const* d_in, const int* in_sizes, int n_in,
                              void* d_out, int out_size, void* d_ws, size_t ws_size,
                              hipStream_t stream)
{
    const float* hs        = (const float*)d_in[0];
    const float* norm_in_g = (const float*)d_in[1];
    const float* norm_in_b = (const float*)d_in[2];
    const float* in_proj_w = (const float*)d_in[3];
    const float* dw_w      = (const float*)d_in[4];
    const float* dw_b      = (const float*)d_in[5];
    const float* qk_w      = (const float*)d_in[6];
    const float* qk_b      = (const float*)d_in[7];
    const float* lepe_w    = (const float*)d_in[8];
    const float* lepe_b    = (const float*)d_in[9];
    const float* conv_x_w  = (const float*)d_in[10];
    const float* conv_z_w  = (const float*)d_in[11];
    const float* x_proj_w  = (const float*)d_in[12];
    const float* dt_proj_w = (const float*)d_in[13];
    const float* dt_proj_b = (const float*)d_in[14];
    const float* A_log     = (const float*)d_in[15];
    const float* Dv        = (const float*)d_in[16];
    const float* out_proj_w= (const float*)d_in[17];
    const float* proj_out_w= (const float*)d_in[18];
    const float* proj_out_b= (const float*)d_in[19];
    const float* out_w     = (const float*)d_in[20];
    const float* out_b     = (const float*)d_in[21];
    const float* norm_mlp_g= (const float*)d_in[22];
    const float* norm_mlp_b= (const float*)d_in[23];
    const float* fc1_w     = (const float*)d_in[24];
    const float* fc1_b     = (const float*)d_in[25];
    const float* fc2_w     = (const float*)d_in[26];
    const float* fc2_b     = (const float*)d_in[27];

    float* ws = (float*)d_ws;
    size_t o = 0;
    float* xzw   = ws + o; o += (size_t)BL_*288;
    float* lin_x = ws + o; o += (size_t)BL_*C_;
    float* aout  = ws + o; o += (size_t)BL_*C_;
    float* xs    = ws + o; o += (size_t)BL_*C_;
    float* zs    = ws + o; o += (size_t)BL_*C_;
    float* ybuf  = ws + o; o += (size_t)BL_*C_;
    float* BC    = ws + o; o += (size_t)BL_*32;
    float* kvpart= ws + o; o += (size_t)B_*NH_*KVCH_*272;
    float* kvf   = ws + o; o += (size_t)B_*NH_*256;
    float* kmf   = ws + o; o += (size_t)B_*NH_*16;
    float* Ap    = ws + o; o += (size_t)B_*NCH_*C_*16;
    float* Be    = ws + o; o += (size_t)B_*NCH_*C_*16;
    float* Hin   = ws + o; o += (size_t)B_*NCH_*C_*16;
    unsigned short* wbf = (unsigned short*)(ws + o); o += (size_t)WFRAGS*512/2;

    float* qbuf  = xzw;
    float* kbuf  = xzw + (size_t)BL_*C_;
    float* delta = xzw + (size_t)2*BL_*C_;

    float* outr = (float*)d_out;

    k_wprep<<<dim3(72,7), 64, 0, stream>>>(in_proj_w, qk_w, out_proj_w, proj_out_w,
                                           out_w, fc1_w, fc2_w, wbf);
    k_ln_inproj_m<<<BL_/64, 256, 0, stream>>>(hs, norm_in_g, norm_in_b, wbf, xzw);
    k_dwconv2d<<<BL_/4, 384, 0, stream>>>(xzw, dw_w, dw_b, lin_x);
    k_conv1d<<<BL_/4, 384, 0, stream>>>(xzw, conv_x_w, conv_z_w, xs, zs);
    k_qk_m<<<BL_/64, 256, 0, stream>>>(lin_x, wbf, qk_b, qbuf, kbuf);
    k_kvred<<<dim3(KVCH_, B_*NH_), 256, 0, stream>>>(kbuf, lin_x, kvpart);
    k_kvfin<<<B_*NH_, 272, 0, stream>>>(kvpart, kvf, kmf);
    k_attnout<<<BL_/4, 384, 0, stream>>>(qbuf, lin_x, kvf, kmf, lepe_w, lepe_b, aout);
    k_xdbl<<<BL_/4, 384, 0, stream>>>(xs, x_proj_w, dt_proj_w, dt_proj_b, delta, BC);
    k_scan1<<<B_*NCH_, 96, 0, stream>>>(delta, xs, BC, A_log, Ap, Be);
    k_scan2<<<(B_*C_*16)/256, 256, 0, stream>>>(Ap, Be, Hin);
    k_scan3<<<B_*NCH_, 96, 0, stream>>>(delta, xs, BC, A_log, Dv, Hin, ybuf);
    k_combine_m<<<BL_/64, 256, 0, stream>>>(ybuf, zs, aout, wbf, proj_out_b,
                                            out_b, hs, outr);
    k_mlp_m<<<BL_/64, 256, 0, stream>>>(outr, norm_mlp_g, norm_mlp_b, wbf,
                                        fc1_b, fc2_b);
}

// Round 3
// 314.734 us; speedup vs baseline: 2.2265x; 1.1949x over previous
//
#include <hip/hip_runtime.h>
#include <hip/hip_bf16.h>
#include <math.h>

#define B_ 2
#define H_ 128
#define W_ 128
#define C_ 96
#define L_ (H_*W_)
#define BL_ (B_*L_)
#define NH_ 6
#define NPROJ_ 38
#define MLPH_ 384
#define NCH_ 256
#define CHL_ (L_/NCH_)

typedef __attribute__((ext_vector_type(8))) short bf16x8;
typedef __attribute__((ext_vector_type(4))) float f32x4;

#define MFMA16(a,b,c) __builtin_amdgcn_mfma_f32_16x16x32_bf16(a,b,c,0,0,0)

// weight fragment table (each frag = 64 lanes * 8 bf16 = 512 elems)
#define WOFF1 0      // in_proj  96x288 : 3*18 = 54
#define WOFF2 54     // qk_w     96x192 : 3*12 = 36
#define WOFF3 90     // out_proj 192x96 : 6*6  = 36
#define WOFF4 126    // proj_out 96x96  : 3*6  = 18
#define WOFF5 144    // out_w    192x96 : 6*6  = 36
#define WOFF6 180    // fc1      96x384 : 3*24 = 72
#define WOFF7 252    // fc2      384x96 : 12*6 = 72
#define WFRAGS 324

__device__ __forceinline__ float siluf(float x){ return x / (1.f + __expf(-x)); }
__device__ __forceinline__ unsigned short f2bf(float x){
    __hip_bfloat16 h = __float2bfloat16(x);
    return *reinterpret_cast<unsigned short*>(&h);
}
__device__ __forceinline__ unsigned pack2(float a, float b){
    return (unsigned)f2bf(a) | ((unsigned)f2bf(b) << 16);
}
__device__ __forceinline__ float bf2f(unsigned short u){
    return __uint_as_float((unsigned)u << 16);
}

// ---------------- K0: setup — weight prep + rope table + kv zero + conv wt transpose ----------------
__global__ __launch_bounds__(64) void k_setup(const float* __restrict__ w1,
    const float* __restrict__ w2, const float* __restrict__ w3,
    const float* __restrict__ w4, const float* __restrict__ w5,
    const float* __restrict__ w6, const float* __restrict__ w7,
    const float* __restrict__ dww, const float* __restrict__ lw,
    unsigned short* __restrict__ dst, float2* __restrict__ ctab,
    float* __restrict__ wt9, float* __restrict__ lw9, float* __restrict__ kvacc)
{
    int m = blockIdx.y;
    int l = threadIdx.x;
    if (m < 7){
        const float* srcs[7] = {w1,w2,w3,w4,w5,w6,w7};
        const int Ks[7]   = {96,96,192,96,192,96,384};
        const int Ns[7]   = {288,192,96,96,96,384,96};
        const int offs[7] = {WOFF1,WOFF2,WOFF3,WOFF4,WOFF5,WOFF6,WOFF7};
        int f = blockIdx.x;
        int nnt = Ns[m] >> 4, nkf = Ks[m] >> 5;
        if (f >= nnt*nkf) return;
        int kf = f / nnt, nt = f - kf*nnt;
        const float* s = srcs[m];
        unsigned short* d = dst + ((size_t)(offs[m] + f)*64 + l)*8;
        int krow = kf*32 + (l>>4)*8;
        int col  = nt*16 + (l&15);
        #pragma unroll
        for (int j=0;j<8;j++) d[j] = f2bf(s[(size_t)(krow+j)*Ns[m] + col]);
    } else {
        int x = blockIdx.x;
        if (x == 0){
            for (int i=l; i<128*24; i+=64){
                int pos = i/24, p = i%24;
                float th = powf(10000.f, -(float)p/24.f);
                float sn, cs; sincosf((float)pos*th, &sn, &cs);
                ctab[i] = make_float2(cs, sn);
            }
        } else if (x == 1){
            for (int i=l; i<3264; i+=64) kvacc[i] = 0.f;
        } else if (x == 2){
            for (int i=l; i<864; i+=64){
                int c = i/9, tap = i%9;
                wt9[tap*96 + c] = dww[i];
                lw9[tap*96 + c] = lw[i];
            }
        }
    }
}

// ---------------- K1: LayerNorm + in_proj (96 -> 288) MFMA, split outputs ----------------
__global__ __launch_bounds__(256) void k_ln_inproj_m(const float* __restrict__ hs,
    const float* __restrict__ gg, const float* __restrict__ bb,
    const unsigned short* __restrict__ wbf,
    float* __restrict__ xx, float* __restrict__ zz, float* __restrict__ ww)
{
    __shared__ unsigned short A[64*128];
    int t = threadIdx.x;
    size_t row0 = (size_t)blockIdx.x * 64;
    {
        int r = t >> 2, q = t & 3;
        const float* src = hs + (row0 + r)*C_ + q*24;
        float v[24];
        float s=0.f, s2=0.f;
        #pragma unroll
        for (int i=0;i<24;i++){ float x=src[i]; v[i]=x; s+=x; s2+=x*x; }
        s += __shfl_xor(s,1); s2 += __shfl_xor(s2,1);
        s += __shfl_xor(s,2); s2 += __shfl_xor(s2,2);
        float mn = s*(1.f/C_);
        float rs = rsqrtf(s2*(1.f/C_) - mn*mn + 1e-5f);
        int base = r*128, sw = (r&7)<<3;
        #pragma unroll
        for (int i=0;i<24;i+=2){
            int c = q*24 + i;
            float a0 = (v[i]  -mn)*rs*gg[c]   + bb[c];
            float a1 = (v[i+1]-mn)*rs*gg[c+1] + bb[c+1];
            *(unsigned*)&A[base + (c ^ sw)] = pack2(a0,a1);
        }
    }
    __syncthreads();
    int w = t>>6, l = t&63, lr = l&15, lh = l>>4;
    int arow = w*16 + lr;
    int abase = arow*128, asw = (arow&7)<<3;
    bf16x8 af[3];
    #pragma unroll
    for (int kf=0;kf<3;kf++)
        af[kf] = *(const bf16x8*)&A[abase + ((kf*32 + lh*8) ^ asw)];
    #pragma unroll 2
    for (int nt=0; nt<18; nt++){
        f32x4 acc = {0.f,0.f,0.f,0.f};
        #pragma unroll
        for (int kf=0;kf<3;kf++){
            bf16x8 bf_ = *(const bf16x8*)(wbf + ((size_t)((WOFF1 + kf*18 + nt)*64 + l))*8);
            acc = MFMA16(af[kf], bf_, acc);
        }
        float* base_;
        if (nt < 6) base_ = xx; else if (nt < 12) base_ = zz; else base_ = ww;
        int col = (nt%6)*16 + lr;
        float* dst = base_ + (row0 + w*16 + lh*4)*C_ + col;
        #pragma unroll
        for (int j=0;j<4;j++) dst[(size_t)j*C_] = acc[j];
    }
}

// ---------------- K2: depthwise 3x3 conv + silu on ww, float4 ----------------
__global__ __launch_bounds__(256) void k_dwconv2d(const float* __restrict__ wwb,
    const float* __restrict__ wt9, const float* __restrict__ dwb,
    float* __restrict__ out)
{
    int gid = blockIdx.x*256 + threadIdx.x;   // BL*24
    int row = gid/24, c4 = gid%24; int c = c4*4;
    int b = row >> 14;
    int ll = row & (L_-1);
    int h = ll >> 7, wq = ll & 127;
    float4 acc = {0.f,0.f,0.f,0.f};
    #pragma unroll
    for (int kh=0; kh<3; kh++){
        int hh = h + kh - 1;
        if ((unsigned)hh < 128u){
            int base_row = (b<<14) + (hh<<7);
            #pragma unroll
            for (int kw=0; kw<3; kw++){
                int wp = wq + kw - 1;
                if ((unsigned)wp < 128u){
                    float4 v = *(const float4*)&wwb[(size_t)(base_row + wp)*C_ + c];
                    float4 wt = *(const float4*)&wt9[(kh*3+kw)*96 + c];
                    acc.x += v.x*wt.x; acc.y += v.y*wt.y;
                    acc.z += v.z*wt.z; acc.w += v.w*wt.w;
                }
            }
        }
    }
    float4 bv = *(const float4*)&dwb[c];
    float4 o;
    o.x = siluf(acc.x+bv.x); o.y = siluf(acc.y+bv.y);
    o.z = siluf(acc.z+bv.z); o.w = siluf(acc.w+bv.w);
    *(float4*)&out[(size_t)row*C_ + c] = o;
}

// ---------------- K3: conv1d+silu on x,z  fused with x_proj/dt_proj/softplus ----------------
__global__ __launch_bounds__(384) void k_conv1d_xdbl(const float* __restrict__ xxb,
    const float* __restrict__ zzb, const float* __restrict__ wx,
    const float* __restrict__ wz, const float* __restrict__ xpw,
    const float* __restrict__ dtw, const float* __restrict__ dtb,
    float* __restrict__ xs, float* __restrict__ zs,
    float* __restrict__ delta, float* __restrict__ BC)
{
    __shared__ float sx[8][C_];
    __shared__ float xd[8][NPROJ_];
    int t = threadIdx.x;
    size_t row0 = (size_t)blockIdx.x*8;
    int b = (int)(row0 >> 14);
    int l0 = (int)(row0 & 16383);
    for (int i=t; i<8*C_; i+=384){
        int r=i/C_, c=i%C_;
        int l = l0 + r;
        float ax=0.f, az=0.f;
        #pragma unroll
        for (int j=0;j<4;j++){
            int lq = l - 1 + j;
            if ((unsigned)lq < (unsigned)L_){
                size_t rr = ((size_t)b<<14) + lq;
                ax += xxb[rr*C_+c]*wx[c*4+j];
                az += zzb[rr*C_+c]*wz[c*4+j];
            }
        }
        ax = siluf(ax); az = siluf(az);
        sx[r][c] = ax;
        xs[(row0+r)*C_+c] = ax;
        zs[(row0+r)*C_+c] = az;
    }
    __syncthreads();
    if (t < 8*NPROJ_){
        int r = t/NPROJ_, e = t%NPROJ_;
        float a = 0.f;
        for (int kk=0; kk<C_; kk++) a += sx[r][kk]*xpw[kk*NPROJ_+e];
        xd[r][e] = a;
    }
    __syncthreads();
    for (int i=t; i<8*C_; i+=384){
        int r=i/C_, c=i%C_;
        float a = dtb[c];
        #pragma unroll
        for (int j=0;j<6;j++) a += xd[r][j]*dtw[j*C_+c];
        float dl = (a>20.f)? a : log1pf(__expf(a));
        delta[(row0+r)*C_+c] = dl;
    }
    if (t < 256){
        int r = t/32, j = t%32;
        BC[(row0+r)*32 + j] = xd[r][6+j];
    }
}

// ---------------- K4: qk MFMA + elu+1 + rope-k + fused kv/kmean partial reduce ----------------
__global__ __launch_bounds__(256) void k_qk_kv(const float* __restrict__ lin,
    const unsigned short* __restrict__ wbf, const float* __restrict__ qkb,
    const float2* __restrict__ ctab, float* __restrict__ qo,
    float* __restrict__ kvacc)
{
    __shared__ unsigned short A[64*128];
    __shared__ float KR[64*100];
    __shared__ float kmsum[96];
    int t = threadIdx.x;
    size_t row0 = (size_t)blockIdx.x * 64;
    int b = (int)(row0 >> 14);
    int l0 = (int)(row0 & 16383);
    for (int p = t; p < 64*48; p += 256){
        int r = p/48, c = (p - r*48)*2;
        float2 xy = *(const float2*)&lin[(row0 + r)*C_ + c];
        *(unsigned*)&A[r*128 + (c ^ ((r&7)<<3))] = pack2(xy.x, xy.y);
    }
    if (t < 96) kmsum[t] = 0.f;
    __syncthreads();
    int w=t>>6, l=t&63, lr=l&15, lh=l>>4;
    int arow = w*16+lr; int asw=(arow&7)<<3;
    bf16x8 af[3];
    #pragma unroll
    for (int kf=0;kf<3;kf++)
        af[kf] = *(const bf16x8*)&A[arow*128 + ((kf*32 + lh*8) ^ asw)];
    #pragma unroll 2
    for (int nt=0; nt<12; nt++){
        f32x4 acc={0.f,0.f,0.f,0.f};
        #pragma unroll
        for (int kf=0;kf<3;kf++){
            bf16x8 bfr=*(const bf16x8*)(wbf + ((size_t)((WOFF2 + kf*12 + nt)*64 + l))*8);
            acc = MFMA16(af[kf], bfr, acc);
        }
        int colg = nt*16 + lr;
        float bias = qkb[colg];
        float vv[4];
        #pragma unroll
        for (int j=0;j<4;j++){
            float v = acc[j] + bias;
            vv[j] = (v>0.f)? v+1.f : __expf(v);
        }
        if (nt < 6){
            float* dp = qo + (row0 + w*16 + lh*4)*C_ + colg;
            #pragma unroll
            for (int j=0;j<4;j++) dp[(size_t)j*C_] = vv[j];
        } else {
            int ck = colg - 96;
            atomicAdd(&kmsum[ck], vv[0]+vv[1]+vv[2]+vv[3]);
            float pv[4];
            #pragma unroll
            for (int j=0;j<4;j++) pv[j] = __shfl_xor(vv[j], 1);
            int p = ck >> 1;
            #pragma unroll
            for (int j=0;j<4;j++){
                int rl = l0 + w*16 + lh*4 + j;
                int hp = rl>>7, wp = rl&127;
                float2 cssn = (p<24)? ctab[hp*24+p] : ctab[wp*24+(p-24)];
                float kr = (ck&1)? (pv[j]*cssn.y + vv[j]*cssn.x)
                                 : (vv[j]*cssn.x - pv[j]*cssn.y);
                KR[(w*16+lh*4+j)*100 + ck] = kr;
            }
        }
    }
    __syncthreads();
    int d = t>>4, e = t&15;
    float accs[6];
    #pragma unroll
    for (int h=0; h<6; h++){
        float a = 0.f;
        int cc = h*16 + e;
        #pragma unroll 8
        for (int r=0; r<64; r++){
            float kv_ = KR[r*100 + h*16 + d];
            float v = bf2f(A[r*128 + (cc ^ ((r&7)<<3))]);
            a += kv_*v;
        }
        accs[h] = a;
    }
    #pragma unroll
    for (int h=0; h<6; h++)
        atomicAdd(&kvacc[b*1536 + h*256 + d*16 + e], accs[h]);
    if (t < 96) atomicAdd(&kvacc[3072 + b*96 + t], kmsum[t]);
}

// ---------------- K5: attention output (table rope q @ kv * zden) + lepe conv ----------------
__global__ __launch_bounds__(384) void k_attnout(const float* __restrict__ qbuf,
    const float* __restrict__ vbuf, const float* __restrict__ kvacc,
    const float2* __restrict__ ctab, const float* __restrict__ lw9,
    const float* __restrict__ lb, float* __restrict__ aout)
{
    __shared__ float qraw[4][C_];
    __shared__ float qr[4][C_];
    __shared__ float kvs[6*272];   // h*272 + d*17 + e
    __shared__ float kms[96];
    int t = threadIdx.x; int r = t/C_, c = t%C_;
    size_t row0 = (size_t)blockIdx.x*4;
    int b = (int)(row0 >> 14);
    const float invL = 1.f/16384.f;
    for (int i=t; i<1536; i+=384){
        int h=i>>8, rem=i&255, d=rem>>4, e=rem&15;
        kvs[h*272 + d*17 + e] = kvacc[b*1536 + i]*invL;
    }
    if (t < 96) kms[t] = kvacc[3072 + b*96 + t]*invL;
    qraw[r][c] = qbuf[(row0+r)*C_ + c];
    __syncthreads();
    int lrow = (int)(row0 & 16383) + r;
    int hp = lrow>>7, wp = lrow&127;
    int p = c>>1;
    {
        float2 cssn = (p<24)? ctab[hp*24+p] : ctab[wp*24+(p-24)];
        float x0 = qraw[r][p*2], x1 = qraw[r][p*2+1];
        qr[r][c] = (c&1)? (x0*cssn.y + x1*cssn.x) : (x0*cssn.x - x1*cssn.y);
    }
    __syncthreads();
    int h = c>>4, e = c&15;
    float zd = 1e-6f;
    #pragma unroll
    for (int d=0; d<16; d++) zd += qraw[r][h*16+d]*kms[h*16+d];
    float o = 0.f;
    #pragma unroll
    for (int d=0; d<16; d++) o += qr[r][h*16+d]*kvs[h*272 + d*17 + e];
    o /= zd;
    float acc = lb[c];
    #pragma unroll
    for (int kh=0; kh<3; kh++){
        int hh = hp + kh - 1;
        if ((unsigned)hh < 128u){
            #pragma unroll
            for (int kw=0; kw<3; kw++){
                int wq = wp + kw - 1;
                if ((unsigned)wq < 128u)
                    acc += vbuf[((size_t)(b<<14) + (hh<<7) + wq)*C_ + c]*lw9[(kh*3+kw)*96 + c];
            }
        }
    }
    aout[(row0+r)*C_ + c] = o + acc;
}

// ---------------- K6a: scan pass1 — per-chunk aggregates, 4 states/thread ----------------
__global__ __launch_bounds__(384) void k_scan1(const float* __restrict__ delta,
    const float* __restrict__ xs, const float* __restrict__ BC,
    const float* __restrict__ A_log, float* __restrict__ Ap, float* __restrict__ Be)
{
    int t = threadIdx.x; int nq = t&3, c = t>>2;
    int blk = blockIdx.x; int b = blk>>8, ch = blk&255;
    float4 a4 = *(const float4*)&A_log[c*16 + nq*4];
    float a0=-__expf(a4.x), a1=-__expf(a4.y), a2=-__expf(a4.z), a3=-__expf(a4.w);
    float ap0=1.f,ap1=1.f,ap2=1.f,ap3=1.f;
    float be0=0.f,be1=0.f,be2=0.f,be3=0.f;
    size_t base = ((size_t)b<<14) + ch*CHL_;
    for (int i=0;i<CHL_;i++){
        size_t row = base + i;
        float dl = delta[row*C_+c];
        float u  = xs[row*C_+c];
        float du = dl*u;
        float4 bc = *(const float4*)&BC[row*32 + nq*4];
        float e0=__expf(dl*a0), e1=__expf(dl*a1), e2=__expf(dl*a2), e3=__expf(dl*a3);
        ap0*=e0; be0=be0*e0+du*bc.x;
        ap1*=e1; be1=be1*e1+du*bc.y;
        ap2*=e2; be2=be2*e2+du*bc.z;
        ap3*=e3; be3=be3*e3+du*bc.w;
    }
    size_t o = (size_t)blk*1536 + c*16 + nq*4;
    float4 apv={ap0,ap1,ap2,ap3}, bev={be0,be1,be2,be3};
    *(float4*)&Ap[o] = apv;
    *(float4*)&Be[o] = bev;
}

// ---------------- K6b: group aggregates (16 chunks/group) ----------------
__global__ __launch_bounds__(384) void k_scan2a(const float* __restrict__ Ap,
    const float* __restrict__ Be, float* __restrict__ GA, float* __restrict__ GB)
{
    int t = threadIdx.x; int blk = blockIdx.x;  // B*16
    int b = blk>>4, g = blk&15;
    int idx = (t>>2)*16 + (t&3)*4;
    float4 A = {1.f,1.f,1.f,1.f}, Bv = {0.f,0.f,0.f,0.f};
    for (int j=0;j<16;j++){
        size_t o = ((size_t)(b*256 + g*16 + j))*1536 + idx;
        float4 a = *(const float4*)&Ap[o];
        float4 bb = *(const float4*)&Be[o];
        Bv.x=a.x*Bv.x+bb.x; Bv.y=a.y*Bv.y+bb.y; Bv.z=a.z*Bv.z+bb.z; Bv.w=a.w*Bv.w+bb.w;
        A.x*=a.x; A.y*=a.y; A.z*=a.z; A.w*=a.w;
    }
    size_t o = (size_t)blk*1536 + idx;
    *(float4*)&GA[o] = A;
    *(float4*)&GB[o] = Bv;
}

// ---------------- K6c: sequential over 16 groups ----------------
__global__ __launch_bounds__(256) void k_scan2b(const float* __restrict__ GA,
    const float* __restrict__ GB, float* __restrict__ Gin)
{
    int t = blockIdx.x*256 + threadIdx.x;  // 3072
    int b = t/1536, m = t%1536;
    float h = 0.f;
    for (int g=0; g<16; g++){
        size_t o = ((size_t)(b*16+g))*1536 + m;
        Gin[o] = h;
        h = GA[o]*h + GB[o];
    }
}

// ---------------- K6d: within-group chunk-incoming states ----------------
__global__ __launch_bounds__(384) void k_scan2c(const float* __restrict__ Ap,
    const float* __restrict__ Be, const float* __restrict__ Gin,
    float* __restrict__ Hin)
{
    int t = threadIdx.x; int blk = blockIdx.x;  // B*16
    int b = blk>>4, g = blk&15;
    int idx = (t>>2)*16 + (t&3)*4;
    float4 h = *(const float4*)&Gin[(size_t)blk*1536 + idx];
    for (int j=0;j<16;j++){
        size_t o = ((size_t)(b*256 + g*16 + j))*1536 + idx;
        *(float4*)&Hin[o] = h;
        float4 a = *(const float4*)&Ap[o];
        float4 bb = *(const float4*)&Be[o];
        h.x=a.x*h.x+bb.x; h.y=a.y*h.y+bb.y; h.z=a.z*h.z+bb.z; h.w=a.w*h.w+bb.w;
    }
}

// ---------------- K6e: scan pass3 — replay + emit y ----------------
__global__ __launch_bounds__(384) void k_scan3(const float* __restrict__ delta,
    const float* __restrict__ xs, const float* __restrict__ BC,
    const float* __restrict__ A_log, const float* __restrict__ Dv,
    const float* __restrict__ Hin, float* __restrict__ y)
{
    int t = threadIdx.x; int nq = t&3, c = t>>2;
    int blk = blockIdx.x; int b = blk>>8, ch = blk&255;
    float4 a4 = *(const float4*)&A_log[c*16 + nq*4];
    float a0=-__expf(a4.x), a1=-__expf(a4.y), a2=-__expf(a4.z), a3=-__expf(a4.w);
    float4 h = *(const float4*)&Hin[(size_t)blk*1536 + c*16 + nq*4];
    float Dc = Dv[c];
    size_t base = ((size_t)b<<14) + ch*CHL_;
    for (int i=0;i<CHL_;i++){
        size_t row = base + i;
        float dl = delta[row*C_+c];
        float u  = xs[row*C_+c];
        float du = dl*u;
        float4 bcB = *(const float4*)&BC[row*32 + nq*4];
        float4 bcC = *(const float4*)&BC[row*32 + 16 + nq*4];
        float e0=__expf(dl*a0), e1=__expf(dl*a1), e2=__expf(dl*a2), e3=__expf(dl*a3);
        h.x=h.x*e0+du*bcB.x; h.y=h.y*e1+du*bcB.y;
        h.z=h.z*e2+du*bcB.z; h.w=h.w*e3+du*bcB.w;
        float yv = h.x*bcC.x + h.y*bcC.y + h.z*bcC.z + h.w*bcC.w;
        yv += __shfl_xor(yv,1);
        yv += __shfl_xor(yv,2);
        if (nq == 0) y[row*C_+c] = yv + Dc*u;
    }
}

// ---------------- K7: combine (3 chained GEMMs) MFMA ----------------
__global__ __launch_bounds__(256) void k_combine_m(const float* __restrict__ y,
    const float* __restrict__ zs, const float* __restrict__ aout,
    const unsigned short* __restrict__ wbf, const float* __restrict__ pob,
    const float* __restrict__ outb, const float* __restrict__ hs,
    float* __restrict__ outr)
{
    __shared__ unsigned short Y[64*192];
    __shared__ unsigned short AZ[64*128];
    __shared__ unsigned short C2[64*192];
    int t=threadIdx.x;
    size_t row0=(size_t)blockIdx.x*64;
    for (int p=t;p<64*48;p+=256){
        int r=p/48, c=(p-r*48)*2;
        size_t g=(row0+r)*C_+c;
        float2 yv=*(const float2*)&y[g];
        float2 zv=*(const float2*)&zs[g];
        float2 av=*(const float2*)&aout[g];
        int sw=(r&7)<<3;
        *(unsigned*)&Y[r*192 + (c^sw)] = pack2(yv.x,yv.y);
        *(unsigned*)&Y[r*192 + ((96+c)^sw)] = pack2(zv.x,zv.y);
        *(unsigned*)&AZ[r*128 + (c^sw)] = pack2(av.x*zv.x, av.y*zv.y);
    }
    __syncthreads();
    int w=t>>6,l=t&63,lr=l&15,lh=l>>4;
    int arow=w*16+lr; int asw=(arow&7)<<3;
    bf16x8 af1[6], af2[3];
    #pragma unroll
    for (int kf=0;kf<6;kf++) af1[kf]=*(const bf16x8*)&Y[arow*192 + ((kf*32+lh*8)^asw)];
    #pragma unroll
    for (int kf=0;kf<3;kf++) af2[kf]=*(const bf16x8*)&AZ[arow*128 + ((kf*32+lh*8)^asw)];
    #pragma unroll 2
    for (int nt=0;nt<6;nt++){
        f32x4 a1={0.f,0.f,0.f,0.f}, a2={0.f,0.f,0.f,0.f};
        #pragma unroll
        for (int kf=0;kf<6;kf++){
            bf16x8 b=*(const bf16x8*)(wbf+((size_t)((WOFF3+kf*6+nt)*64+l))*8);
            a1=MFMA16(af1[kf],b,a1);
        }
        #pragma unroll
        for (int kf=0;kf<3;kf++){
            bf16x8 b=*(const bf16x8*)(wbf+((size_t)((WOFF4+kf*6+nt)*64+l))*8);
            a2=MFMA16(af2[kf],b,a2);
        }
        int col=nt*16+lr;
        float pb=pob[col];
        #pragma unroll
        for (int j=0;j<4;j++){
            int row=w*16+lh*4+j;
            int sw2=(row&7)<<3;
            C2[row*192 + (col^sw2)] = f2bf(a1[j]);
            C2[row*192 + ((96+col)^sw2)] = f2bf(a2[j]+pb);
        }
    }
    __syncthreads();
    bf16x8 af3[6];
    #pragma unroll
    for (int kf=0;kf<6;kf++) af3[kf]=*(const bf16x8*)&C2[arow*192 + ((kf*32+lh*8)^asw)];
    #pragma unroll 2
    for (int nt=0;nt<6;nt++){
        f32x4 acc={0.f,0.f,0.f,0.f};
        #pragma unroll
        for (int kf=0;kf<6;kf++){
            bf16x8 b=*(const bf16x8*)(wbf+((size_t)((WOFF5+kf*6+nt)*64+l))*8);
            acc=MFMA16(af3[kf],b,acc);
        }
        int col=nt*16+lr;
        float ob=outb[col];
        #pragma unroll
        for (int j=0;j<4;j++){
            size_t row=row0+w*16+lh*4+j;
            outr[row*C_+col] = acc[j] + ob + hs[row*C_+col];
        }
    }
}

// ---------------- K8: MLP (LN + fc1 + gelu + fc2 + residual) MFMA ----------------
__global__ __launch_bounds__(256) void k_mlp_m(float* __restrict__ outr,
    const float* __restrict__ gg, const float* __restrict__ bb,
    const unsigned short* __restrict__ wbf,
    const float* __restrict__ f1b, const float* __restrict__ f2b)
{
    __shared__ unsigned short A[64*128];
    __shared__ unsigned short HID[64*384];
    int t=threadIdx.x;
    size_t row0=(size_t)blockIdx.x*64;
    {
        int r=t>>2, q=t&3;
        const float* src = outr + (row0+r)*C_ + q*24;
        float v[24]; float s=0.f,s2=0.f;
        #pragma unroll
        for(int i=0;i<24;i++){float x=src[i];v[i]=x;s+=x;s2+=x*x;}
        s+=__shfl_xor(s,1); s2+=__shfl_xor(s2,1);
        s+=__shfl_xor(s,2); s2+=__shfl_xor(s2,2);
        float mn=s*(1.f/C_), rs=rsqrtf(s2*(1.f/C_)-mn*mn+1e-5f);
        int base=r*128, sw=(r&7)<<3;
        #pragma unroll
        for(int i=0;i<24;i+=2){
            int c=q*24+i;
            *(unsigned*)&A[base+(c^sw)] = pack2((v[i]  -mn)*rs*gg[c]  +bb[c],
                                               (v[i+1]-mn)*rs*gg[c+1]+bb[c+1]);
        }
    }
    __syncthreads();
    int w=t>>6,l=t&63,lr=l&15,lh=l>>4;
    int arow=w*16+lr, asw=(arow&7)<<3;
    {
        bf16x8 af[3];
        #pragma unroll
        for(int kf=0;kf<3;kf++) af[kf]=*(const bf16x8*)&A[arow*128+((kf*32+lh*8)^asw)];
        #pragma unroll 2
        for(int nt=0;nt<24;nt++){
            f32x4 acc={0.f,0.f,0.f,0.f};
            #pragma unroll
            for(int kf=0;kf<3;kf++){
                bf16x8 b=*(const bf16x8*)(wbf+((size_t)((WOFF6+kf*24+nt)*64+l))*8);
                acc=MFMA16(af[kf],b,acc);
            }
            int col=nt*16+lr;
            float bias=f1b[col];
            #pragma unroll
            for(int j=0;j<4;j++){
                int row=w*16+lh*4+j;
                float x=acc[j]+bias;
                float g=0.5f*x*(1.f+erff(x*0.70710678f));
                HID[row*384 + (col^((row&7)<<3))] = f2bf(g);
            }
        }
    }
    __syncthreads();
    {
        bf16x8 af2[12];
        #pragma unroll
        for(int kf=0;kf<12;kf++) af2[kf]=*(const bf16x8*)&HID[arow*384+((kf*32+lh*8)^asw)];
        #pragma unroll 2
        for(int nt=0;nt<6;nt++){
            f32x4 acc={0.f,0.f,0.f,0.f};
            #pragma unroll
            for(int kf=0;kf<12;kf++){
                bf16x8 b=*(const bf16x8*)(wbf+((size_t)((WOFF7+kf*6+nt)*64+l))*8);
                acc=MFMA16(af2[kf],b,acc);
            }
            int col=nt*16+lr;
            float bias=f2b[col];
            #pragma unroll
            for(int j=0;j<4;j++){
                size_t row=row0+w*16+lh*4+j;
                outr[row*C_+col] += acc[j]+bias;
            }
        }
    }
}

extern "C" void kernel_launch(void* const* d_in, const int* in_sizes, int n_in,
                              void* d_out, int out_size, void* d_ws, size_t ws_size,
                              hipStream_t stream)
{
    const float* hs        = (const float*)d_in[0];
    const float* norm_in_g = (const float*)d_in[1];
    const float* norm_in_b = (const float*)d_in[2];
    const float* in_proj_w = (const float*)d_in[3];
    const float* dw_w      = (const float*)d_in[4];
    const float* dw_b      = (const float*)d_in[5];
    const float* qk_w      = (const float*)d_in[6];
    const float* qk_b      = (const float*)d_in[7];
    const float* lepe_w    = (const float*)d_in[8];
    const float* lepe_b    = (const float*)d_in[9];
    const float* conv_x_w  = (const float*)d_in[10];
    const float* conv_z_w  = (const float*)d_in[11];
    const float* x_proj_w  = (const float*)d_in[12];
    const float* dt_proj_w = (const float*)d_in[13];
    const float* dt_proj_b = (const float*)d_in[14];
    const float* A_log     = (const float*)d_in[15];
    const float* Dv        = (const float*)d_in[16];
    const float* out_proj_w= (const float*)d_in[17];
    const float* proj_out_w= (const float*)d_in[18];
    const float* proj_out_b= (const float*)d_in[19];
    const float* out_w     = (const float*)d_in[20];
    const float* out_b     = (const float*)d_in[21];
    const float* norm_mlp_g= (const float*)d_in[22];
    const float* norm_mlp_b= (const float*)d_in[23];
    const float* fc1_w     = (const float*)d_in[24];
    const float* fc1_b     = (const float*)d_in[25];
    const float* fc2_w     = (const float*)d_in[26];
    const float* fc2_b     = (const float*)d_in[27];

    float* ws = (float*)d_ws;
    size_t o = 0;
    float* xx    = ws + o; o += (size_t)BL_*C_;   // -> qbuf after conv1d_xdbl
    float* zz    = ws + o; o += (size_t)BL_*C_;   // -> ybuf after conv1d_xdbl
    float* wwb   = ws + o; o += (size_t)BL_*C_;   // -> aout after dwconv2d
    float* lin_x = ws + o; o += (size_t)BL_*C_;
    float* xs    = ws + o; o += (size_t)BL_*C_;
    float* zs    = ws + o; o += (size_t)BL_*C_;
    float* delta = ws + o; o += (size_t)BL_*C_;
    float* BC    = ws + o; o += (size_t)BL_*32;
    float* Ap    = ws + o; o += (size_t)B_*NCH_*1536;
    float* Be    = ws + o; o += (size_t)B_*NCH_*1536;
    float* Hin   = ws + o; o += (size_t)B_*NCH_*1536;
    float* GA    = ws + o; o += (size_t)B_*16*1536;
    float* GB    = ws + o; o += (size_t)B_*16*1536;
    float* Gin   = ws + o; o += (size_t)B_*16*1536;
    float* kvacc = ws + o; o += 3264;
    float2* ctab = (float2*)(ws + o); o += 6144;
    float* wt9   = ws + o; o += 864;
    float* lw9   = ws + o; o += 864;
    unsigned short* wbf = (unsigned short*)(ws + o);

    float* qbuf = xx;
    float* ybuf = zz;
    float* aout = wwb;
    float* outr = (float*)d_out;

    k_setup<<<dim3(72,8), 64, 0, stream>>>(in_proj_w, qk_w, out_proj_w, proj_out_w,
                                           out_w, fc1_w, fc2_w, dw_w, lepe_w,
                                           wbf, ctab, wt9, lw9, kvacc);
    k_ln_inproj_m<<<BL_/64, 256, 0, stream>>>(hs, norm_in_g, norm_in_b, wbf, xx, zz, wwb);
    k_dwconv2d<<<(BL_*24)/256, 256, 0, stream>>>(wwb, wt9, dw_b, lin_x);
    k_conv1d_xdbl<<<BL_/8, 384, 0, stream>>>(xx, zz, conv_x_w, conv_z_w, x_proj_w,
                                             dt_proj_w, dt_proj_b, xs, zs, delta, BC);
    k_qk_kv<<<BL_/64, 256, 0, stream>>>(lin_x, wbf, qk_b, ctab, qbuf, kvacc);
    k_attnout<<<BL_/4, 384, 0, stream>>>(qbuf, lin_x, kvacc, ctab, lw9, lepe_b, aout);
    k_scan1<<<B_*NCH_, 384, 0, stream>>>(delta, xs, BC, A_log, Ap, Be);
    k_scan2a<<<B_*16, 384, 0, stream>>>(Ap, Be, GA, GB);
    k_scan2b<<<12, 256, 0, stream>>>(GA, GB, Gin);
    k_scan2c<<<B_*16, 384, 0, stream>>>(Ap, Be, Gin, Hin);
    k_scan3<<<B_*NCH_, 384, 0, stream>>>(delta, xs, BC, A_log, Dv, Hin, ybuf);
    k_combine_m<<<BL_/64, 256, 0, stream>>>(ybuf, zs, aout, wbf, proj_out_b,
                                            out_b, hs, outr);
    k_mlp_m<<<BL_/64, 256, 0, stream>>>(outr, norm_mlp_g, norm_mlp_b, wbf,
                                        fc1_b, fc2_b);
}

// Round 4
// 265.698 us; speedup vs baseline: 2.6375x; 1.1846x over previous
//
#include <hip/hip_runtime.h>
#include <hip/hip_bf16.h>
#include <math.h>

#define B_ 2
#define H_ 128
#define W_ 128
#define C_ 96
#define L_ (H_*W_)
#define BL_ (B_*L_)
#define NH_ 6
#define NPROJ_ 38
#define MLPH_ 384
#define NCH_ 256
#define CHL_ (L_/NCH_)

typedef __attribute__((ext_vector_type(8))) short bf16x8;
typedef __attribute__((ext_vector_type(4))) float f32x4;

#define MFMA16(a,b,c) __builtin_amdgcn_mfma_f32_16x16x32_bf16(a,b,c,0,0,0)

// weight fragment table (each frag = 64 lanes * 8 bf16 = 512 elems)
#define WOFF1 0      // in_proj  96x288 : 3*18 = 54
#define WOFF2 54     // qk_w     96x192 : 3*12 = 36
#define WOFF3 90     // out_proj 192x96 : 6*6  = 36
#define WOFF4 126    // proj_out 96x96  : 3*6  = 18
#define WOFF5 144    // out_w    192x96 : 6*6  = 36
#define WOFF6 180    // fc1      96x384 : 3*24 = 72
#define WOFF7 252    // fc2      384x96 : 12*6 = 72
#define WFRAGS 324

__device__ __forceinline__ float siluf(float x){ return x / (1.f + __expf(-x)); }
__device__ __forceinline__ unsigned short f2bf(float x){
    __hip_bfloat16 h = __float2bfloat16(x);
    return *reinterpret_cast<unsigned short*>(&h);
}
__device__ __forceinline__ unsigned pack2(float a, float b){
    return (unsigned)f2bf(a) | ((unsigned)f2bf(b) << 16);
}
__device__ __forceinline__ float bf2f(unsigned short u){
    return __uint_as_float((unsigned)u << 16);
}

// ---------------- K0: setup — weight prep + rope table + kv zero + conv wt transpose ----------------
__global__ __launch_bounds__(64) void k_setup(const float* __restrict__ w1,
    const float* __restrict__ w2, const float* __restrict__ w3,
    const float* __restrict__ w4, const float* __restrict__ w5,
    const float* __restrict__ w6, const float* __restrict__ w7,
    const float* __restrict__ dww, const float* __restrict__ lw,
    unsigned short* __restrict__ dst, float2* __restrict__ ctab,
    float* __restrict__ wt9, float* __restrict__ lw9, float* __restrict__ kvacc)
{
    int m = blockIdx.y;
    int l = threadIdx.x;
    if (m < 7){
        const float* srcs[7] = {w1,w2,w3,w4,w5,w6,w7};
        const int Ks[7]   = {96,96,192,96,192,96,384};
        const int Ns[7]   = {288,192,96,96,96,384,96};
        const int offs[7] = {WOFF1,WOFF2,WOFF3,WOFF4,WOFF5,WOFF6,WOFF7};
        int f = blockIdx.x;
        int nnt = Ns[m] >> 4, nkf = Ks[m] >> 5;
        if (f >= nnt*nkf) return;
        int kf = f / nnt, nt = f - kf*nnt;
        const float* s = srcs[m];
        unsigned short* d = dst + ((size_t)(offs[m] + f)*64 + l)*8;
        int krow = kf*32 + (l>>4)*8;
        int col  = nt*16 + (l&15);
        #pragma unroll
        for (int j=0;j<8;j++) d[j] = f2bf(s[(size_t)(krow+j)*Ns[m] + col]);
    } else {
        int x = blockIdx.x;
        if (x == 0){
            for (int i=l; i<128*24; i+=64){
                int pos = i/24, p = i%24;
                float th = powf(10000.f, -(float)p/24.f);
                float sn, cs; sincosf((float)pos*th, &sn, &cs);
                ctab[i] = make_float2(cs, sn);
            }
        } else if (x == 1){
            for (int i=l; i<3264; i+=64) kvacc[i] = 0.f;
        } else if (x == 2){
            for (int i=l; i<864; i+=64){
                int c = i/9, tap = i%9;
                wt9[tap*96 + c] = dww[i];
                lw9[tap*96 + c] = lw[i];
            }
        }
    }
}

// ---------------- K1: LayerNorm + in_proj (96 -> 288) MFMA, split outputs ----------------
__global__ __launch_bounds__(256) void k_ln_inproj_m(const float* __restrict__ hs,
    const float* __restrict__ gg, const float* __restrict__ bb,
    const unsigned short* __restrict__ wbf,
    float* __restrict__ xx, float* __restrict__ zz, float* __restrict__ ww)
{
    __shared__ unsigned short A[64*128];
    int t = threadIdx.x;
    size_t row0 = (size_t)blockIdx.x * 64;
    {
        int r = t >> 2, q = t & 3;
        const float* src = hs + (row0 + r)*C_ + q*24;
        float v[24];
        float s=0.f, s2=0.f;
        #pragma unroll
        for (int i=0;i<24;i++){ float x=src[i]; v[i]=x; s+=x; s2+=x*x; }
        s += __shfl_xor(s,1); s2 += __shfl_xor(s2,1);
        s += __shfl_xor(s,2); s2 += __shfl_xor(s2,2);
        float mn = s*(1.f/C_);
        float rs = rsqrtf(s2*(1.f/C_) - mn*mn + 1e-5f);
        int base = r*128, sw = (r&7)<<3;
        #pragma unroll
        for (int i=0;i<24;i+=2){
            int c = q*24 + i;
            float a0 = (v[i]  -mn)*rs*gg[c]   + bb[c];
            float a1 = (v[i+1]-mn)*rs*gg[c+1] + bb[c+1];
            *(unsigned*)&A[base + (c ^ sw)] = pack2(a0,a1);
        }
    }
    __syncthreads();
    int w = t>>6, l = t&63, lr = l&15, lh = l>>4;
    int arow = w*16 + lr;
    int abase = arow*128, asw = (arow&7)<<3;
    bf16x8 af[3];
    #pragma unroll
    for (int kf=0;kf<3;kf++)
        af[kf] = *(const bf16x8*)&A[abase + ((kf*32 + lh*8) ^ asw)];
    #pragma unroll 2
    for (int nt=0; nt<18; nt++){
        f32x4 acc = {0.f,0.f,0.f,0.f};
        #pragma unroll
        for (int kf=0;kf<3;kf++){
            bf16x8 bf_ = *(const bf16x8*)(wbf + ((size_t)((WOFF1 + kf*18 + nt)*64 + l))*8);
            acc = MFMA16(af[kf], bf_, acc);
        }
        float* base_;
        if (nt < 6) base_ = xx; else if (nt < 12) base_ = zz; else base_ = ww;
        int col = (nt%6)*16 + lr;
        float* dst = base_ + (row0 + w*16 + lh*4)*C_ + col;
        #pragma unroll
        for (int j=0;j<4;j++) dst[(size_t)j*C_] = acc[j];
    }
}

// ---------------- K2: depthwise 3x3 conv + silu on ww, float4 ----------------
__global__ __launch_bounds__(256) void k_dwconv2d(const float* __restrict__ wwb,
    const float* __restrict__ wt9, const float* __restrict__ dwb,
    float* __restrict__ out)
{
    int gid = blockIdx.x*256 + threadIdx.x;   // BL*24
    int row = gid/24, c4 = gid%24; int c = c4*4;
    int b = row >> 14;
    int ll = row & (L_-1);
    int h = ll >> 7, wq = ll & 127;
    float4 acc = {0.f,0.f,0.f,0.f};
    #pragma unroll
    for (int kh=0; kh<3; kh++){
        int hh = h + kh - 1;
        if ((unsigned)hh < 128u){
            int base_row = (b<<14) + (hh<<7);
            #pragma unroll
            for (int kw=0; kw<3; kw++){
                int wp = wq + kw - 1;
                if ((unsigned)wp < 128u){
                    float4 v = *(const float4*)&wwb[(size_t)(base_row + wp)*C_ + c];
                    float4 wt = *(const float4*)&wt9[(kh*3+kw)*96 + c];
                    acc.x += v.x*wt.x; acc.y += v.y*wt.y;
                    acc.z += v.z*wt.z; acc.w += v.w*wt.w;
                }
            }
        }
    }
    float4 bv = *(const float4*)&dwb[c];
    float4 o;
    o.x = siluf(acc.x+bv.x); o.y = siluf(acc.y+bv.y);
    o.z = siluf(acc.z+bv.z); o.w = siluf(acc.w+bv.w);
    *(float4*)&out[(size_t)row*C_ + c] = o;
}

// ---------------- K3: conv1d+silu on x,z  fused with x_proj/dt_proj/softplus ----------------
__global__ __launch_bounds__(384) void k_conv1d_xdbl(const float* __restrict__ xxb,
    const float* __restrict__ zzb, const float* __restrict__ wx,
    const float* __restrict__ wz, const float* __restrict__ xpw,
    const float* __restrict__ dtw, const float* __restrict__ dtb,
    float* __restrict__ xs, float* __restrict__ zs,
    float* __restrict__ delta, float* __restrict__ BC)
{
    __shared__ float sx[8][C_];
    __shared__ float xd[8][NPROJ_];
    int t = threadIdx.x;
    size_t row0 = (size_t)blockIdx.x*8;
    int b = (int)(row0 >> 14);
    int l0 = (int)(row0 & 16383);
    for (int i=t; i<8*C_; i+=384){
        int r=i/C_, c=i%C_;
        int l = l0 + r;
        float ax=0.f, az=0.f;
        #pragma unroll
        for (int j=0;j<4;j++){
            int lq = l - 1 + j;
            if ((unsigned)lq < (unsigned)L_){
                size_t rr = ((size_t)b<<14) + lq;
                ax += xxb[rr*C_+c]*wx[c*4+j];
                az += zzb[rr*C_+c]*wz[c*4+j];
            }
        }
        ax = siluf(ax); az = siluf(az);
        sx[r][c] = ax;
        xs[(row0+r)*C_+c] = ax;
        zs[(row0+r)*C_+c] = az;
    }
    __syncthreads();
    if (t < 8*NPROJ_){
        int r = t/NPROJ_, e = t%NPROJ_;
        float a = 0.f;
        for (int kk=0; kk<C_; kk++) a += sx[r][kk]*xpw[kk*NPROJ_+e];
        xd[r][e] = a;
    }
    __syncthreads();
    for (int i=t; i<8*C_; i+=384){
        int r=i/C_, c=i%C_;
        float a = dtb[c];
        #pragma unroll
        for (int j=0;j<6;j++) a += xd[r][j]*dtw[j*C_+c];
        float dl = (a>20.f)? a : log1pf(__expf(a));
        delta[(row0+r)*C_+c] = dl;
    }
    if (t < 256){
        int r = t/32, j = t%32;
        BC[(row0+r)*32 + j] = xd[r][6+j];
    }
}

// ---------------- K4: qk MFMA + elu+1 + rope-k + MFMA kv reduce + kmean ----------------
__global__ __launch_bounds__(256) void k_qk_kv(const float* __restrict__ lin,
    const unsigned short* __restrict__ wbf, const float* __restrict__ qkb,
    const float2* __restrict__ ctab, float* __restrict__ qo,
    float* __restrict__ kvacc)
{
    __shared__ unsigned short A[64*128];
    __shared__ float KR[64*105];
    __shared__ float kmsum[96];
    int t = threadIdx.x;
    size_t row0 = (size_t)blockIdx.x * 64;
    int b = (int)(row0 >> 14);
    int l0 = (int)(row0 & 16383);
    for (int p = t; p < 64*48; p += 256){
        int r = p/48, c = (p - r*48)*2;
        float2 xy = *(const float2*)&lin[(row0 + r)*C_ + c];
        *(unsigned*)&A[r*128 + (c ^ ((r&7)<<3))] = pack2(xy.x, xy.y);
    }
    if (t < 96) kmsum[t] = 0.f;
    __syncthreads();
    int w=t>>6, l=t&63, lr=l&15, lh=l>>4;
    int arow = w*16+lr; int asw=(arow&7)<<3;
    bf16x8 af[3];
    #pragma unroll
    for (int kf=0;kf<3;kf++)
        af[kf] = *(const bf16x8*)&A[arow*128 + ((kf*32 + lh*8) ^ asw)];
    #pragma unroll 2
    for (int nt=0; nt<12; nt++){
        f32x4 acc={0.f,0.f,0.f,0.f};
        #pragma unroll
        for (int kf=0;kf<3;kf++){
            bf16x8 bfr=*(const bf16x8*)(wbf + ((size_t)((WOFF2 + kf*12 + nt)*64 + l))*8);
            acc = MFMA16(af[kf], bfr, acc);
        }
        int colg = nt*16 + lr;
        float bias = qkb[colg];
        float vv[4];
        #pragma unroll
        for (int j=0;j<4;j++){
            float v = acc[j] + bias;
            vv[j] = (v>0.f)? v+1.f : __expf(v);
        }
        if (nt < 6){
            float* dp = qo + (row0 + w*16 + lh*4)*C_ + colg;
            #pragma unroll
            for (int j=0;j<4;j++) dp[(size_t)j*C_] = vv[j];
        } else {
            int ck = colg - 96;
            atomicAdd(&kmsum[ck], vv[0]+vv[1]+vv[2]+vv[3]);
            float pv[4];
            #pragma unroll
            for (int j=0;j<4;j++) pv[j] = __shfl_xor(vv[j], 1);
            int p = ck >> 1;
            #pragma unroll
            for (int j=0;j<4;j++){
                int rl = l0 + w*16 + lh*4 + j;
                int hp = rl>>7, wp = rl&127;
                float2 cssn = (p<24)? ctab[hp*24+p] : ctab[wp*24+(p-24)];
                float kr = (ck&1)? (pv[j]*cssn.y + vv[j]*cssn.x)
                                 : (vv[j]*cssn.x - pv[j]*cssn.y);
                KR[(w*16+lh*4+j)*105 + ck] = kr;
            }
        }
    }
    __syncthreads();
    // phase 2: kv[h] = KR^T (16x64) @ V (64x16) via MFMA, 2 waves x 3 heads
    if (w < 2){
        #pragma unroll
        for (int hh=0; hh<3; hh++){
            int h = w*3 + hh;
            f32x4 acc = {0.f,0.f,0.f,0.f};
            #pragma unroll
            for (int kk=0; kk<2; kk++){
                union { bf16x8 v; unsigned short u[8]; } afu, bfu;
                #pragma unroll
                for (int j=0;j<8;j++){
                    int rr = kk*32 + lh*8 + j;
                    afu.u[j] = f2bf(KR[rr*105 + h*16 + lr]);
                    bfu.u[j] = A[rr*128 + ((h*16+lr) ^ ((rr&7)<<3))];
                }
                acc = MFMA16(afu.v, bfu.v, acc);
            }
            #pragma unroll
            for (int i=0;i<4;i++)
                atomicAdd(&kvacc[b*1536 + h*256 + (lh*4+i)*16 + lr], acc[i]);
        }
    }
    if (t < 96) atomicAdd(&kvacc[3072 + b*96 + t], kmsum[t]);
}

// ---------------- K5: attention output, 4 channels/thread, float4 ----------------
__global__ __launch_bounds__(384) void k_attnout(const float* __restrict__ qbuf,
    const float* __restrict__ vbuf, const float* __restrict__ kvacc,
    const float2* __restrict__ ctab, const float* __restrict__ lw9,
    const float* __restrict__ lb, float* __restrict__ aout)
{
    __shared__ float kvs[1536];
    __shared__ float kms[96];
    int t = threadIdx.x;
    size_t row0 = (size_t)blockIdx.x * 16;
    int b = (int)(row0 >> 14);
    const float invL = 1.f/16384.f;
    for (int i=t; i<1536; i+=384) kvs[i] = kvacc[b*1536+i]*invL;
    if (t < 96) kms[t] = kvacc[3072+b*96+t]*invL;
    __syncthreads();
    int r = t/24, c4 = t%24;
    int c = c4*4;
    int lrow = (int)(row0 & 16383) + r;
    int hp = lrow>>7, wp = lrow&127;
    size_t row = row0 + r;
    float4 q4 = *(const float4*)&qbuf[row*C_ + c];
    // rope the two complex pairs
    int p0 = c>>1, p1 = p0+1;
    float2 cs0 = (p0<24)? ctab[hp*24+p0] : ctab[wp*24+(p0-24)];
    float2 cs1 = (p1<24)? ctab[hp*24+p1] : ctab[wp*24+(p1-24)];
    float4 qr;
    qr.x = q4.x*cs0.x - q4.y*cs0.y;
    qr.y = q4.x*cs0.y + q4.y*cs0.x;
    qr.z = q4.z*cs1.x - q4.w*cs1.y;
    qr.w = q4.z*cs1.y + q4.w*cs1.x;
    int h = c4>>2, j = c4&3;
    int dbase = j*4;
    // zden partial over this thread's 4 dims (unroped q), reduce over quad
    float zp = q4.x*kms[h*16+dbase]   + q4.y*kms[h*16+dbase+1]
             + q4.z*kms[h*16+dbase+2] + q4.w*kms[h*16+dbase+3];
    zp += __shfl_xor(zp,1);
    zp += __shfl_xor(zp,2);
    float zd = 1.f/(zp + 1e-6f);
    // out[e0..e0+3], e0 = j*4: cooperative over the quad via shfl rotation
    float4 o = {0.f,0.f,0.f,0.f};
    #pragma unroll
    for (int g=0; g<4; g++){
        float4 qg;
        if (g==0) qg = qr;
        else {
            qg.x=__shfl_xor(qr.x,g); qg.y=__shfl_xor(qr.y,g);
            qg.z=__shfl_xor(qr.z,g); qg.w=__shfl_xor(qr.w,g);
        }
        int db = ((j^g)<<2);
        const float* kp = &kvs[h*256 + db*16 + j*4];
        #pragma unroll
        for (int i=0;i<4;i++){
            float qi = (i==0)?qg.x:(i==1)?qg.y:(i==2)?qg.z:qg.w;
            float4 kv4 = *(const float4*)&kp[i*16];
            o.x += qi*kv4.x; o.y += qi*kv4.y;
            o.z += qi*kv4.z; o.w += qi*kv4.w;
        }
    }
    // lepe 3x3 depthwise conv, float4
    float4 acc = *(const float4*)&lb[c];
    #pragma unroll
    for (int kh=0; kh<3; kh++){
        int hh = hp + kh - 1;
        if ((unsigned)hh < 128u){
            int base_row = (b<<14) + (hh<<7);
            #pragma unroll
            for (int kw=0; kw<3; kw++){
                int wq = wp + kw - 1;
                if ((unsigned)wq < 128u){
                    float4 v = *(const float4*)&vbuf[(size_t)(base_row + wq)*C_ + c];
                    float4 wt = *(const float4*)&lw9[(kh*3+kw)*96 + c];
                    acc.x += v.x*wt.x; acc.y += v.y*wt.y;
                    acc.z += v.z*wt.z; acc.w += v.w*wt.w;
                }
            }
        }
    }
    float4 res;
    res.x = o.x*zd + acc.x; res.y = o.y*zd + acc.y;
    res.z = o.z*zd + acc.z; res.w = o.w*zd + acc.w;
    *(float4*)&aout[row*C_ + c] = res;
}

// ---------------- K6a: scan pass1 — per-chunk aggregates, 4 states/thread ----------------
__global__ __launch_bounds__(384) void k_scan1(const float* __restrict__ delta,
    const float* __restrict__ xs, const float* __restrict__ BC,
    const float* __restrict__ A_log, float* __restrict__ Ap, float* __restrict__ Be)
{
    int t = threadIdx.x; int nq = t&3, c = t>>2;
    int blk = blockIdx.x; int b = blk>>8, ch = blk&255;
    float4 a4 = *(const float4*)&A_log[c*16 + nq*4];
    float a0=-__expf(a4.x), a1=-__expf(a4.y), a2=-__expf(a4.z), a3=-__expf(a4.w);
    float ap0=1.f,ap1=1.f,ap2=1.f,ap3=1.f;
    float be0=0.f,be1=0.f,be2=0.f,be3=0.f;
    size_t base = ((size_t)b<<14) + ch*CHL_;
    for (int i=0;i<CHL_;i++){
        size_t row = base + i;
        float dl = delta[row*C_+c];
        float u  = xs[row*C_+c];
        float du = dl*u;
        float4 bc = *(const float4*)&BC[row*32 + nq*4];
        float e0=__expf(dl*a0), e1=__expf(dl*a1), e2=__expf(dl*a2), e3=__expf(dl*a3);
        ap0*=e0; be0=be0*e0+du*bc.x;
        ap1*=e1; be1=be1*e1+du*bc.y;
        ap2*=e2; be2=be2*e2+du*bc.z;
        ap3*=e3; be3=be3*e3+du*bc.w;
    }
    size_t o = (size_t)blk*1536 + c*16 + nq*4;
    float4 apv={ap0,ap1,ap2,ap3}, bev={be0,be1,be2,be3};
    *(float4*)&Ap[o] = apv;
    *(float4*)&Be[o] = bev;
}

// ---------------- K6b: group aggregates (16 chunks/group) ----------------
__global__ __launch_bounds__(384) void k_scan2a(const float* __restrict__ Ap,
    const float* __restrict__ Be, float* __restrict__ GA, float* __restrict__ GB)
{
    int t = threadIdx.x; int blk = blockIdx.x;  // B*16
    int b = blk>>4, g = blk&15;
    int idx = (t>>2)*16 + (t&3)*4;
    float4 A = {1.f,1.f,1.f,1.f}, Bv = {0.f,0.f,0.f,0.f};
    for (int j=0;j<16;j++){
        size_t o = ((size_t)(b*256 + g*16 + j))*1536 + idx;
        float4 a = *(const float4*)&Ap[o];
        float4 bb = *(const float4*)&Be[o];
        Bv.x=a.x*Bv.x+bb.x; Bv.y=a.y*Bv.y+bb.y; Bv.z=a.z*Bv.z+bb.z; Bv.w=a.w*Bv.w+bb.w;
        A.x*=a.x; A.y*=a.y; A.z*=a.z; A.w*=a.w;
    }
    size_t o = (size_t)blk*1536 + idx;
    *(float4*)&GA[o] = A;
    *(float4*)&GB[o] = Bv;
}

// ---------------- K6c: sequential over 16 groups ----------------
__global__ __launch_bounds__(256) void k_scan2b(const float* __restrict__ GA,
    const float* __restrict__ GB, float* __restrict__ Gin)
{
    int t = blockIdx.x*256 + threadIdx.x;  // 3072
    int b = t/1536, m = t%1536;
    float h = 0.f;
    for (int g=0; g<16; g++){
        size_t o = ((size_t)(b*16+g))*1536 + m;
        Gin[o] = h;
        h = GA[o]*h + GB[o];
    }
}

// ---------------- K6d: within-group chunk-incoming states ----------------
__global__ __launch_bounds__(384) void k_scan2c(const float* __restrict__ Ap,
    const float* __restrict__ Be, const float* __restrict__ Gin,
    float* __restrict__ Hin)
{
    int t = threadIdx.x; int blk = blockIdx.x;  // B*16
    int b = blk>>4, g = blk&15;
    int idx = (t>>2)*16 + (t&3)*4;
    float4 h = *(const float4*)&Gin[(size_t)blk*1536 + idx];
    for (int j=0;j<16;j++){
        size_t o = ((size_t)(b*256 + g*16 + j))*1536 + idx;
        *(float4*)&Hin[o] = h;
        float4 a = *(const float4*)&Ap[o];
        float4 bb = *(const float4*)&Be[o];
        h.x=a.x*h.x+bb.x; h.y=a.y*h.y+bb.y; h.z=a.z*h.z+bb.z; h.w=a.w*h.w+bb.w;
    }
}

// ---------------- K6e: scan pass3 — replay + emit y ----------------
__global__ __launch_bounds__(384) void k_scan3(const float* __restrict__ delta,
    const float* __restrict__ xs, const float* __restrict__ BC,
    const float* __restrict__ A_log, const float* __restrict__ Dv,
    const float* __restrict__ Hin, float* __restrict__ y)
{
    int t = threadIdx.x; int nq = t&3, c = t>>2;
    int blk = blockIdx.x; int b = blk>>8, ch = blk&255;
    float4 a4 = *(const float4*)&A_log[c*16 + nq*4];
    float a0=-__expf(a4.x), a1=-__expf(a4.y), a2=-__expf(a4.z), a3=-__expf(a4.w);
    float4 h = *(const float4*)&Hin[(size_t)blk*1536 + c*16 + nq*4];
    float Dc = Dv[c];
    size_t base = ((size_t)b<<14) + ch*CHL_;
    for (int i=0;i<CHL_;i++){
        size_t row = base + i;
        float dl = delta[row*C_+c];
        float u  = xs[row*C_+c];
        float du = dl*u;
        float4 bcB = *(const float4*)&BC[row*32 + nq*4];
        float4 bcC = *(const float4*)&BC[row*32 + 16 + nq*4];
        float e0=__expf(dl*a0), e1=__expf(dl*a1), e2=__expf(dl*a2), e3=__expf(dl*a3);
        h.x=h.x*e0+du*bcB.x; h.y=h.y*e1+du*bcB.y;
        h.z=h.z*e2+du*bcB.z; h.w=h.w*e3+du*bcB.w;
        float yv = h.x*bcC.x + h.y*bcC.y + h.z*bcC.z + h.w*bcC.w;
        yv += __shfl_xor(yv,1);
        yv += __shfl_xor(yv,2);
        if (nq == 0) y[row*C_+c] = yv + Dc*u;
    }
}

// ---------------- K7: combine (3 chained GEMMs) MFMA ----------------
__global__ __launch_bounds__(256) void k_combine_m(const float* __restrict__ y,
    const float* __restrict__ zs, const float* __restrict__ aout,
    const unsigned short* __restrict__ wbf, const float* __restrict__ pob,
    const float* __restrict__ outb, const float* __restrict__ hs,
    float* __restrict__ outr)
{
    __shared__ unsigned short Y[64*192];
    __shared__ unsigned short AZ[64*128];
    __shared__ unsigned short C2[64*192];
    int t=threadIdx.x;
    size_t row0=(size_t)blockIdx.x*64;
    for (int p=t;p<64*48;p+=256){
        int r=p/48, c=(p-r*48)*2;
        size_t g=(row0+r)*C_+c;
        float2 yv=*(const float2*)&y[g];
        float2 zv=*(const float2*)&zs[g];
        float2 av=*(const float2*)&aout[g];
        int sw=(r&7)<<3;
        *(unsigned*)&Y[r*192 + (c^sw)] = pack2(yv.x,yv.y);
        *(unsigned*)&Y[r*192 + ((96+c)^sw)] = pack2(zv.x,zv.y);
        *(unsigned*)&AZ[r*128 + (c^sw)] = pack2(av.x*zv.x, av.y*zv.y);
    }
    __syncthreads();
    int w=t>>6,l=t&63,lr=l&15,lh=l>>4;
    int arow=w*16+lr; int asw=(arow&7)<<3;
    bf16x8 af1[6], af2[3];
    #pragma unroll
    for (int kf=0;kf<6;kf++) af1[kf]=*(const bf16x8*)&Y[arow*192 + ((kf*32+lh*8)^asw)];
    #pragma unroll
    for (int kf=0;kf<3;kf++) af2[kf]=*(const bf16x8*)&AZ[arow*128 + ((kf*32+lh*8)^asw)];
    #pragma unroll 2
    for (int nt=0;nt<6;nt++){
        f32x4 a1={0.f,0.f,0.f,0.f}, a2={0.f,0.f,0.f,0.f};
        #pragma unroll
        for (int kf=0;kf<6;kf++){
            bf16x8 b=*(const bf16x8*)(wbf+((size_t)((WOFF3+kf*6+nt)*64+l))*8);
            a1=MFMA16(af1[kf],b,a1);
        }
        #pragma unroll
        for (int kf=0;kf<3;kf++){
            bf16x8 b=*(const bf16x8*)(wbf+((size_t)((WOFF4+kf*6+nt)*64+l))*8);
            a2=MFMA16(af2[kf],b,a2);
        }
        int col=nt*16+lr;
        float pb=pob[col];
        #pragma unroll
        for (int j=0;j<4;j++){
            int row=w*16+lh*4+j;
            int sw2=(row&7)<<3;
            C2[row*192 + (col^sw2)] = f2bf(a1[j]);
            C2[row*192 + ((96+col)^sw2)] = f2bf(a2[j]+pb);
        }
    }
    __syncthreads();
    bf16x8 af3[6];
    #pragma unroll
    for (int kf=0;kf<6;kf++) af3[kf]=*(const bf16x8*)&C2[arow*192 + ((kf*32+lh*8)^asw)];
    #pragma unroll 2
    for (int nt=0;nt<6;nt++){
        f32x4 acc={0.f,0.f,0.f,0.f};
        #pragma unroll
        for (int kf=0;kf<6;kf++){
            bf16x8 b=*(const bf16x8*)(wbf+((size_t)((WOFF5+kf*6+nt)*64+l))*8);
            acc=MFMA16(af3[kf],b,acc);
        }
        int col=nt*16+lr;
        float ob=outb[col];
        #pragma unroll
        for (int j=0;j<4;j++){
            size_t row=row0+w*16+lh*4+j;
            outr[row*C_+col] = acc[j] + ob + hs[row*C_+col];
        }
    }
}

// ---------------- K8: MLP (LN + fc1 + gelu + fc2 + residual) MFMA ----------------
__global__ __launch_bounds__(256) void k_mlp_m(float* __restrict__ outr,
    const float* __restrict__ gg, const float* __restrict__ bb,
    const unsigned short* __restrict__ wbf,
    const float* __restrict__ f1b, const float* __restrict__ f2b)
{
    __shared__ unsigned short A[64*128];
    __shared__ unsigned short HID[64*384];
    int t=threadIdx.x;
    size_t row0=(size_t)blockIdx.x*64;
    {
        int r=t>>2, q=t&3;
        const float* src = outr + (row0+r)*C_ + q*24;
        float v[24]; float s=0.f,s2=0.f;
        #pragma unroll
        for(int i=0;i<24;i++){float x=src[i];v[i]=x;s+=x;s2+=x*x;}
        s+=__shfl_xor(s,1); s2+=__shfl_xor(s2,1);
        s+=__shfl_xor(s,2); s2+=__shfl_xor(s2,2);
        float mn=s*(1.f/C_), rs=rsqrtf(s2*(1.f/C_)-mn*mn+1e-5f);
        int base=r*128, sw=(r&7)<<3;
        #pragma unroll
        for(int i=0;i<24;i+=2){
            int c=q*24+i;
            *(unsigned*)&A[base+(c^sw)] = pack2((v[i]  -mn)*rs*gg[c]  +bb[c],
                                               (v[i+1]-mn)*rs*gg[c+1]+bb[c+1]);
        }
    }
    __syncthreads();
    int w=t>>6,l=t&63,lr=l&15,lh=l>>4;
    int arow=w*16+lr, asw=(arow&7)<<3;
    {
        bf16x8 af[3];
        #pragma unroll
        for(int kf=0;kf<3;kf++) af[kf]=*(const bf16x8*)&A[arow*128+((kf*32+lh*8)^asw)];
        #pragma unroll 2
        for(int nt=0;nt<24;nt++){
            f32x4 acc={0.f,0.f,0.f,0.f};
            #pragma unroll
            for(int kf=0;kf<3;kf++){
                bf16x8 b=*(const bf16x8*)(wbf+((size_t)((WOFF6+kf*24+nt)*64+l))*8);
                acc=MFMA16(af[kf],b,acc);
            }
            int col=nt*16+lr;
            float bias=f1b[col];
            #pragma unroll
            for(int j=0;j<4;j++){
                int row=w*16+lh*4+j;
                float x=acc[j]+bias;
                float g=0.5f*x*(1.f+erff(x*0.70710678f));
                HID[row*384 + (col^((row&7)<<3))] = f2bf(g);
            }
        }
    }
    __syncthreads();
    {
        bf16x8 af2[12];
        #pragma unroll
        for(int kf=0;kf<12;kf++) af2[kf]=*(const bf16x8*)&HID[arow*384+((kf*32+lh*8)^asw)];
        #pragma unroll 2
        for(int nt=0;nt<6;nt++){
            f32x4 acc={0.f,0.f,0.f,0.f};
            #pragma unroll
            for(int kf=0;kf<12;kf++){
                bf16x8 b=*(const bf16x8*)(wbf+((size_t)((WOFF7+kf*6+nt)*64+l))*8);
                acc=MFMA16(af2[kf],b,acc);
            }
            int col=nt*16+lr;
            float bias=f2b[col];
            #pragma unroll
            for(int j=0;j<4;j++){
                size_t row=row0+w*16+lh*4+j;
                outr[row*C_+col] += acc[j]+bias;
            }
        }
    }
}

extern "C" void kernel_launch(void* const* d_in, const int* in_sizes, int n_in,
                              void* d_out, int out_size, void* d_ws, size_t ws_size,
                              hipStream_t stream)
{
    const float* hs        = (const float*)d_in[0];
    const float* norm_in_g = (const float*)d_in[1];
    const float* norm_in_b = (const float*)d_in[2];
    const float* in_proj_w = (const float*)d_in[3];
    const float* dw_w      = (const float*)d_in[4];
    const float* dw_b      = (const float*)d_in[5];
    const float* qk_w      = (const float*)d_in[6];
    const float* qk_b      = (const float*)d_in[7];
    const float* lepe_w    = (const float*)d_in[8];
    const float* lepe_b    = (const float*)d_in[9];
    const float* conv_x_w  = (const float*)d_in[10];
    const float* conv_z_w  = (const float*)d_in[11];
    const float* x_proj_w  = (const float*)d_in[12];
    const float* dt_proj_w = (const float*)d_in[13];
    const float* dt_proj_b = (const float*)d_in[14];
    const float* A_log     = (const float*)d_in[15];
    const float* Dv        = (const float*)d_in[16];
    const float* out_proj_w= (const float*)d_in[17];
    const float* proj_out_w= (const float*)d_in[18];
    const float* proj_out_b= (const float*)d_in[19];
    const float* out_w     = (const float*)d_in[20];
    const float* out_b     = (const float*)d_in[21];
    const float* norm_mlp_g= (const float*)d_in[22];
    const float* norm_mlp_b= (const float*)d_in[23];
    const float* fc1_w     = (const float*)d_in[24];
    const float* fc1_b     = (const float*)d_in[25];
    const float* fc2_w     = (const float*)d_in[26];
    const float* fc2_b     = (const float*)d_in[27];

    float* ws = (float*)d_ws;
    size_t o = 0;
    float* xx    = ws + o; o += (size_t)BL_*C_;   // -> qbuf after conv1d_xdbl
    float* zz    = ws + o; o += (size_t)BL_*C_;   // -> ybuf after conv1d_xdbl
    float* wwb   = ws + o; o += (size_t)BL_*C_;   // -> aout after dwconv2d
    float* lin_x = ws + o; o += (size_t)BL_*C_;
    float* xs    = ws + o; o += (size_t)BL_*C_;
    float* zs    = ws + o; o += (size_t)BL_*C_;
    float* delta = ws + o; o += (size_t)BL_*C_;
    float* BC    = ws + o; o += (size_t)BL_*32;
    float* Ap    = ws + o; o += (size_t)B_*NCH_*1536;
    float* Be    = ws + o; o += (size_t)B_*NCH_*1536;
    float* Hin   = ws + o; o += (size_t)B_*NCH_*1536;
    float* GA    = ws + o; o += (size_t)B_*16*1536;
    float* GB    = ws + o; o += (size_t)B_*16*1536;
    float* Gin   = ws + o; o += (size_t)B_*16*1536;
    float* kvacc = ws + o; o += 3264;
    float2* ctab = (float2*)(ws + o); o += 6144;
    float* wt9   = ws + o; o += 864;
    float* lw9   = ws + o; o += 864;
    unsigned short* wbf = (unsigned short*)(ws + o);

    float* qbuf = xx;
    float* ybuf = zz;
    float* aout = wwb;
    float* outr = (float*)d_out;

    k_setup<<<dim3(72,8), 64, 0, stream>>>(in_proj_w, qk_w, out_proj_w, proj_out_w,
                                           out_w, fc1_w, fc2_w, dw_w, lepe_w,
                                           wbf, ctab, wt9, lw9, kvacc);
    k_ln_inproj_m<<<BL_/64, 256, 0, stream>>>(hs, norm_in_g, norm_in_b, wbf, xx, zz, wwb);
    k_dwconv2d<<<(BL_*24)/256, 256, 0, stream>>>(wwb, wt9, dw_b, lin_x);
    k_conv1d_xdbl<<<BL_/8, 384, 0, stream>>>(xx, zz, conv_x_w, conv_z_w, x_proj_w,
                                             dt_proj_w, dt_proj_b, xs, zs, delta, BC);
    k_qk_kv<<<BL_/64, 256, 0, stream>>>(lin_x, wbf, qk_b, ctab, qbuf, kvacc);
    k_attnout<<<BL_/16, 384, 0, stream>>>(qbuf, lin_x, kvacc, ctab, lw9, lepe_b, aout);
    k_scan1<<<B_*NCH_, 384, 0, stream>>>(delta, xs, BC, A_log, Ap, Be);
    k_scan2a<<<B_*16, 384, 0, stream>>>(Ap, Be, GA, GB);
    k_scan2b<<<12, 256, 0, stream>>>(GA, GB, Gin);
    k_scan2c<<<B_*16, 384, 0, stream>>>(Ap, Be, Gin, Hin);
    k_scan3<<<B_*NCH_, 384, 0, stream>>>(delta, xs, BC, A_log, Dv, Hin, ybuf);
    k_combine_m<<<BL_/64, 256, 0, stream>>>(ybuf, zs, aout, wbf, proj_out_b,
                                            out_b, hs, outr);
    k_mlp_m<<<BL_/64, 256, 0, stream>>>(outr, norm_mlp_g, norm_mlp_b, wbf,
                                        fc1_b, fc2_b);
}

// Round 5
// 223.766 us; speedup vs baseline: 3.1317x; 1.1874x over previous
//
#include <hip/hip_runtime.h>
#include <hip/hip_bf16.h>
#include <math.h>

#define B_ 2
#define H_ 128
#define W_ 128
#define C_ 96
#define L_ (H_*W_)
#define BL_ (B_*L_)
#define NH_ 6
#define NPROJ_ 38
#define MLPH_ 384
#define NCH_ 256
#define CHL_ (L_/NCH_)

typedef __attribute__((ext_vector_type(8))) short bf16x8;
typedef __attribute__((ext_vector_type(4))) float f32x4;

#define MFMA16(a,b,c) __builtin_amdgcn_mfma_f32_16x16x32_bf16(a,b,c,0,0,0)

// weight fragment table (each frag = 64 lanes * 8 bf16 = 512 elems)
#define WOFF1 0      // in_proj  96x288 : 3*18 = 54
#define WOFF2 54     // qk_w     96x192 : 3*12 = 36
#define WOFF3 90     // out_proj 192x96 : 6*6  = 36
#define WOFF4 126    // proj_out 96x96  : 3*6  = 18
#define WOFF5 144    // out_w    192x96 : 6*6  = 36
#define WOFF6 180    // fc1      96x384 : 3*24 = 72
#define WOFF7 252    // fc2      384x96 : 12*6 = 72
#define WOFF8 324    // x_proj   96x38(->48 pad) : 3*3 = 9
#define WFRAGS 333

__device__ __forceinline__ float siluf(float x){ return x / (1.f + __expf(-x)); }
__device__ __forceinline__ unsigned short f2bf(float x){
    __hip_bfloat16 h = __float2bfloat16(x);
    return *reinterpret_cast<unsigned short*>(&h);
}
__device__ __forceinline__ unsigned pack2(float a, float b){
    return (unsigned)f2bf(a) | ((unsigned)f2bf(b) << 16);
}
__device__ __forceinline__ float bf2f(unsigned short u){
    return __uint_as_float((unsigned)u << 16);
}

// ---------------- K0: setup — weight prep + rope table + misc transposes ----------------
__global__ __launch_bounds__(64) void k_setup(const float* __restrict__ w1,
    const float* __restrict__ w2, const float* __restrict__ w3,
    const float* __restrict__ w4, const float* __restrict__ w5,
    const float* __restrict__ w6, const float* __restrict__ w7,
    const float* __restrict__ dww, const float* __restrict__ lw,
    const float* __restrict__ xpw, const float* __restrict__ cxw,
    const float* __restrict__ czw,
    unsigned short* __restrict__ dst, float2* __restrict__ ctab,
    float* __restrict__ wt9, float* __restrict__ lw9, float* __restrict__ kvacc,
    float* __restrict__ wxT, float* __restrict__ wzT)
{
    int m = blockIdx.y;
    int l = threadIdx.x;
    if (m < 7){
        const float* srcs[7] = {w1,w2,w3,w4,w5,w6,w7};
        const int Ks[7]   = {96,96,192,96,192,96,384};
        const int Ns[7]   = {288,192,96,96,96,384,96};
        const int offs[7] = {WOFF1,WOFF2,WOFF3,WOFF4,WOFF5,WOFF6,WOFF7};
        int f = blockIdx.x;
        int nnt = Ns[m] >> 4, nkf = Ks[m] >> 5;
        if (f >= nnt*nkf) return;
        int kf = f / nnt, nt = f - kf*nnt;
        const float* s = srcs[m];
        unsigned short* d = dst + ((size_t)(offs[m] + f)*64 + l)*8;
        int krow = kf*32 + (l>>4)*8;
        int col  = nt*16 + (l&15);
        #pragma unroll
        for (int j=0;j<8;j++) d[j] = f2bf(s[(size_t)(krow+j)*Ns[m] + col]);
    } else {
        int x = blockIdx.x;
        if (x == 0){
            for (int i=l; i<128*24; i+=64){
                int pos = i/24, p = i%24;
                float th = powf(10000.f, -(float)p/24.f);
                float sn, cs; sincosf((float)pos*th, &sn, &cs);
                ctab[i] = make_float2(cs, sn);
            }
        } else if (x == 1){
            for (int i=l; i<3264; i+=64) kvacc[i] = 0.f;
        } else if (x == 2){
            for (int i=l; i<864; i+=64){
                int c = i/9, tap = i%9;
                wt9[tap*96 + c] = dww[i];
                lw9[tap*96 + c] = lw[i];
            }
        } else if (x == 3){
            // x_proj 96x38 -> padded 96x48 frags
            for (int f=0; f<9; f++){
                int kf=f/3, nt=f%3;
                unsigned short* d = dst + ((size_t)(WOFF8 + f)*64 + l)*8;
                int krow = kf*32 + (l>>4)*8;
                int col  = nt*16 + (l&15);
                #pragma unroll
                for (int j=0;j<8;j++){
                    float v = (col < NPROJ_) ? xpw[(size_t)(krow+j)*NPROJ_ + col] : 0.f;
                    d[j] = f2bf(v);
                }
            }
        } else if (x == 4){
            for (int i=l; i<384; i+=64){
                int j = i/96, c = i%96;
                wxT[i] = cxw[c*4 + j];
                wzT[i] = czw[c*4 + j];
            }
        }
    }
}

// ---------------- K1: LayerNorm + in_proj (96 -> 288) MFMA, split outputs ----------------
__global__ __launch_bounds__(256) void k_ln_inproj_m(const float* __restrict__ hs,
    const float* __restrict__ gg, const float* __restrict__ bb,
    const unsigned short* __restrict__ wbf,
    float* __restrict__ xx, float* __restrict__ zz, float* __restrict__ ww)
{
    __shared__ unsigned short A[64*128];
    int t = threadIdx.x;
    size_t row0 = (size_t)blockIdx.x * 64;
    {
        int r = t >> 2, q = t & 3;
        const float* src = hs + (row0 + r)*C_ + q*24;
        float v[24];
        float s=0.f, s2=0.f;
        #pragma unroll
        for (int i=0;i<24;i++){ float x=src[i]; v[i]=x; s+=x; s2+=x*x; }
        s += __shfl_xor(s,1); s2 += __shfl_xor(s2,1);
        s += __shfl_xor(s,2); s2 += __shfl_xor(s2,2);
        float mn = s*(1.f/C_);
        float rs = rsqrtf(s2*(1.f/C_) - mn*mn + 1e-5f);
        int base = r*128, sw = (r&7)<<3;
        #pragma unroll
        for (int i=0;i<24;i+=2){
            int c = q*24 + i;
            float a0 = (v[i]  -mn)*rs*gg[c]   + bb[c];
            float a1 = (v[i+1]-mn)*rs*gg[c+1] + bb[c+1];
            *(unsigned*)&A[base + (c ^ sw)] = pack2(a0,a1);
        }
    }
    __syncthreads();
    int w = t>>6, l = t&63, lr = l&15, lh = l>>4;
    int arow = w*16 + lr;
    int abase = arow*128, asw = (arow&7)<<3;
    bf16x8 af[3];
    #pragma unroll
    for (int kf=0;kf<3;kf++)
        af[kf] = *(const bf16x8*)&A[abase + ((kf*32 + lh*8) ^ asw)];
    #pragma unroll 2
    for (int nt=0; nt<18; nt++){
        f32x4 acc = {0.f,0.f,0.f,0.f};
        #pragma unroll
        for (int kf=0;kf<3;kf++){
            bf16x8 bf_ = *(const bf16x8*)(wbf + ((size_t)((WOFF1 + kf*18 + nt)*64 + l))*8);
            acc = MFMA16(af[kf], bf_, acc);
        }
        float* base_;
        if (nt < 6) base_ = xx; else if (nt < 12) base_ = zz; else base_ = ww;
        int col = (nt%6)*16 + lr;
        float* dst = base_ + (row0 + w*16 + lh*4)*C_ + col;
        #pragma unroll
        for (int j=0;j<4;j++) dst[(size_t)j*C_] = acc[j];
    }
}

// ---------------- K2: depthwise 3x3 conv + silu on ww, float4 ----------------
__global__ __launch_bounds__(256) void k_dwconv2d(const float* __restrict__ wwb,
    const float* __restrict__ wt9, const float* __restrict__ dwb,
    float* __restrict__ out)
{
    int gid = blockIdx.x*256 + threadIdx.x;   // BL*24
    int row = gid/24, c4 = gid%24; int c = c4*4;
    int b = row >> 14;
    int ll = row & (L_-1);
    int h = ll >> 7, wq = ll & 127;
    float4 acc = {0.f,0.f,0.f,0.f};
    #pragma unroll
    for (int kh=0; kh<3; kh++){
        int hh = h + kh - 1;
        if ((unsigned)hh < 128u){
            int base_row = (b<<14) + (hh<<7);
            #pragma unroll
            for (int kw=0; kw<3; kw++){
                int wp = wq + kw - 1;
                if ((unsigned)wp < 128u){
                    float4 v = *(const float4*)&wwb[(size_t)(base_row + wp)*C_ + c];
                    float4 wt = *(const float4*)&wt9[(kh*3+kw)*96 + c];
                    acc.x += v.x*wt.x; acc.y += v.y*wt.y;
                    acc.z += v.z*wt.z; acc.w += v.w*wt.w;
                }
            }
        }
    }
    float4 bv = *(const float4*)&dwb[c];
    float4 o;
    o.x = siluf(acc.x+bv.x); o.y = siluf(acc.y+bv.y);
    o.z = siluf(acc.z+bv.z); o.w = siluf(acc.w+bv.w);
    *(float4*)&out[(size_t)row*C_ + c] = o;
}

// ---------------- K3: conv1d+silu (float4) + x_proj MFMA + dt_proj/softplus ----------------
__global__ __launch_bounds__(256) void k_conv1d_xdbl(const float* __restrict__ xxb,
    const float* __restrict__ zzb, const float* __restrict__ wxT,
    const float* __restrict__ wzT, const unsigned short* __restrict__ wbf,
    const float* __restrict__ dtw, const float* __restrict__ dtb,
    float* __restrict__ xs, float* __restrict__ zs,
    float* __restrict__ delta, float* __restrict__ BC)
{
    __shared__ unsigned short A[64*128];   // silu(conv1d(x)) bf16, swizzled A-tile
    __shared__ float XD[64][8];            // dt part of x_dbl (cols 0..5)
    __shared__ float dtws[6][96];
    int t = threadIdx.x;
    size_t row0 = (size_t)blockIdx.x * 64;
    int b = (int)(row0 >> 14);
    int l0 = (int)(row0 & 16383);
    for (int i=t; i<576; i+=256) dtws[i/96][i%96] = dtw[i];
    // phase 1: conv1d + silu, float4 over channels
    for (int p=t; p<64*24; p+=256){
        int r = p/24, cq = p - r*24, c = cq*4;
        int l = l0 + r;
        float ax0=0.f,ax1=0.f,ax2=0.f,ax3=0.f;
        float az0=0.f,az1=0.f,az2=0.f,az3=0.f;
        #pragma unroll
        for (int j=0;j<4;j++){
            int lq = l - 1 + j;
            if ((unsigned)lq < (unsigned)L_){
                size_t off = ((size_t)(b<<14) + lq)*C_ + c;
                float4 xv = *(const float4*)&xxb[off];
                float4 zv = *(const float4*)&zzb[off];
                float4 wx4 = *(const float4*)&wxT[j*96 + c];
                float4 wz4 = *(const float4*)&wzT[j*96 + c];
                ax0 += xv.x*wx4.x; ax1 += xv.y*wx4.y; ax2 += xv.z*wx4.z; ax3 += xv.w*wx4.w;
                az0 += zv.x*wz4.x; az1 += zv.y*wz4.y; az2 += zv.z*wz4.z; az3 += zv.w*wz4.w;
            }
        }
        ax0=siluf(ax0); ax1=siluf(ax1); ax2=siluf(ax2); ax3=siluf(ax3);
        az0=siluf(az0); az1=siluf(az1); az2=siluf(az2); az3=siluf(az3);
        float4 xo={ax0,ax1,ax2,ax3}, zo={az0,az1,az2,az3};
        *(float4*)&xs[(row0+r)*C_ + c] = xo;
        *(float4*)&zs[(row0+r)*C_ + c] = zo;
        int sw = (r&7)<<3;
        uint2 pk = { pack2(ax0,ax1), pack2(ax2,ax3) };
        *(uint2*)&A[r*128 + (c ^ sw)] = pk;
    }
    __syncthreads();
    // phase 2: x_proj via MFMA (96 -> 48 padded; real cols: 0..5 dt, 6..37 BC)
    int w=t>>6, l=t&63, lr=l&15, lh=l>>4;
    int arow = w*16+lr, asw=(arow&7)<<3;
    bf16x8 af[3];
    #pragma unroll
    for (int kf=0;kf<3;kf++)
        af[kf] = *(const bf16x8*)&A[arow*128 + ((kf*32 + lh*8) ^ asw)];
    #pragma unroll
    for (int nt=0; nt<3; nt++){
        f32x4 acc={0.f,0.f,0.f,0.f};
        #pragma unroll
        for (int kf=0;kf<3;kf++){
            bf16x8 bfr=*(const bf16x8*)(wbf + ((size_t)((WOFF8 + kf*3 + nt)*64 + l))*8);
            acc = MFMA16(af[kf], bfr, acc);
        }
        int col = nt*16 + lr;
        #pragma unroll
        for (int j=0;j<4;j++){
            int row = w*16 + lh*4 + j;
            if (col < 6) XD[row][col] = acc[j];
            else if (col < NPROJ_) BC[(row0+row)*32 + (col-6)] = acc[j];
        }
    }
    __syncthreads();
    // phase 3: dt_proj (K=6) + softplus, float4
    {
        int r = t>>2, q = t&3;
        float xd0=XD[r][0], xd1=XD[r][1], xd2=XD[r][2];
        float xd3=XD[r][3], xd4=XD[r][4], xd5=XD[r][5];
        #pragma unroll
        for (int g=0; g<6; g++){
            int c = q*24 + g*4;
            float4 acc = *(const float4*)&dtb[c];
            float4 w0 = *(const float4*)&dtws[0][c];
            float4 w1 = *(const float4*)&dtws[1][c];
            float4 w2 = *(const float4*)&dtws[2][c];
            float4 w3 = *(const float4*)&dtws[3][c];
            float4 w4 = *(const float4*)&dtws[4][c];
            float4 w5 = *(const float4*)&dtws[5][c];
            acc.x += xd0*w0.x + xd1*w1.x + xd2*w2.x + xd3*w3.x + xd4*w4.x + xd5*w5.x;
            acc.y += xd0*w0.y + xd1*w1.y + xd2*w2.y + xd3*w3.y + xd4*w4.y + xd5*w5.y;
            acc.z += xd0*w0.z + xd1*w1.z + xd2*w2.z + xd3*w3.z + xd4*w4.z + xd5*w5.z;
            acc.w += xd0*w0.w + xd1*w1.w + xd2*w2.w + xd3*w3.w + xd4*w4.w + xd5*w5.w;
            float4 dl;
            dl.x = (acc.x>20.f)? acc.x : __logf(1.f+__expf(acc.x));
            dl.y = (acc.y>20.f)? acc.y : __logf(1.f+__expf(acc.y));
            dl.z = (acc.z>20.f)? acc.z : __logf(1.f+__expf(acc.z));
            dl.w = (acc.w>20.f)? acc.w : __logf(1.f+__expf(acc.w));
            *(float4*)&delta[(row0+r)*C_ + c] = dl;
        }
    }
}

// ---------------- K4: qk MFMA + elu+1 + rope-k + MFMA kv reduce + kmean ----------------
__global__ __launch_bounds__(256) void k_qk_kv(const float* __restrict__ lin,
    const unsigned short* __restrict__ wbf, const float* __restrict__ qkb,
    const float2* __restrict__ ctab, float* __restrict__ qo,
    float* __restrict__ kvacc)
{
    __shared__ unsigned short A[64*128];
    __shared__ float KR[64*105];
    __shared__ float kmsum[96];
    int t = threadIdx.x;
    size_t row0 = (size_t)blockIdx.x * 64;
    int b = (int)(row0 >> 14);
    int l0 = (int)(row0 & 16383);
    for (int p = t; p < 64*48; p += 256){
        int r = p/48, c = (p - r*48)*2;
        float2 xy = *(const float2*)&lin[(row0 + r)*C_ + c];
        *(unsigned*)&A[r*128 + (c ^ ((r&7)<<3))] = pack2(xy.x, xy.y);
    }
    if (t < 96) kmsum[t] = 0.f;
    __syncthreads();
    int w=t>>6, l=t&63, lr=l&15, lh=l>>4;
    int arow = w*16+lr; int asw=(arow&7)<<3;
    bf16x8 af[3];
    #pragma unroll
    for (int kf=0;kf<3;kf++)
        af[kf] = *(const bf16x8*)&A[arow*128 + ((kf*32 + lh*8) ^ asw)];
    #pragma unroll 2
    for (int nt=0; nt<12; nt++){
        f32x4 acc={0.f,0.f,0.f,0.f};
        #pragma unroll
        for (int kf=0;kf<3;kf++){
            bf16x8 bfr=*(const bf16x8*)(wbf + ((size_t)((WOFF2 + kf*12 + nt)*64 + l))*8);
            acc = MFMA16(af[kf], bfr, acc);
        }
        int colg = nt*16 + lr;
        float bias = qkb[colg];
        float vv[4];
        #pragma unroll
        for (int j=0;j<4;j++){
            float v = acc[j] + bias;
            vv[j] = (v>0.f)? v+1.f : __expf(v);
        }
        if (nt < 6){
            float* dp = qo + (row0 + w*16 + lh*4)*C_ + colg;
            #pragma unroll
            for (int j=0;j<4;j++) dp[(size_t)j*C_] = vv[j];
        } else {
            int ck = colg - 96;
            atomicAdd(&kmsum[ck], vv[0]+vv[1]+vv[2]+vv[3]);
            float pv[4];
            #pragma unroll
            for (int j=0;j<4;j++) pv[j] = __shfl_xor(vv[j], 1);
            int p = ck >> 1;
            #pragma unroll
            for (int j=0;j<4;j++){
                int rl = l0 + w*16 + lh*4 + j;
                int hp = rl>>7, wp = rl&127;
                float2 cssn = (p<24)? ctab[hp*24+p] : ctab[wp*24+(p-24)];
                float kr = (ck&1)? (pv[j]*cssn.y + vv[j]*cssn.x)
                                 : (vv[j]*cssn.x - pv[j]*cssn.y);
                KR[(w*16+lh*4+j)*105 + ck] = kr;
            }
        }
    }
    __syncthreads();
    // phase 2: kv[h] = KR^T (16x64) @ V (64x16) via MFMA, 2 waves x 3 heads
    if (w < 2){
        #pragma unroll
        for (int hh=0; hh<3; hh++){
            int h = w*3 + hh;
            f32x4 acc = {0.f,0.f,0.f,0.f};
            #pragma unroll
            for (int kk=0; kk<2; kk++){
                union { bf16x8 v; unsigned short u[8]; } afu, bfu;
                #pragma unroll
                for (int j=0;j<8;j++){
                    int rr = kk*32 + lh*8 + j;
                    afu.u[j] = f2bf(KR[rr*105 + h*16 + lr]);
                    bfu.u[j] = A[rr*128 + ((h*16+lr) ^ ((rr&7)<<3))];
                }
                acc = MFMA16(afu.v, bfu.v, acc);
            }
            #pragma unroll
            for (int i=0;i<4;i++)
                atomicAdd(&kvacc[b*1536 + h*256 + (lh*4+i)*16 + lr], acc[i]);
        }
    }
    if (t < 96) atomicAdd(&kvacc[3072 + b*96 + t], kmsum[t]);
}

// ---------------- K5: attention output, 4 channels/thread, float4 ----------------
__global__ __launch_bounds__(384) void k_attnout(const float* __restrict__ qbuf,
    const float* __restrict__ vbuf, const float* __restrict__ kvacc,
    const float2* __restrict__ ctab, const float* __restrict__ lw9,
    const float* __restrict__ lb, float* __restrict__ aout)
{
    __shared__ float kvs[1536];
    __shared__ float kms[96];
    int t = threadIdx.x;
    size_t row0 = (size_t)blockIdx.x * 16;
    int b = (int)(row0 >> 14);
    const float invL = 1.f/16384.f;
    for (int i=t; i<1536; i+=384) kvs[i] = kvacc[b*1536+i]*invL;
    if (t < 96) kms[t] = kvacc[3072+b*96+t]*invL;
    __syncthreads();
    int r = t/24, c4 = t%24;
    int c = c4*4;
    int lrow = (int)(row0 & 16383) + r;
    int hp = lrow>>7, wp = lrow&127;
    size_t row = row0 + r;
    float4 q4 = *(const float4*)&qbuf[row*C_ + c];
    int p0 = c>>1, p1 = p0+1;
    float2 cs0 = (p0<24)? ctab[hp*24+p0] : ctab[wp*24+(p0-24)];
    float2 cs1 = (p1<24)? ctab[hp*24+p1] : ctab[wp*24+(p1-24)];
    float4 qr;
    qr.x = q4.x*cs0.x - q4.y*cs0.y;
    qr.y = q4.x*cs0.y + q4.y*cs0.x;
    qr.z = q4.z*cs1.x - q4.w*cs1.y;
    qr.w = q4.z*cs1.y + q4.w*cs1.x;
    int h = c4>>2, j = c4&3;
    int dbase = j*4;
    float zp = q4.x*kms[h*16+dbase]   + q4.y*kms[h*16+dbase+1]
             + q4.z*kms[h*16+dbase+2] + q4.w*kms[h*16+dbase+3];
    zp += __shfl_xor(zp,1);
    zp += __shfl_xor(zp,2);
    float zd = 1.f/(zp + 1e-6f);
    float4 o = {0.f,0.f,0.f,0.f};
    #pragma unroll
    for (int g=0; g<4; g++){
        float4 qg;
        if (g==0) qg = qr;
        else {
            qg.x=__shfl_xor(qr.x,g); qg.y=__shfl_xor(qr.y,g);
            qg.z=__shfl_xor(qr.z,g); qg.w=__shfl_xor(qr.w,g);
        }
        int db = ((j^g)<<2);
        const float* kp = &kvs[h*256 + db*16 + j*4];
        #pragma unroll
        for (int i=0;i<4;i++){
            float qi = (i==0)?qg.x:(i==1)?qg.y:(i==2)?qg.z:qg.w;
            float4 kv4 = *(const float4*)&kp[i*16];
            o.x += qi*kv4.x; o.y += qi*kv4.y;
            o.z += qi*kv4.z; o.w += qi*kv4.w;
        }
    }
    float4 acc = *(const float4*)&lb[c];
    #pragma unroll
    for (int kh=0; kh<3; kh++){
        int hh = hp + kh - 1;
        if ((unsigned)hh < 128u){
            int base_row = (b<<14) + (hh<<7);
            #pragma unroll
            for (int kw=0; kw<3; kw++){
                int wq = wp + kw - 1;
                if ((unsigned)wq < 128u){
                    float4 v = *(const float4*)&vbuf[(size_t)(base_row + wq)*C_ + c];
                    float4 wt = *(const float4*)&lw9[(kh*3+kw)*96 + c];
                    acc.x += v.x*wt.x; acc.y += v.y*wt.y;
                    acc.z += v.z*wt.z; acc.w += v.w*wt.w;
                }
            }
        }
    }
    float4 res;
    res.x = o.x*zd + acc.x; res.y = o.y*zd + acc.y;
    res.z = o.z*zd + acc.z; res.w = o.w*zd + acc.w;
    *(float4*)&aout[row*C_ + c] = res;
}

// ---------------- K6a: scan pass1 — per-chunk aggregates, 4 states/thread ----------------
__global__ __launch_bounds__(384) void k_scan1(const float* __restrict__ delta,
    const float* __restrict__ xs, const float* __restrict__ BC,
    const float* __restrict__ A_log, float* __restrict__ Ap, float* __restrict__ Be)
{
    int t = threadIdx.x; int nq = t&3, c = t>>2;
    int blk = blockIdx.x; int b = blk>>8, ch = blk&255;
    float4 a4 = *(const float4*)&A_log[c*16 + nq*4];
    float a0=-__expf(a4.x), a1=-__expf(a4.y), a2=-__expf(a4.z), a3=-__expf(a4.w);
    float ap0=1.f,ap1=1.f,ap2=1.f,ap3=1.f;
    float be0=0.f,be1=0.f,be2=0.f,be3=0.f;
    size_t base = ((size_t)b<<14) + ch*CHL_;
    for (int i=0;i<CHL_;i++){
        size_t row = base + i;
        float dl = delta[row*C_+c];
        float u  = xs[row*C_+c];
        float du = dl*u;
        float4 bc = *(const float4*)&BC[row*32 + nq*4];
        float e0=__expf(dl*a0), e1=__expf(dl*a1), e2=__expf(dl*a2), e3=__expf(dl*a3);
        ap0*=e0; be0=be0*e0+du*bc.x;
        ap1*=e1; be1=be1*e1+du*bc.y;
        ap2*=e2; be2=be2*e2+du*bc.z;
        ap3*=e3; be3=be3*e3+du*bc.w;
    }
    size_t o = (size_t)blk*1536 + c*16 + nq*4;
    float4 apv={ap0,ap1,ap2,ap3}, bev={be0,be1,be2,be3};
    *(float4*)&Ap[o] = apv;
    *(float4*)&Be[o] = bev;
}

// ---------------- K6b: group aggregates (16 chunks/group) ----------------
__global__ __launch_bounds__(384) void k_scan2a(const float* __restrict__ Ap,
    const float* __restrict__ Be, float* __restrict__ GA, float* __restrict__ GB)
{
    int t = threadIdx.x; int blk = blockIdx.x;  // B*16
    int b = blk>>4, g = blk&15;
    int idx = (t>>2)*16 + (t&3)*4;
    float4 A = {1.f,1.f,1.f,1.f}, Bv = {0.f,0.f,0.f,0.f};
    for (int j=0;j<16;j++){
        size_t o = ((size_t)(b*256 + g*16 + j))*1536 + idx;
        float4 a = *(const float4*)&Ap[o];
        float4 bb = *(const float4*)&Be[o];
        Bv.x=a.x*Bv.x+bb.x; Bv.y=a.y*Bv.y+bb.y; Bv.z=a.z*Bv.z+bb.z; Bv.w=a.w*Bv.w+bb.w;
        A.x*=a.x; A.y*=a.y; A.z*=a.z; A.w*=a.w;
    }
    size_t o = (size_t)blk*1536 + idx;
    *(float4*)&GA[o] = A;
    *(float4*)&GB[o] = Bv;
}

// ---------------- K6c: sequential over 16 groups ----------------
__global__ __launch_bounds__(256) void k_scan2b(const float* __restrict__ GA,
    const float* __restrict__ GB, float* __restrict__ Gin)
{
    int t = blockIdx.x*256 + threadIdx.x;  // 3072
    int b = t/1536, m = t%1536;
    float h = 0.f;
    for (int g=0; g<16; g++){
        size_t o = ((size_t)(b*16+g))*1536 + m;
        Gin[o] = h;
        h = GA[o]*h + GB[o];
    }
}

// ---------------- K6d: within-group chunk-incoming states ----------------
__global__ __launch_bounds__(384) void k_scan2c(const float* __restrict__ Ap,
    const float* __restrict__ Be, const float* __restrict__ Gin,
    float* __restrict__ Hin)
{
    int t = threadIdx.x; int blk = blockIdx.x;  // B*16
    int b = blk>>4, g = blk&15;
    int idx = (t>>2)*16 + (t&3)*4;
    float4 h = *(const float4*)&Gin[(size_t)blk*1536 + idx];
    for (int j=0;j<16;j++){
        size_t o = ((size_t)(b*256 + g*16 + j))*1536 + idx;
        *(float4*)&Hin[o] = h;
        float4 a = *(const float4*)&Ap[o];
        float4 bb = *(const float4*)&Be[o];
        h.x=a.x*h.x+bb.x; h.y=a.y*h.y+bb.y; h.z=a.z*h.z+bb.z; h.w=a.w*h.w+bb.w;
    }
}

// ---------------- K6e: scan pass3 — replay + emit y ----------------
__global__ __launch_bounds__(384) void k_scan3(const float* __restrict__ delta,
    const float* __restrict__ xs, const float* __restrict__ BC,
    const float* __restrict__ A_log, const float* __restrict__ Dv,
    const float* __restrict__ Hin, float* __restrict__ y)
{
    int t = threadIdx.x; int nq = t&3, c = t>>2;
    int blk = blockIdx.x; int b = blk>>8, ch = blk&255;
    float4 a4 = *(const float4*)&A_log[c*16 + nq*4];
    float a0=-__expf(a4.x), a1=-__expf(a4.y), a2=-__expf(a4.z), a3=-__expf(a4.w);
    float4 h = *(const float4*)&Hin[(size_t)blk*1536 + c*16 + nq*4];
    float Dc = Dv[c];
    size_t base = ((size_t)b<<14) + ch*CHL_;
    for (int i=0;i<CHL_;i++){
        size_t row = base + i;
        float dl = delta[row*C_+c];
        float u  = xs[row*C_+c];
        float du = dl*u;
        float4 bcB = *(const float4*)&BC[row*32 + nq*4];
        float4 bcC = *(const float4*)&BC[row*32 + 16 + nq*4];
        float e0=__expf(dl*a0), e1=__expf(dl*a1), e2=__expf(dl*a2), e3=__expf(dl*a3);
        h.x=h.x*e0+du*bcB.x; h.y=h.y*e1+du*bcB.y;
        h.z=h.z*e2+du*bcB.z; h.w=h.w*e3+du*bcB.w;
        float yv = h.x*bcC.x + h.y*bcC.y + h.z*bcC.z + h.w*bcC.w;
        yv += __shfl_xor(yv,1);
        yv += __shfl_xor(yv,2);
        if (nq == 0) y[row*C_+c] = yv + Dc*u;
    }
}

// ---------------- K7: combine (3 chained GEMMs) MFMA ----------------
__global__ __launch_bounds__(256) void k_combine_m(const float* __restrict__ y,
    const float* __restrict__ zs, const float* __restrict__ aout,
    const unsigned short* __restrict__ wbf, const float* __restrict__ pob,
    const float* __restrict__ outb, const float* __restrict__ hs,
    float* __restrict__ outr)
{
    __shared__ unsigned short Y[64*192];
    __shared__ unsigned short AZ[64*128];
    __shared__ unsigned short C2[64*192];
    int t=threadIdx.x;
    size_t row0=(size_t)blockIdx.x*64;
    for (int p=t;p<64*48;p+=256){
        int r=p/48, c=(p-r*48)*2;
        size_t g=(row0+r)*C_+c;
        float2 yv=*(const float2*)&y[g];
        float2 zv=*(const float2*)&zs[g];
        float2 av=*(const float2*)&aout[g];
        int sw=(r&7)<<3;
        *(unsigned*)&Y[r*192 + (c^sw)] = pack2(yv.x,yv.y);
        *(unsigned*)&Y[r*192 + ((96+c)^sw)] = pack2(zv.x,zv.y);
        *(unsigned*)&AZ[r*128 + (c^sw)] = pack2(av.x*zv.x, av.y*zv.y);
    }
    __syncthreads();
    int w=t>>6,l=t&63,lr=l&15,lh=l>>4;
    int arow=w*16+lr; int asw=(arow&7)<<3;
    bf16x8 af1[6], af2[3];
    #pragma unroll
    for (int kf=0;kf<6;kf++) af1[kf]=*(const bf16x8*)&Y[arow*192 + ((kf*32+lh*8)^asw)];
    #pragma unroll
    for (int kf=0;kf<3;kf++) af2[kf]=*(const bf16x8*)&AZ[arow*128 + ((kf*32+lh*8)^asw)];
    #pragma unroll 2
    for (int nt=0;nt<6;nt++){
        f32x4 a1={0.f,0.f,0.f,0.f}, a2={0.f,0.f,0.f,0.f};
        #pragma unroll
        for (int kf=0;kf<6;kf++){
            bf16x8 b=*(const bf16x8*)(wbf+((size_t)((WOFF3+kf*6+nt)*64+l))*8);
            a1=MFMA16(af1[kf],b,a1);
        }
        #pragma unroll
        for (int kf=0;kf<3;kf++){
            bf16x8 b=*(const bf16x8*)(wbf+((size_t)((WOFF4+kf*6+nt)*64+l))*8);
            a2=MFMA16(af2[kf],b,a2);
        }
        int col=nt*16+lr;
        float pb=pob[col];
        #pragma unroll
        for (int j=0;j<4;j++){
            int row=w*16+lh*4+j;
            int sw2=(row&7)<<3;
            C2[row*192 + (col^sw2)] = f2bf(a1[j]);
            C2[row*192 + ((96+col)^sw2)] = f2bf(a2[j]+pb);
        }
    }
    __syncthreads();
    bf16x8 af3[6];
    #pragma unroll
    for (int kf=0;kf<6;kf++) af3[kf]=*(const bf16x8*)&C2[arow*192 + ((kf*32+lh*8)^asw)];
    #pragma unroll 2
    for (int nt=0;nt<6;nt++){
        f32x4 acc={0.f,0.f,0.f,0.f};
        #pragma unroll
        for (int kf=0;kf<6;kf++){
            bf16x8 b=*(const bf16x8*)(wbf+((size_t)((WOFF5+kf*6+nt)*64+l))*8);
            acc=MFMA16(af3[kf],b,acc);
        }
        int col=nt*16+lr;
        float ob=outb[col];
        #pragma unroll
        for (int j=0;j<4;j++){
            size_t row=row0+w*16+lh*4+j;
            outr[row*C_+col] = acc[j] + ob + hs[row*C_+col];
        }
    }
}

// ---------------- K8: MLP (LN + fc1 + gelu + fc2 + residual) MFMA ----------------
__global__ __launch_bounds__(256) void k_mlp_m(float* __restrict__ outr,
    const float* __restrict__ gg, const float* __restrict__ bb,
    const unsigned short* __restrict__ wbf,
    const float* __restrict__ f1b, const float* __restrict__ f2b)
{
    __shared__ unsigned short A[64*128];
    __shared__ unsigned short HID[64*384];
    int t=threadIdx.x;
    size_t row0=(size_t)blockIdx.x*64;
    {
        int r=t>>2, q=t&3;
        const float* src = outr + (row0+r)*C_ + q*24;
        float v[24]; float s=0.f,s2=0.f;
        #pragma unroll
        for(int i=0;i<24;i++){float x=src[i];v[i]=x;s+=x;s2+=x*x;}
        s+=__shfl_xor(s,1); s2+=__shfl_xor(s2,1);
        s+=__shfl_xor(s,2); s2+=__shfl_xor(s2,2);
        float mn=s*(1.f/C_), rs=rsqrtf(s2*(1.f/C_)-mn*mn+1e-5f);
        int base=r*128, sw=(r&7)<<3;
        #pragma unroll
        for(int i=0;i<24;i+=2){
            int c=q*24+i;
            *(unsigned*)&A[base+(c^sw)] = pack2((v[i]  -mn)*rs*gg[c]  +bb[c],
                                               (v[i+1]-mn)*rs*gg[c+1]+bb[c+1]);
        }
    }
    __syncthreads();
    int w=t>>6,l=t&63,lr=l&15,lh=l>>4;
    int arow=w*16+lr, asw=(arow&7)<<3;
    {
        bf16x8 af[3];
        #pragma unroll
        for(int kf=0;kf<3;kf++) af[kf]=*(const bf16x8*)&A[arow*128+((kf*32+lh*8)^asw)];
        #pragma unroll 2
        for(int nt=0;nt<24;nt++){
            f32x4 acc={0.f,0.f,0.f,0.f};
            #pragma unroll
            for(int kf=0;kf<3;kf++){
                bf16x8 b=*(const bf16x8*)(wbf+((size_t)((WOFF6+kf*24+nt)*64+l))*8);
                acc=MFMA16(af[kf],b,acc);
            }
            int col=nt*16+lr;
            float bias=f1b[col];
            #pragma unroll
            for(int j=0;j<4;j++){
                int row=w*16+lh*4+j;
                float x=acc[j]+bias;
                float g=0.5f*x*(1.f+erff(x*0.70710678f));
                HID[row*384 + (col^((row&7)<<3))] = f2bf(g);
            }
        }
    }
    __syncthreads();
    {
        bf16x8 af2[12];
        #pragma unroll
        for(int kf=0;kf<12;kf++) af2[kf]=*(const bf16x8*)&HID[arow*384+((kf*32+lh*8)^asw)];
        #pragma unroll 2
        for(int nt=0;nt<6;nt++){
            f32x4 acc={0.f,0.f,0.f,0.f};
            #pragma unroll
            for(int kf=0;kf<12;kf++){
                bf16x8 b=*(const bf16x8*)(wbf+((size_t)((WOFF7+kf*6+nt)*64+l))*8);
                acc=MFMA16(af2[kf],b,acc);
            }
            int col=nt*16+lr;
            float bias=f2b[col];
            #pragma unroll
            for(int j=0;j<4;j++){
                size_t row=row0+w*16+lh*4+j;
                outr[row*C_+col] += acc[j]+bias;
            }
        }
    }
}

extern "C" void kernel_launch(void* const* d_in, const int* in_sizes, int n_in,
                              void* d_out, int out_size, void* d_ws, size_t ws_size,
                              hipStream_t stream)
{
    const float* hs        = (const float*)d_in[0];
    const float* norm_in_g = (const float*)d_in[1];
    const float* norm_in_b = (const float*)d_in[2];
    const float* in_proj_w = (const float*)d_in[3];
    const float* dw_w      = (const float*)d_in[4];
    const float* dw_b      = (const float*)d_in[5];
    const float* qk_w      = (const float*)d_in[6];
    const float* qk_b      = (const float*)d_in[7];
    const float* lepe_w    = (const float*)d_in[8];
    const float* lepe_b    = (const float*)d_in[9];
    const float* conv_x_w  = (const float*)d_in[10];
    const float* conv_z_w  = (const float*)d_in[11];
    const float* x_proj_w  = (const float*)d_in[12];
    const float* dt_proj_w = (const float*)d_in[13];
    const float* dt_proj_b = (const float*)d_in[14];
    const float* A_log     = (const float*)d_in[15];
    const float* Dv        = (const float*)d_in[16];
    const float* out_proj_w= (const float*)d_in[17];
    const float* proj_out_w= (const float*)d_in[18];
    const float* proj_out_b= (const float*)d_in[19];
    const float* out_w     = (const float*)d_in[20];
    const float* out_b     = (const float*)d_in[21];
    const float* norm_mlp_g= (const float*)d_in[22];
    const float* norm_mlp_b= (const float*)d_in[23];
    const float* fc1_w     = (const float*)d_in[24];
    const float* fc1_b     = (const float*)d_in[25];
    const float* fc2_w     = (const float*)d_in[26];
    const float* fc2_b     = (const float*)d_in[27];

    float* ws = (float*)d_ws;
    size_t o = 0;
    float* xx    = ws + o; o += (size_t)BL_*C_;   // -> qbuf after conv1d_xdbl
    float* zz    = ws + o; o += (size_t)BL_*C_;   // -> ybuf after conv1d_xdbl
    float* wwb   = ws + o; o += (size_t)BL_*C_;   // -> aout after dwconv2d
    float* lin_x = ws + o; o += (size_t)BL_*C_;
    float* xs    = ws + o; o += (size_t)BL_*C_;
    float* zs    = ws + o; o += (size_t)BL_*C_;
    float* delta = ws + o; o += (size_t)BL_*C_;
    float* BC    = ws + o; o += (size_t)BL_*32;
    float* Ap    = ws + o; o += (size_t)B_*NCH_*1536;
    float* Be    = ws + o; o += (size_t)B_*NCH_*1536;
    float* Hin   = ws + o; o += (size_t)B_*NCH_*1536;
    float* GA    = ws + o; o += (size_t)B_*16*1536;
    float* GB    = ws + o; o += (size_t)B_*16*1536;
    float* Gin   = ws + o; o += (size_t)B_*16*1536;
    float* kvacc = ws + o; o += 3264;
    float2* ctab = (float2*)(ws + o); o += 6144;
    float* wt9   = ws + o; o += 864;
    float* lw9   = ws + o; o += 864;
    float* wxT   = ws + o; o += 384;
    float* wzT   = ws + o; o += 384;
    unsigned short* wbf = (unsigned short*)(ws + o);

    float* qbuf = xx;
    float* ybuf = zz;
    float* aout = wwb;
    float* outr = (float*)d_out;

    k_setup<<<dim3(72,8), 64, 0, stream>>>(in_proj_w, qk_w, out_proj_w, proj_out_w,
                                           out_w, fc1_w, fc2_w, dw_w, lepe_w,
                                           x_proj_w, conv_x_w, conv_z_w,
                                           wbf, ctab, wt9, lw9, kvacc, wxT, wzT);
    k_ln_inproj_m<<<BL_/64, 256, 0, stream>>>(hs, norm_in_g, norm_in_b, wbf, xx, zz, wwb);
    k_dwconv2d<<<(BL_*24)/256, 256, 0, stream>>>(wwb, wt9, dw_b, lin_x);
    k_conv1d_xdbl<<<BL_/64, 256, 0, stream>>>(xx, zz, wxT, wzT, wbf,
                                              dt_proj_w, dt_proj_b, xs, zs, delta, BC);
    k_qk_kv<<<BL_/64, 256, 0, stream>>>(lin_x, wbf, qk_b, ctab, qbuf, kvacc);
    k_attnout<<<BL_/16, 384, 0, stream>>>(qbuf, lin_x, kvacc, ctab, lw9, lepe_b, aout);
    k_scan1<<<B_*NCH_, 384, 0, stream>>>(delta, xs, BC, A_log, Ap, Be);
    k_scan2a<<<B_*16, 384, 0, stream>>>(Ap, Be, GA, GB);
    k_scan2b<<<12, 256, 0, stream>>>(GA, GB, Gin);
    k_scan2c<<<B_*16, 384, 0, stream>>>(Ap, Be, Gin, Hin);
    k_scan3<<<B_*NCH_, 384, 0, stream>>>(delta, xs, BC, A_log, Dv, Hin, ybuf);
    k_combine_m<<<BL_/64, 256, 0, stream>>>(ybuf, zs, aout, wbf, proj_out_b,
                                            out_b, hs, outr);
    k_mlp_m<<<BL_/64, 256, 0, stream>>>(outr, norm_mlp_g, norm_mlp_b, wbf,
                                        fc1_b, fc2_b);
}

// Round 6
// 209.077 us; speedup vs baseline: 3.3517x; 1.0703x over previous
//
#include <hip/hip_runtime.h>
#include <hip/hip_bf16.h>
#include <math.h>

#define B_ 2
#define H_ 128
#define W_ 128
#define C_ 96
#define L_ (H_*W_)
#define BL_ (B_*L_)
#define NH_ 6
#define NPROJ_ 38
#define MLPH_ 384
#define NCH_ 512
#define CHL_ (L_/NCH_)
#define NG_ 32

typedef __attribute__((ext_vector_type(8))) short bf16x8;
typedef __attribute__((ext_vector_type(4))) float f32x4;

#define MFMA16(a,b,c) __builtin_amdgcn_mfma_f32_16x16x32_bf16(a,b,c,0,0,0)

// weight fragment table (each frag = 64 lanes * 8 bf16 = 512 elems)
#define WOFF1 0      // in_proj  96x288 : 3*18 = 54
#define WOFF2 54     // qk_w     96x192 : 3*12 = 36
#define WOFF3 90     // out_proj 192x96 : 6*6  = 36
#define WOFF4 126    // proj_out 96x96  : 3*6  = 18
#define WOFF5 144    // out_w    192x96 : 6*6  = 36
#define WOFF6 180    // fc1      96x384 : 3*24 = 72
#define WOFF7 252    // fc2      384x96 : 12*6 = 72
#define WOFF8 324    // x_proj   96x38(->48 pad) : 3*3 = 9
#define WFRAGS 333

__device__ __forceinline__ float siluf(float x){ return x / (1.f + __expf(-x)); }
__device__ __forceinline__ unsigned short f2bf(float x){
    __hip_bfloat16 h = __float2bfloat16(x);
    return *reinterpret_cast<unsigned short*>(&h);
}
__device__ __forceinline__ unsigned pack2(float a, float b){
    return (unsigned)f2bf(a) | ((unsigned)f2bf(b) << 16);
}
__device__ __forceinline__ float bf2f(unsigned short u){
    return __uint_as_float((unsigned)u << 16);
}
__device__ __forceinline__ float gelu_fast(float x){
    float u_ = 0.7978845608f*x*(1.f + 0.044715f*x*x);
    float au = fabsf(u_);
    float e = __expf(-2.f*au);
    float th = (1.f - e)/(1.f + e);
    th = copysignf(th, u_);
    return 0.5f*x*(1.f + th);
}

// ---------------- K0: setup — weight prep + rope table + misc transposes ----------------
__global__ __launch_bounds__(64) void k_setup(const float* __restrict__ w1,
    const float* __restrict__ w2, const float* __restrict__ w3,
    const float* __restrict__ w4, const float* __restrict__ w5,
    const float* __restrict__ w6, const float* __restrict__ w7,
    const float* __restrict__ dww, const float* __restrict__ lw,
    const float* __restrict__ xpw, const float* __restrict__ cxw,
    const float* __restrict__ czw,
    unsigned short* __restrict__ dst, float2* __restrict__ ctab,
    float* __restrict__ wt9, float* __restrict__ lw9, float* __restrict__ kvacc,
    float* __restrict__ wxT, float* __restrict__ wzT)
{
    int m = blockIdx.y;
    int l = threadIdx.x;
    if (m < 7){
        const float* srcs[7] = {w1,w2,w3,w4,w5,w6,w7};
        const int Ks[7]   = {96,96,192,96,192,96,384};
        const int Ns[7]   = {288,192,96,96,96,384,96};
        const int offs[7] = {WOFF1,WOFF2,WOFF3,WOFF4,WOFF5,WOFF6,WOFF7};
        int f = blockIdx.x;
        int nnt = Ns[m] >> 4, nkf = Ks[m] >> 5;
        if (f >= nnt*nkf) return;
        int kf = f / nnt, nt = f - kf*nnt;
        const float* s = srcs[m];
        unsigned short* d = dst + ((size_t)(offs[m] + f)*64 + l)*8;
        int krow = kf*32 + (l>>4)*8;
        int col  = nt*16 + (l&15);
        #pragma unroll
        for (int j=0;j<8;j++) d[j] = f2bf(s[(size_t)(krow+j)*Ns[m] + col]);
    } else {
        int x = blockIdx.x;
        if (x == 0){
            for (int i=l; i<128*24; i+=64){
                int pos = i/24, p = i%24;
                float th = powf(10000.f, -(float)p/24.f);
                float sn, cs; sincosf((float)pos*th, &sn, &cs);
                ctab[i] = make_float2(cs, sn);
            }
        } else if (x == 1){
            for (int i=l; i<3264; i+=64) kvacc[i] = 0.f;
        } else if (x == 2){
            for (int i=l; i<864; i+=64){
                int c = i/9, tap = i%9;
                wt9[tap*96 + c] = dww[i];
                lw9[tap*96 + c] = lw[i];
            }
        } else if (x == 3){
            for (int f=0; f<9; f++){
                int kf=f/3, nt=f%3;
                unsigned short* d = dst + ((size_t)(WOFF8 + f)*64 + l)*8;
                int krow = kf*32 + (l>>4)*8;
                int col  = nt*16 + (l&15);
                #pragma unroll
                for (int j=0;j<8;j++){
                    float v = (col < NPROJ_) ? xpw[(size_t)(krow+j)*NPROJ_ + col] : 0.f;
                    d[j] = f2bf(v);
                }
            }
        } else if (x == 4){
            for (int i=l; i<384; i+=64){
                int j = i/96, c = i%96;
                wxT[i] = cxw[c*4 + j];
                wzT[i] = czw[c*4 + j];
            }
        }
    }
}

// ---------------- K1: LayerNorm + in_proj (96 -> 288) MFMA, split outputs ----------------
__global__ __launch_bounds__(256) void k_ln_inproj_m(const float* __restrict__ hs,
    const float* __restrict__ gg, const float* __restrict__ bb,
    const unsigned short* __restrict__ wbf,
    float* __restrict__ xx, float* __restrict__ zz, float* __restrict__ ww)
{
    __shared__ unsigned short A[64*128];
    int t = threadIdx.x;
    size_t row0 = (size_t)blockIdx.x * 64;
    {
        int r = t >> 2, q = t & 3;
        const float* src = hs + (row0 + r)*C_ + q*24;
        float v[24];
        float s=0.f, s2=0.f;
        #pragma unroll
        for (int i=0;i<24;i++){ float x=src[i]; v[i]=x; s+=x; s2+=x*x; }
        s += __shfl_xor(s,1); s2 += __shfl_xor(s2,1);
        s += __shfl_xor(s,2); s2 += __shfl_xor(s2,2);
        float mn = s*(1.f/C_);
        float rs = rsqrtf(s2*(1.f/C_) - mn*mn + 1e-5f);
        int base = r*128, sw = (r&7)<<3;
        #pragma unroll
        for (int i=0;i<24;i+=2){
            int c = q*24 + i;
            float a0 = (v[i]  -mn)*rs*gg[c]   + bb[c];
            float a1 = (v[i+1]-mn)*rs*gg[c+1] + bb[c+1];
            *(unsigned*)&A[base + (c ^ sw)] = pack2(a0,a1);
        }
    }
    __syncthreads();
    int w = t>>6, l = t&63, lr = l&15, lh = l>>4;
    int arow = w*16 + lr;
    int abase = arow*128, asw = (arow&7)<<3;
    bf16x8 af[3];
    #pragma unroll
    for (int kf=0;kf<3;kf++)
        af[kf] = *(const bf16x8*)&A[abase + ((kf*32 + lh*8) ^ asw)];
    #pragma unroll 2
    for (int nt=0; nt<18; nt++){
        f32x4 acc = {0.f,0.f,0.f,0.f};
        #pragma unroll
        for (int kf=0;kf<3;kf++){
            bf16x8 bf_ = *(const bf16x8*)(wbf + ((size_t)((WOFF1 + kf*18 + nt)*64 + l))*8);
            acc = MFMA16(af[kf], bf_, acc);
        }
        float* base_;
        if (nt < 6) base_ = xx; else if (nt < 12) base_ = zz; else base_ = ww;
        int col = (nt%6)*16 + lr;
        float* dst = base_ + (row0 + w*16 + lh*4)*C_ + col;
        #pragma unroll
        for (int j=0;j<4;j++) dst[(size_t)j*C_] = acc[j];
    }
}

// ---------------- K2: depthwise 3x3 conv + silu on ww, float4 ----------------
__global__ __launch_bounds__(256) void k_dwconv2d(const float* __restrict__ wwb,
    const float* __restrict__ wt9, const float* __restrict__ dwb,
    float* __restrict__ out)
{
    int gid = blockIdx.x*256 + threadIdx.x;   // BL*24
    int row = gid/24, c4 = gid%24; int c = c4*4;
    int b = row >> 14;
    int ll = row & (L_-1);
    int h = ll >> 7, wq = ll & 127;
    float4 acc = {0.f,0.f,0.f,0.f};
    #pragma unroll
    for (int kh=0; kh<3; kh++){
        int hh = h + kh - 1;
        if ((unsigned)hh < 128u){
            int base_row = (b<<14) + (hh<<7);
            #pragma unroll
            for (int kw=0; kw<3; kw++){
                int wp = wq + kw - 1;
                if ((unsigned)wp < 128u){
                    float4 v = *(const float4*)&wwb[(size_t)(base_row + wp)*C_ + c];
                    float4 wt = *(const float4*)&wt9[(kh*3+kw)*96 + c];
                    acc.x += v.x*wt.x; acc.y += v.y*wt.y;
                    acc.z += v.z*wt.z; acc.w += v.w*wt.w;
                }
            }
        }
    }
    float4 bv = *(const float4*)&dwb[c];
    float4 o;
    o.x = siluf(acc.x+bv.x); o.y = siluf(acc.y+bv.y);
    o.z = siluf(acc.z+bv.z); o.w = siluf(acc.w+bv.w);
    *(float4*)&out[(size_t)row*C_ + c] = o;
}

// ---------------- K3: conv1d+silu (float4) + x_proj MFMA + dt_proj/softplus ----------------
__global__ __launch_bounds__(256) void k_conv1d_xdbl(const float* __restrict__ xxb,
    const float* __restrict__ zzb, const float* __restrict__ wxT,
    const float* __restrict__ wzT, const unsigned short* __restrict__ wbf,
    const float* __restrict__ dtw, const float* __restrict__ dtb,
    float* __restrict__ xs, float* __restrict__ zs,
    float* __restrict__ delta, float* __restrict__ BC)
{
    __shared__ unsigned short A[64*128];   // silu(conv1d(x)) bf16, swizzled A-tile
    __shared__ float XD[64][8];            // dt part of x_dbl (cols 0..5)
    __shared__ float dtws[6][96];
    int t = threadIdx.x;
    size_t row0 = (size_t)blockIdx.x * 64;
    int b = (int)(row0 >> 14);
    int l0 = (int)(row0 & 16383);
    for (int i=t; i<576; i+=256) dtws[i/96][i%96] = dtw[i];
    for (int p=t; p<64*24; p+=256){
        int r = p/24, cq = p - r*24, c = cq*4;
        int l = l0 + r;
        float ax0=0.f,ax1=0.f,ax2=0.f,ax3=0.f;
        float az0=0.f,az1=0.f,az2=0.f,az3=0.f;
        #pragma unroll
        for (int j=0;j<4;j++){
            int lq = l - 1 + j;
            if ((unsigned)lq < (unsigned)L_){
                size_t off = ((size_t)(b<<14) + lq)*C_ + c;
                float4 xv = *(const float4*)&xxb[off];
                float4 zv = *(const float4*)&zzb[off];
                float4 wx4 = *(const float4*)&wxT[j*96 + c];
                float4 wz4 = *(const float4*)&wzT[j*96 + c];
                ax0 += xv.x*wx4.x; ax1 += xv.y*wx4.y; ax2 += xv.z*wx4.z; ax3 += xv.w*wx4.w;
                az0 += zv.x*wz4.x; az1 += zv.y*wz4.y; az2 += zv.z*wz4.z; az3 += zv.w*wz4.w;
            }
        }
        ax0=siluf(ax0); ax1=siluf(ax1); ax2=siluf(ax2); ax3=siluf(ax3);
        az0=siluf(az0); az1=siluf(az1); az2=siluf(az2); az3=siluf(az3);
        float4 xo={ax0,ax1,ax2,ax3}, zo={az0,az1,az2,az3};
        *(float4*)&xs[(row0+r)*C_ + c] = xo;
        *(float4*)&zs[(row0+r)*C_ + c] = zo;
        int sw = (r&7)<<3;
        uint2 pk = { pack2(ax0,ax1), pack2(ax2,ax3) };
        *(uint2*)&A[r*128 + (c ^ sw)] = pk;
    }
    __syncthreads();
    int w=t>>6, l=t&63, lr=l&15, lh=l>>4;
    int arow = w*16+lr, asw=(arow&7)<<3;
    bf16x8 af[3];
    #pragma unroll
    for (int kf=0;kf<3;kf++)
        af[kf] = *(const bf16x8*)&A[arow*128 + ((kf*32 + lh*8) ^ asw)];
    #pragma unroll
    for (int nt=0; nt<3; nt++){
        f32x4 acc={0.f,0.f,0.f,0.f};
        #pragma unroll
        for (int kf=0;kf<3;kf++){
            bf16x8 bfr=*(const bf16x8*)(wbf + ((size_t)((WOFF8 + kf*3 + nt)*64 + l))*8);
            acc = MFMA16(af[kf], bfr, acc);
        }
        int col = nt*16 + lr;
        #pragma unroll
        for (int j=0;j<4;j++){
            int row = w*16 + lh*4 + j;
            if (col < 6) XD[row][col] = acc[j];
            else if (col < NPROJ_) BC[(row0+row)*32 + (col-6)] = acc[j];
        }
    }
    __syncthreads();
    {
        int r = t>>2, q = t&3;
        float xd0=XD[r][0], xd1=XD[r][1], xd2=XD[r][2];
        float xd3=XD[r][3], xd4=XD[r][4], xd5=XD[r][5];
        #pragma unroll
        for (int g=0; g<6; g++){
            int c = q*24 + g*4;
            float4 acc = *(const float4*)&dtb[c];
            float4 w0 = *(const float4*)&dtws[0][c];
            float4 w1 = *(const float4*)&dtws[1][c];
            float4 w2 = *(const float4*)&dtws[2][c];
            float4 w3 = *(const float4*)&dtws[3][c];
            float4 w4 = *(const float4*)&dtws[4][c];
            float4 w5 = *(const float4*)&dtws[5][c];
            acc.x += xd0*w0.x + xd1*w1.x + xd2*w2.x + xd3*w3.x + xd4*w4.x + xd5*w5.x;
            acc.y += xd0*w0.y + xd1*w1.y + xd2*w2.y + xd3*w3.y + xd4*w4.y + xd5*w5.y;
            acc.z += xd0*w0.z + xd1*w1.z + xd2*w2.z + xd3*w3.z + xd4*w4.z + xd5*w5.z;
            acc.w += xd0*w0.w + xd1*w1.w + xd2*w2.w + xd3*w3.w + xd4*w4.w + xd5*w5.w;
            float4 dl;
            dl.x = (acc.x>20.f)? acc.x : __logf(1.f+__expf(acc.x));
            dl.y = (acc.y>20.f)? acc.y : __logf(1.f+__expf(acc.y));
            dl.z = (acc.z>20.f)? acc.z : __logf(1.f+__expf(acc.z));
            dl.w = (acc.w>20.f)? acc.w : __logf(1.f+__expf(acc.w));
            *(float4*)&delta[(row0+r)*C_ + c] = dl;
        }
    }
}

// ---------------- K4: qk MFMA + elu+1 + rope-k + MFMA kv reduce + kmean ----------------
__global__ __launch_bounds__(256) void k_qk_kv(const float* __restrict__ lin,
    const unsigned short* __restrict__ wbf, const float* __restrict__ qkb,
    const float2* __restrict__ ctab, float* __restrict__ qo,
    float* __restrict__ kvacc)
{
    __shared__ unsigned short A[64*128];
    __shared__ float KR[64*105];
    __shared__ float kmsum[96];
    int t = threadIdx.x;
    size_t row0 = (size_t)blockIdx.x * 64;
    int b = (int)(row0 >> 14);
    int l0 = (int)(row0 & 16383);
    for (int p = t; p < 64*48; p += 256){
        int r = p/48, c = (p - r*48)*2;
        float2 xy = *(const float2*)&lin[(row0 + r)*C_ + c];
        *(unsigned*)&A[r*128 + (c ^ ((r&7)<<3))] = pack2(xy.x, xy.y);
    }
    if (t < 96) kmsum[t] = 0.f;
    __syncthreads();
    int w=t>>6, l=t&63, lr=l&15, lh=l>>4;
    int arow = w*16+lr; int asw=(arow&7)<<3;
    bf16x8 af[3];
    #pragma unroll
    for (int kf=0;kf<3;kf++)
        af[kf] = *(const bf16x8*)&A[arow*128 + ((kf*32 + lh*8) ^ asw)];
    #pragma unroll 2
    for (int nt=0; nt<12; nt++){
        f32x4 acc={0.f,0.f,0.f,0.f};
        #pragma unroll
        for (int kf=0;kf<3;kf++){
            bf16x8 bfr=*(const bf16x8*)(wbf + ((size_t)((WOFF2 + kf*12 + nt)*64 + l))*8);
            acc = MFMA16(af[kf], bfr, acc);
        }
        int colg = nt*16 + lr;
        float bias = qkb[colg];
        float vv[4];
        #pragma unroll
        for (int j=0;j<4;j++){
            float v = acc[j] + bias;
            vv[j] = (v>0.f)? v+1.f : __expf(v);
        }
        if (nt < 6){
            float* dp = qo + (row0 + w*16 + lh*4)*C_ + colg;
            #pragma unroll
            for (int j=0;j<4;j++) dp[(size_t)j*C_] = vv[j];
        } else {
            int ck = colg - 96;
            atomicAdd(&kmsum[ck], vv[0]+vv[1]+vv[2]+vv[3]);
            float pv[4];
            #pragma unroll
            for (int j=0;j<4;j++) pv[j] = __shfl_xor(vv[j], 1);
            int p = ck >> 1;
            #pragma unroll
            for (int j=0;j<4;j++){
                int rl = l0 + w*16 + lh*4 + j;
                int hp = rl>>7, wp = rl&127;
                float2 cssn = (p<24)? ctab[hp*24+p] : ctab[wp*24+(p-24)];
                float kr = (ck&1)? (pv[j]*cssn.y + vv[j]*cssn.x)
                                 : (vv[j]*cssn.x - pv[j]*cssn.y);
                KR[(w*16+lh*4+j)*105 + ck] = kr;
            }
        }
    }
    __syncthreads();
    if (w < 2){
        #pragma unroll
        for (int hh=0; hh<3; hh++){
            int h = w*3 + hh;
            f32x4 acc = {0.f,0.f,0.f,0.f};
            #pragma unroll
            for (int kk=0; kk<2; kk++){
                union { bf16x8 v; unsigned short u[8]; } afu, bfu;
                #pragma unroll
                for (int j=0;j<8;j++){
                    int rr = kk*32 + lh*8 + j;
                    afu.u[j] = f2bf(KR[rr*105 + h*16 + lr]);
                    bfu.u[j] = A[rr*128 + ((h*16+lr) ^ ((rr&7)<<3))];
                }
                acc = MFMA16(afu.v, bfu.v, acc);
            }
            #pragma unroll
            for (int i=0;i<4;i++)
                atomicAdd(&kvacc[b*1536 + h*256 + (lh*4+i)*16 + lr], acc[i]);
        }
    }
    if (t < 96) atomicAdd(&kvacc[3072 + b*96 + t], kmsum[t]);
}

// ---------------- K5: attention output, 4 channels/thread, float4 ----------------
__global__ __launch_bounds__(384) void k_attnout(const float* __restrict__ qbuf,
    const float* __restrict__ vbuf, const float* __restrict__ kvacc,
    const float2* __restrict__ ctab, const float* __restrict__ lw9,
    const float* __restrict__ lb, float* __restrict__ aout)
{
    __shared__ float kvs[1536];
    __shared__ float kms[96];
    int t = threadIdx.x;
    size_t row0 = (size_t)blockIdx.x * 16;
    int b = (int)(row0 >> 14);
    const float invL = 1.f/16384.f;
    for (int i=t; i<1536; i+=384) kvs[i] = kvacc[b*1536+i]*invL;
    if (t < 96) kms[t] = kvacc[3072+b*96+t]*invL;
    __syncthreads();
    int r = t/24, c4 = t%24;
    int c = c4*4;
    int lrow = (int)(row0 & 16383) + r;
    int hp = lrow>>7, wp = lrow&127;
    size_t row = row0 + r;
    float4 q4 = *(const float4*)&qbuf[row*C_ + c];
    int p0 = c>>1, p1 = p0+1;
    float2 cs0 = (p0<24)? ctab[hp*24+p0] : ctab[wp*24+(p0-24)];
    float2 cs1 = (p1<24)? ctab[hp*24+p1] : ctab[wp*24+(p1-24)];
    float4 qr;
    qr.x = q4.x*cs0.x - q4.y*cs0.y;
    qr.y = q4.x*cs0.y + q4.y*cs0.x;
    qr.z = q4.z*cs1.x - q4.w*cs1.y;
    qr.w = q4.z*cs1.y + q4.w*cs1.x;
    int h = c4>>2, j = c4&3;
    int dbase = j*4;
    float zp = q4.x*kms[h*16+dbase]   + q4.y*kms[h*16+dbase+1]
             + q4.z*kms[h*16+dbase+2] + q4.w*kms[h*16+dbase+3];
    zp += __shfl_xor(zp,1);
    zp += __shfl_xor(zp,2);
    float zd = 1.f/(zp + 1e-6f);
    float4 o = {0.f,0.f,0.f,0.f};
    #pragma unroll
    for (int g=0; g<4; g++){
        float4 qg;
        if (g==0) qg = qr;
        else {
            qg.x=__shfl_xor(qr.x,g); qg.y=__shfl_xor(qr.y,g);
            qg.z=__shfl_xor(qr.z,g); qg.w=__shfl_xor(qr.w,g);
        }
        int db = ((j^g)<<2);
        const float* kp = &kvs[h*256 + db*16 + j*4];
        #pragma unroll
        for (int i=0;i<4;i++){
            float qi = (i==0)?qg.x:(i==1)?qg.y:(i==2)?qg.z:qg.w;
            float4 kv4 = *(const float4*)&kp[i*16];
            o.x += qi*kv4.x; o.y += qi*kv4.y;
            o.z += qi*kv4.z; o.w += qi*kv4.w;
        }
    }
    float4 acc = *(const float4*)&lb[c];
    #pragma unroll
    for (int kh=0; kh<3; kh++){
        int hh = hp + kh - 1;
        if ((unsigned)hh < 128u){
            int base_row = (b<<14) + (hh<<7);
            #pragma unroll
            for (int kw=0; kw<3; kw++){
                int wq = wp + kw - 1;
                if ((unsigned)wq < 128u){
                    float4 v = *(const float4*)&vbuf[(size_t)(base_row + wq)*C_ + c];
                    float4 wt = *(const float4*)&lw9[(kh*3+kw)*96 + c];
                    acc.x += v.x*wt.x; acc.y += v.y*wt.y;
                    acc.z += v.z*wt.z; acc.w += v.w*wt.w;
                }
            }
        }
    }
    float4 res;
    res.x = o.x*zd + acc.x; res.y = o.y*zd + acc.y;
    res.z = o.z*zd + acc.z; res.w = o.w*zd + acc.w;
    *(float4*)&aout[row*C_ + c] = res;
}

// ---------------- K6a: scan pass1 — per-chunk aggregates, 4 states/thread ----------------
__global__ __launch_bounds__(384) void k_scan1(const float* __restrict__ delta,
    const float* __restrict__ xs, const float* __restrict__ BC,
    const float* __restrict__ A_log, float* __restrict__ Ap, float* __restrict__ Be)
{
    int t = threadIdx.x; int nq = t&3, c = t>>2;
    int blk = blockIdx.x; int b = blk>>9, ch = blk&(NCH_-1);
    float4 a4 = *(const float4*)&A_log[c*16 + nq*4];
    float a0=-__expf(a4.x), a1=-__expf(a4.y), a2=-__expf(a4.z), a3=-__expf(a4.w);
    float ap0=1.f,ap1=1.f,ap2=1.f,ap3=1.f;
    float be0=0.f,be1=0.f,be2=0.f,be3=0.f;
    size_t base = ((size_t)b<<14) + ch*CHL_;
    for (int i=0;i<CHL_;i++){
        size_t row = base + i;
        float dl = delta[row*C_+c];
        float u  = xs[row*C_+c];
        float du = dl*u;
        float4 bc = *(const float4*)&BC[row*32 + nq*4];
        float e0=__expf(dl*a0), e1=__expf(dl*a1), e2=__expf(dl*a2), e3=__expf(dl*a3);
        ap0*=e0; be0=be0*e0+du*bc.x;
        ap1*=e1; be1=be1*e1+du*bc.y;
        ap2*=e2; be2=be2*e2+du*bc.z;
        ap3*=e3; be3=be3*e3+du*bc.w;
    }
    size_t o = (size_t)blk*1536 + c*16 + nq*4;
    float4 apv={ap0,ap1,ap2,ap3}, bev={be0,be1,be2,be3};
    *(float4*)&Ap[o] = apv;
    *(float4*)&Be[o] = bev;
}

// ---------------- K6b: group aggregates (16 chunks/group) ----------------
__global__ __launch_bounds__(384) void k_scan2a(const float* __restrict__ Ap,
    const float* __restrict__ Be, float* __restrict__ GA, float* __restrict__ GB)
{
    int t = threadIdx.x; int blk = blockIdx.x;  // B*NG
    int b = blk>>5, g = blk&(NG_-1);
    int idx = (t>>2)*16 + (t&3)*4;
    float4 A = {1.f,1.f,1.f,1.f}, Bv = {0.f,0.f,0.f,0.f};
    for (int j=0;j<16;j++){
        size_t o = ((size_t)(b*NCH_ + g*16 + j))*1536 + idx;
        float4 a = *(const float4*)&Ap[o];
        float4 bb = *(const float4*)&Be[o];
        Bv.x=a.x*Bv.x+bb.x; Bv.y=a.y*Bv.y+bb.y; Bv.z=a.z*Bv.z+bb.z; Bv.w=a.w*Bv.w+bb.w;
        A.x*=a.x; A.y*=a.y; A.z*=a.z; A.w*=a.w;
    }
    size_t o = (size_t)blk*1536 + idx;
    *(float4*)&GA[o] = A;
    *(float4*)&GB[o] = Bv;
}

// ---------------- K6c: sequential over NG groups ----------------
__global__ __launch_bounds__(256) void k_scan2b(const float* __restrict__ GA,
    const float* __restrict__ GB, float* __restrict__ Gin)
{
    int t = blockIdx.x*256 + threadIdx.x;  // 3072
    int b = t/1536, m = t%1536;
    float h = 0.f;
    for (int g=0; g<NG_; g++){
        size_t o = ((size_t)(b*NG_+g))*1536 + m;
        Gin[o] = h;
        h = GA[o]*h + GB[o];
    }
}

// ---------------- K6d: within-group chunk-incoming states ----------------
__global__ __launch_bounds__(384) void k_scan2c(const float* __restrict__ Ap,
    const float* __restrict__ Be, const float* __restrict__ Gin,
    float* __restrict__ Hin)
{
    int t = threadIdx.x; int blk = blockIdx.x;  // B*NG
    int b = blk>>5, g = blk&(NG_-1);
    int idx = (t>>2)*16 + (t&3)*4;
    float4 h = *(const float4*)&Gin[(size_t)blk*1536 + idx];
    for (int j=0;j<16;j++){
        size_t o = ((size_t)(b*NCH_ + g*16 + j))*1536 + idx;
        *(float4*)&Hin[o] = h;
        float4 a = *(const float4*)&Ap[o];
        float4 bb = *(const float4*)&Be[o];
        h.x=a.x*h.x+bb.x; h.y=a.y*h.y+bb.y; h.z=a.z*h.z+bb.z; h.w=a.w*h.w+bb.w;
    }
}

// ---------------- K6e: scan pass3 — replay + emit y ----------------
__global__ __launch_bounds__(384) void k_scan3(const float* __restrict__ delta,
    const float* __restrict__ xs, const float* __restrict__ BC,
    const float* __restrict__ A_log, const float* __restrict__ Dv,
    const float* __restrict__ Hin, float* __restrict__ y)
{
    int t = threadIdx.x; int nq = t&3, c = t>>2;
    int blk = blockIdx.x; int b = blk>>9, ch = blk&(NCH_-1);
    float4 a4 = *(const float4*)&A_log[c*16 + nq*4];
    float a0=-__expf(a4.x), a1=-__expf(a4.y), a2=-__expf(a4.z), a3=-__expf(a4.w);
    float4 h = *(const float4*)&Hin[(size_t)blk*1536 + c*16 + nq*4];
    float Dc = Dv[c];
    size_t base = ((size_t)b<<14) + ch*CHL_;
    for (int i=0;i<CHL_;i++){
        size_t row = base + i;
        float dl = delta[row*C_+c];
        float u  = xs[row*C_+c];
        float du = dl*u;
        float4 bcB = *(const float4*)&BC[row*32 + nq*4];
        float4 bcC = *(const float4*)&BC[row*32 + 16 + nq*4];
        float e0=__expf(dl*a0), e1=__expf(dl*a1), e2=__expf(dl*a2), e3=__expf(dl*a3);
        h.x=h.x*e0+du*bcB.x; h.y=h.y*e1+du*bcB.y;
        h.z=h.z*e2+du*bcB.z; h.w=h.w*e3+du*bcB.w;
        float yv = h.x*bcC.x + h.y*bcC.y + h.z*bcC.z + h.w*bcC.w;
        yv += __shfl_xor(yv,1);
        yv += __shfl_xor(yv,2);
        if (nq == 0) y[row*C_+c] = yv + Dc*u;
    }
}

// ---------------- K7: combine (3 chained GEMMs) + LN + MLP, fully fused ----------------
__global__ __launch_bounds__(256) void k_combine_mlp(const float* __restrict__ y,
    const float* __restrict__ zs, const float* __restrict__ aout,
    const unsigned short* __restrict__ wbf, const float* __restrict__ pob,
    const float* __restrict__ outb, const float* __restrict__ hs,
    const float* __restrict__ gg, const float* __restrict__ bb,
    const float* __restrict__ f1b, const float* __restrict__ f2b,
    float* __restrict__ outr)
{
    __shared__ __attribute__((aligned(16))) char POOL[65536];
    unsigned short* Y  = (unsigned short*)POOL;            // 64*192 (24 KB)
    unsigned short* AZ = (unsigned short*)(POOL + 24576);  // 64*128 (16 KB)
    unsigned short* C2 = (unsigned short*)(POOL + 40960);  // 64*192 (24 KB)
    unsigned short* AT = (unsigned short*)POOL;            // 64*128 (16 KB) phase B
    unsigned short* HID= (unsigned short*)(POOL + 16384);  // 64*384 (48 KB) phase B
    int t=threadIdx.x;
    size_t row0=(size_t)blockIdx.x*64;
    for (int p=t;p<64*48;p+=256){
        int r=p/48, c=(p-r*48)*2;
        size_t g=(row0+r)*C_+c;
        float2 yv=*(const float2*)&y[g];
        float2 zv=*(const float2*)&zs[g];
        float2 av=*(const float2*)&aout[g];
        int sw=(r&7)<<3;
        *(unsigned*)&Y[r*192 + (c^sw)] = pack2(yv.x,yv.y);
        *(unsigned*)&Y[r*192 + ((96+c)^sw)] = pack2(zv.x,zv.y);
        *(unsigned*)&AZ[r*128 + (c^sw)] = pack2(av.x*zv.x, av.y*zv.y);
    }
    __syncthreads();
    int w=t>>6,l=t&63,lr=l&15,lh=l>>4;
    int arow=w*16+lr; int asw=(arow&7)<<3;
    bf16x8 af1[6], af2[3];
    #pragma unroll
    for (int kf=0;kf<6;kf++) af1[kf]=*(const bf16x8*)&Y[arow*192 + ((kf*32+lh*8)^asw)];
    #pragma unroll
    for (int kf=0;kf<3;kf++) af2[kf]=*(const bf16x8*)&AZ[arow*128 + ((kf*32+lh*8)^asw)];
    #pragma unroll 2
    for (int nt=0;nt<6;nt++){
        f32x4 a1={0.f,0.f,0.f,0.f}, a2={0.f,0.f,0.f,0.f};
        #pragma unroll
        for (int kf=0;kf<6;kf++){
            bf16x8 b=*(const bf16x8*)(wbf+((size_t)((WOFF3+kf*6+nt)*64+l))*8);
            a1=MFMA16(af1[kf],b,a1);
        }
        #pragma unroll
        for (int kf=0;kf<3;kf++){
            bf16x8 b=*(const bf16x8*)(wbf+((size_t)((WOFF4+kf*6+nt)*64+l))*8);
            a2=MFMA16(af2[kf],b,a2);
        }
        int col=nt*16+lr;
        float pb=pob[col];
        #pragma unroll
        for (int j=0;j<4;j++){
            int row=w*16+lh*4+j;
            int sw2=(row&7)<<3;
            C2[row*192 + (col^sw2)] = f2bf(a1[j]);
            C2[row*192 + ((96+col)^sw2)] = f2bf(a2[j]+pb);
        }
    }
    __syncthreads();
    bf16x8 af3[6];
    #pragma unroll
    for (int kf=0;kf<6;kf++) af3[kf]=*(const bf16x8*)&C2[arow*192 + ((kf*32+lh*8)^asw)];
    // out-stack GEMM + residual, keep 24 outputs in registers
    float outv[6][4];
    #pragma unroll 2
    for (int nt=0;nt<6;nt++){
        f32x4 acc={0.f,0.f,0.f,0.f};
        #pragma unroll
        for (int kf=0;kf<6;kf++){
            bf16x8 b=*(const bf16x8*)(wbf+((size_t)((WOFF5+kf*6+nt)*64+l))*8);
            acc=MFMA16(af3[kf],b,acc);
        }
        int col=nt*16+lr;
        float ob=outb[col];
        #pragma unroll
        for (int j=0;j<4;j++){
            size_t row=row0+w*16+lh*4+j;
            outv[nt][j] = acc[j] + ob + hs[row*C_+col];
        }
    }
    // LayerNorm across the 16-lane lr group (each row's 96 cols live on 16 lanes x 6 nt)
    float s_[4], s2_[4];
    #pragma unroll
    for (int j=0;j<4;j++){
        float s=0.f, s2=0.f;
        #pragma unroll
        for (int nt=0;nt<6;nt++){ float v=outv[nt][j]; s+=v; s2+=v*v; }
        s_[j]=s; s2_[j]=s2;
    }
    #pragma unroll
    for (int m=1;m<16;m<<=1){
        #pragma unroll
        for (int j=0;j<4;j++){
            s_[j]  += __shfl_xor(s_[j],  m);
            s2_[j] += __shfl_xor(s2_[j], m);
        }
    }
    __syncthreads();   // phase A LDS reads done; AT/HID overwrite Y/AZ/C2
    #pragma unroll
    for (int j=0;j<4;j++){
        float mn = s_[j]*(1.f/C_);
        float rs = rsqrtf(s2_[j]*(1.f/C_) - mn*mn + 1e-5f);
        int row = w*16+lh*4+j;
        int sw2 = (row&7)<<3;
        #pragma unroll
        for (int nt=0;nt<6;nt++){
            int col = nt*16+lr;
            AT[row*128 + (col^sw2)] = f2bf((outv[nt][j]-mn)*rs*gg[col]+bb[col]);
        }
    }
    __syncthreads();
    // fc1 + gelu
    {
        bf16x8 af[3];
        #pragma unroll
        for(int kf=0;kf<3;kf++) af[kf]=*(const bf16x8*)&AT[arow*128+((kf*32+lh*8)^asw)];
        #pragma unroll 2
        for(int nt=0;nt<24;nt++){
            f32x4 acc={0.f,0.f,0.f,0.f};
            #pragma unroll
            for(int kf=0;kf<3;kf++){
                bf16x8 b=*(const bf16x8*)(wbf+((size_t)((WOFF6+kf*24+nt)*64+l))*8);
                acc=MFMA16(af[kf],b,acc);
            }
            int col=nt*16+lr;
            float bias=f1b[col];
            #pragma unroll
            for(int j=0;j<4;j++){
                int row=w*16+lh*4+j;
                HID[row*384 + (col^((row&7)<<3))] = f2bf(gelu_fast(acc[j]+bias));
            }
        }
    }
    __syncthreads();
    // fc2 + final residual write (single global store of the block output)
    {
        bf16x8 afh[12];
        #pragma unroll
        for(int kf=0;kf<12;kf++) afh[kf]=*(const bf16x8*)&HID[arow*384+((kf*32+lh*8)^asw)];
        #pragma unroll 2
        for(int nt=0;nt<6;nt++){
            f32x4 acc={0.f,0.f,0.f,0.f};
            #pragma unroll
            for(int kf=0;kf<12;kf++){
                bf16x8 b=*(const bf16x8*)(wbf+((size_t)((WOFF7+kf*6+nt)*64+l))*8);
                acc=MFMA16(afh[kf],b,acc);
            }
            int col=nt*16+lr;
            float bias=f2b[col];
            #pragma unroll
            for(int j=0;j<4;j++){
                size_t row=row0+w*16+lh*4+j;
                outr[row*C_+col] = outv[nt][j] + acc[j] + bias;
            }
        }
    }
}

extern "C" void kernel_launch(void* const* d_in, const int* in_sizes, int n_in,
                              void* d_out, int out_size, void* d_ws, size_t ws_size,
                              hipStream_t stream)
{
    const float* hs        = (const float*)d_in[0];
    const float* norm_in_g = (const float*)d_in[1];
    const float* norm_in_b = (const float*)d_in[2];
    const float* in_proj_w = (const float*)d_in[3];
    const float* dw_w      = (const float*)d_in[4];
    const float* dw_b      = (const float*)d_in[5];
    const float* qk_w      = (const float*)d_in[6];
    const float* qk_b      = (const float*)d_in[7];
    const float* lepe_w    = (const float*)d_in[8];
    const float* lepe_b    = (const float*)d_in[9];
    const float* conv_x_w  = (const float*)d_in[10];
    const float* conv_z_w  = (const float*)d_in[11];
    const float* x_proj_w  = (const float*)d_in[12];
    const float* dt_proj_w = (const float*)d_in[13];
    const float* dt_proj_b = (const float*)d_in[14];
    const float* A_log     = (const float*)d_in[15];
    const float* Dv        = (const float*)d_in[16];
    const float* out_proj_w= (const float*)d_in[17];
    const float* proj_out_w= (const float*)d_in[18];
    const float* proj_out_b= (const float*)d_in[19];
    const float* out_w     = (const float*)d_in[20];
    const float* out_b     = (const float*)d_in[21];
    const float* norm_mlp_g= (const float*)d_in[22];
    const float* norm_mlp_b= (const float*)d_in[23];
    const float* fc1_w     = (const float*)d_in[24];
    const float* fc1_b     = (const float*)d_in[25];
    const float* fc2_w     = (const float*)d_in[26];
    const float* fc2_b     = (const float*)d_in[27];

    float* ws = (float*)d_ws;
    size_t o = 0;
    float* xx    = ws + o; o += (size_t)BL_*C_;   // -> qbuf after conv1d_xdbl
    float* zz    = ws + o; o += (size_t)BL_*C_;   // -> ybuf after conv1d_xdbl
    float* wwb   = ws + o; o += (size_t)BL_*C_;   // -> aout after dwconv2d
    float* lin_x = ws + o; o += (size_t)BL_*C_;
    float* xs    = ws + o; o += (size_t)BL_*C_;
    float* zs    = ws + o; o += (size_t)BL_*C_;
    float* delta = ws + o; o += (size_t)BL_*C_;
    float* BC    = ws + o; o += (size_t)BL_*32;
    float* Ap    = ws + o; o += (size_t)B_*NCH_*1536;
    float* Be    = ws + o; o += (size_t)B_*NCH_*1536;
    float* Hin   = ws + o; o += (size_t)B_*NCH_*1536;
    float* GA    = ws + o; o += (size_t)B_*NG_*1536;
    float* GB    = ws + o; o += (size_t)B_*NG_*1536;
    float* Gin   = ws + o; o += (size_t)B_*NG_*1536;
    float* kvacc = ws + o; o += 3264;
    float2* ctab = (float2*)(ws + o); o += 6144;
    float* wt9   = ws + o; o += 864;
    float* lw9   = ws + o; o += 864;
    float* wxT   = ws + o; o += 384;
    float* wzT   = ws + o; o += 384;
    unsigned short* wbf = (unsigned short*)(ws + o);

    float* qbuf = xx;
    float* ybuf = zz;
    float* aout = wwb;
    float* outr = (float*)d_out;

    k_setup<<<dim3(72,8), 64, 0, stream>>>(in_proj_w, qk_w, out_proj_w, proj_out_w,
                                           out_w, fc1_w, fc2_w, dw_w, lepe_w,
                                           x_proj_w, conv_x_w, conv_z_w,
                                           wbf, ctab, wt9, lw9, kvacc, wxT, wzT);
    k_ln_inproj_m<<<BL_/64, 256, 0, stream>>>(hs, norm_in_g, norm_in_b, wbf, xx, zz, wwb);
    k_dwconv2d<<<(BL_*24)/256, 256, 0, stream>>>(wwb, wt9, dw_b, lin_x);
    k_conv1d_xdbl<<<BL_/64, 256, 0, stream>>>(xx, zz, wxT, wzT, wbf,
                                              dt_proj_w, dt_proj_b, xs, zs, delta, BC);
    k_qk_kv<<<BL_/64, 256, 0, stream>>>(lin_x, wbf, qk_b, ctab, qbuf, kvacc);
    k_attnout<<<BL_/16, 384, 0, stream>>>(qbuf, lin_x, kvacc, ctab, lw9, lepe_b, aout);
    k_scan1<<<B_*NCH_, 384, 0, stream>>>(delta, xs, BC, A_log, Ap, Be);
    k_scan2a<<<B_*NG_, 384, 0, stream>>>(Ap, Be, GA, GB);
    k_scan2b<<<12, 256, 0, stream>>>(GA, GB, Gin);
    k_scan2c<<<B_*NG_, 384, 0, stream>>>(Ap, Be, Gin, Hin);
    k_scan3<<<B_*NCH_, 384, 0, stream>>>(delta, xs, BC, A_log, Dv, Hin, ybuf);
    k_combine_mlp<<<BL_/64, 256, 0, stream>>>(ybuf, zs, aout, wbf, proj_out_b,
                                              out_b, hs, norm_mlp_g, norm_mlp_b,
                                              fc1_b, fc2_b, outr);
}

// Round 7
// 203.247 us; speedup vs baseline: 3.4479x; 1.0287x over previous
//
#include <hip/hip_runtime.h>
#include <hip/hip_bf16.h>
#include <math.h>

#define B_ 2
#define H_ 128
#define W_ 128
#define C_ 96
#define L_ (H_*W_)
#define BL_ (B_*L_)
#define NH_ 6
#define NPROJ_ 38
#define MLPH_ 384
#define NCH_ 512
#define CHL_ (L_/NCH_)
#define NG_ 32

typedef __attribute__((ext_vector_type(8))) short bf16x8;
typedef __attribute__((ext_vector_type(4))) float f32x4;

#define MFMA16(a,b,c) __builtin_amdgcn_mfma_f32_16x16x32_bf16(a,b,c,0,0,0)

// weight fragment table (each frag = 64 lanes * 8 bf16 = 512 elems)
#define WOFF1 0      // in_proj  96x288 : 3*18 = 54
#define WOFF2 54     // qk_w     96x192 : 3*12 = 36
#define WOFF3 90     // out_proj 192x96 : 6*6  = 36
#define WOFF4 126    // proj_out 96x96  : 3*6  = 18
#define WOFF5 144    // out_w    192x96 : 6*6  = 36
#define WOFF6 180    // fc1      96x384 : 3*24 = 72
#define WOFF7 252    // fc2      384x96 : 12*6 = 72
#define WOFF8 324    // x_proj   96x38(->48 pad) : 3*3 = 9
#define WFRAGS 333

__device__ __forceinline__ float siluf(float x){ return x / (1.f + __expf(-x)); }
__device__ __forceinline__ unsigned short f2bf(float x){
    __hip_bfloat16 h = __float2bfloat16(x);
    return *reinterpret_cast<unsigned short*>(&h);
}
__device__ __forceinline__ unsigned pack2(float a, float b){
    return (unsigned)f2bf(a) | ((unsigned)f2bf(b) << 16);
}
__device__ __forceinline__ float bf2f(unsigned short u){
    return __uint_as_float((unsigned)u << 16);
}
__device__ __forceinline__ float gelu_fast(float x){
    float u_ = 0.7978845608f*x*(1.f + 0.044715f*x*x);
    float au = fabsf(u_);
    float e = __expf(-2.f*au);
    float th = (1.f - e)/(1.f + e);
    th = copysignf(th, u_);
    return 0.5f*x*(1.f + th);
}

// ---------------- K0: setup — weight prep + rope table + misc transposes ----------------
__global__ __launch_bounds__(64) void k_setup(const float* __restrict__ w1,
    const float* __restrict__ w2, const float* __restrict__ w3,
    const float* __restrict__ w4, const float* __restrict__ w5,
    const float* __restrict__ w6, const float* __restrict__ w7,
    const float* __restrict__ dww, const float* __restrict__ lw,
    const float* __restrict__ xpw, const float* __restrict__ cxw,
    const float* __restrict__ czw,
    unsigned short* __restrict__ dst, float2* __restrict__ ctab,
    float* __restrict__ wt9, float* __restrict__ lw9, float* __restrict__ kvacc,
    float* __restrict__ wxT, float* __restrict__ wzT)
{
    int m = blockIdx.y;
    int l = threadIdx.x;
    if (m < 7){
        const float* srcs[7] = {w1,w2,w3,w4,w5,w6,w7};
        const int Ks[7]   = {96,96,192,96,192,96,384};
        const int Ns[7]   = {288,192,96,96,96,384,96};
        const int offs[7] = {WOFF1,WOFF2,WOFF3,WOFF4,WOFF5,WOFF6,WOFF7};
        int f = blockIdx.x;
        int nnt = Ns[m] >> 4, nkf = Ks[m] >> 5;
        if (f >= nnt*nkf) return;
        int kf = f / nnt, nt = f - kf*nnt;
        const float* s = srcs[m];
        unsigned short* d = dst + ((size_t)(offs[m] + f)*64 + l)*8;
        int krow = kf*32 + (l>>4)*8;
        int col  = nt*16 + (l&15);
        #pragma unroll
        for (int j=0;j<8;j++) d[j] = f2bf(s[(size_t)(krow+j)*Ns[m] + col]);
    } else {
        int x = blockIdx.x;
        if (x == 0){
            for (int i=l; i<128*24; i+=64){
                int pos = i/24, p = i%24;
                float th = powf(10000.f, -(float)p/24.f);
                float sn, cs; sincosf((float)pos*th, &sn, &cs);
                ctab[i] = make_float2(cs, sn);
            }
        } else if (x == 1){
            for (int i=l; i<3264; i+=64) kvacc[i] = 0.f;
        } else if (x == 2){
            for (int i=l; i<864; i+=64){
                int c = i/9, tap = i%9;
                wt9[tap*96 + c] = dww[i];
                lw9[tap*96 + c] = lw[i];
            }
        } else if (x == 3){
            for (int f=0; f<9; f++){
                int kf=f/3, nt=f%3;
                unsigned short* d = dst + ((size_t)(WOFF8 + f)*64 + l)*8;
                int krow = kf*32 + (l>>4)*8;
                int col  = nt*16 + (l&15);
                #pragma unroll
                for (int j=0;j<8;j++){
                    float v = (col < NPROJ_) ? xpw[(size_t)(krow+j)*NPROJ_ + col] : 0.f;
                    d[j] = f2bf(v);
                }
            }
        } else if (x == 4){
            for (int i=l; i<384; i+=64){
                int j = i/96, c = i%96;
                wxT[i] = cxw[c*4 + j];
                wzT[i] = czw[c*4 + j];
            }
        }
    }
}

// ---------------- K1: LayerNorm + in_proj (96 -> 288) MFMA, split outputs ----------------
__global__ __launch_bounds__(256) void k_ln_inproj_m(const float* __restrict__ hs,
    const float* __restrict__ gg, const float* __restrict__ bb,
    const unsigned short* __restrict__ wbf,
    float* __restrict__ xx, float* __restrict__ zz, float* __restrict__ ww)
{
    __shared__ unsigned short A[64*128];
    int t = threadIdx.x;
    size_t row0 = (size_t)blockIdx.x * 64;
    {
        int r = t >> 2, q = t & 3;
        const float* src = hs + (row0 + r)*C_ + q*24;
        float v[24];
        float s=0.f, s2=0.f;
        #pragma unroll
        for (int i=0;i<24;i++){ float x=src[i]; v[i]=x; s+=x; s2+=x*x; }
        s += __shfl_xor(s,1); s2 += __shfl_xor(s2,1);
        s += __shfl_xor(s,2); s2 += __shfl_xor(s2,2);
        float mn = s*(1.f/C_);
        float rs = rsqrtf(s2*(1.f/C_) - mn*mn + 1e-5f);
        int base = r*128, sw = (r&7)<<3;
        #pragma unroll
        for (int i=0;i<24;i+=2){
            int c = q*24 + i;
            float a0 = (v[i]  -mn)*rs*gg[c]   + bb[c];
            float a1 = (v[i+1]-mn)*rs*gg[c+1] + bb[c+1];
            *(unsigned*)&A[base + (c ^ sw)] = pack2(a0,a1);
        }
    }
    __syncthreads();
    int w = t>>6, l = t&63, lr = l&15, lh = l>>4;
    int arow = w*16 + lr;
    int abase = arow*128, asw = (arow&7)<<3;
    bf16x8 af[3];
    #pragma unroll
    for (int kf=0;kf<3;kf++)
        af[kf] = *(const bf16x8*)&A[abase + ((kf*32 + lh*8) ^ asw)];
    #pragma unroll 2
    for (int nt=0; nt<18; nt++){
        f32x4 acc = {0.f,0.f,0.f,0.f};
        #pragma unroll
        for (int kf=0;kf<3;kf++){
            bf16x8 bf_ = *(const bf16x8*)(wbf + ((size_t)((WOFF1 + kf*18 + nt)*64 + l))*8);
            acc = MFMA16(af[kf], bf_, acc);
        }
        float* base_;
        if (nt < 6) base_ = xx; else if (nt < 12) base_ = zz; else base_ = ww;
        int col = (nt%6)*16 + lr;
        float* dst = base_ + (row0 + w*16 + lh*4)*C_ + col;
        #pragma unroll
        for (int j=0;j<4;j++) dst[(size_t)j*C_] = acc[j];
    }
}

// ---------------- K2: depthwise 3x3 conv + silu on ww, float4 ----------------
__global__ __launch_bounds__(256) void k_dwconv2d(const float* __restrict__ wwb,
    const float* __restrict__ wt9, const float* __restrict__ dwb,
    float* __restrict__ out)
{
    int gid = blockIdx.x*256 + threadIdx.x;   // BL*24
    int row = gid/24, c4 = gid%24; int c = c4*4;
    int b = row >> 14;
    int ll = row & (L_-1);
    int h = ll >> 7, wq = ll & 127;
    float4 acc = {0.f,0.f,0.f,0.f};
    #pragma unroll
    for (int kh=0; kh<3; kh++){
        int hh = h + kh - 1;
        if ((unsigned)hh < 128u){
            int base_row = (b<<14) + (hh<<7);
            #pragma unroll
            for (int kw=0; kw<3; kw++){
                int wp = wq + kw - 1;
                if ((unsigned)wp < 128u){
                    float4 v = *(const float4*)&wwb[(size_t)(base_row + wp)*C_ + c];
                    float4 wt = *(const float4*)&wt9[(kh*3+kw)*96 + c];
                    acc.x += v.x*wt.x; acc.y += v.y*wt.y;
                    acc.z += v.z*wt.z; acc.w += v.w*wt.w;
                }
            }
        }
    }
    float4 bv = *(const float4*)&dwb[c];
    float4 o;
    o.x = siluf(acc.x+bv.x); o.y = siluf(acc.y+bv.y);
    o.z = siluf(acc.z+bv.z); o.w = siluf(acc.w+bv.w);
    *(float4*)&out[(size_t)row*C_ + c] = o;
}

// ---------------- K3: conv1d+silu (float4) + x_proj MFMA + dt_proj/softplus ----------------
__global__ __launch_bounds__(256) void k_conv1d_xdbl(const float* __restrict__ xxb,
    const float* __restrict__ zzb, const float* __restrict__ wxT,
    const float* __restrict__ wzT, const unsigned short* __restrict__ wbf,
    const float* __restrict__ dtw, const float* __restrict__ dtb,
    float* __restrict__ xs, float* __restrict__ zs,
    float* __restrict__ delta, float* __restrict__ BC)
{
    __shared__ unsigned short A[64*128];   // silu(conv1d(x)) bf16, swizzled A-tile
    __shared__ float XD[64][8];            // dt part of x_dbl (cols 0..5)
    __shared__ float dtws[6][96];
    int t = threadIdx.x;
    size_t row0 = (size_t)blockIdx.x * 64;
    int b = (int)(row0 >> 14);
    int l0 = (int)(row0 & 16383);
    for (int i=t; i<576; i+=256) dtws[i/96][i%96] = dtw[i];
    for (int p=t; p<64*24; p+=256){
        int r = p/24, cq = p - r*24, c = cq*4;
        int l = l0 + r;
        float ax0=0.f,ax1=0.f,ax2=0.f,ax3=0.f;
        float az0=0.f,az1=0.f,az2=0.f,az3=0.f;
        #pragma unroll
        for (int j=0;j<4;j++){
            int lq = l - 1 + j;
            if ((unsigned)lq < (unsigned)L_){
                size_t off = ((size_t)(b<<14) + lq)*C_ + c;
                float4 xv = *(const float4*)&xxb[off];
                float4 zv = *(const float4*)&zzb[off];
                float4 wx4 = *(const float4*)&wxT[j*96 + c];
                float4 wz4 = *(const float4*)&wzT[j*96 + c];
                ax0 += xv.x*wx4.x; ax1 += xv.y*wx4.y; ax2 += xv.z*wx4.z; ax3 += xv.w*wx4.w;
                az0 += zv.x*wz4.x; az1 += zv.y*wz4.y; az2 += zv.z*wz4.z; az3 += zv.w*wz4.w;
            }
        }
        ax0=siluf(ax0); ax1=siluf(ax1); ax2=siluf(ax2); ax3=siluf(ax3);
        az0=siluf(az0); az1=siluf(az1); az2=siluf(az2); az3=siluf(az3);
        float4 xo={ax0,ax1,ax2,ax3}, zo={az0,az1,az2,az3};
        *(float4*)&xs[(row0+r)*C_ + c] = xo;
        *(float4*)&zs[(row0+r)*C_ + c] = zo;
        int sw = (r&7)<<3;
        uint2 pk = { pack2(ax0,ax1), pack2(ax2,ax3) };
        *(uint2*)&A[r*128 + (c ^ sw)] = pk;
    }
    __syncthreads();
    int w=t>>6, l=t&63, lr=l&15, lh=l>>4;
    int arow = w*16+lr, asw=(arow&7)<<3;
    bf16x8 af[3];
    #pragma unroll
    for (int kf=0;kf<3;kf++)
        af[kf] = *(const bf16x8*)&A[arow*128 + ((kf*32 + lh*8) ^ asw)];
    #pragma unroll
    for (int nt=0; nt<3; nt++){
        f32x4 acc={0.f,0.f,0.f,0.f};
        #pragma unroll
        for (int kf=0;kf<3;kf++){
            bf16x8 bfr=*(const bf16x8*)(wbf + ((size_t)((WOFF8 + kf*3 + nt)*64 + l))*8);
            acc = MFMA16(af[kf], bfr, acc);
        }
        int col = nt*16 + lr;
        #pragma unroll
        for (int j=0;j<4;j++){
            int row = w*16 + lh*4 + j;
            if (col < 6) XD[row][col] = acc[j];
            else if (col < NPROJ_) BC[(row0+row)*32 + (col-6)] = acc[j];
        }
    }
    __syncthreads();
    {
        int r = t>>2, q = t&3;
        float xd0=XD[r][0], xd1=XD[r][1], xd2=XD[r][2];
        float xd3=XD[r][3], xd4=XD[r][4], xd5=XD[r][5];
        #pragma unroll
        for (int g=0; g<6; g++){
            int c = q*24 + g*4;
            float4 acc = *(const float4*)&dtb[c];
            float4 w0 = *(const float4*)&dtws[0][c];
            float4 w1 = *(const float4*)&dtws[1][c];
            float4 w2 = *(const float4*)&dtws[2][c];
            float4 w3 = *(const float4*)&dtws[3][c];
            float4 w4 = *(const float4*)&dtws[4][c];
            float4 w5 = *(const float4*)&dtws[5][c];
            acc.x += xd0*w0.x + xd1*w1.x + xd2*w2.x + xd3*w3.x + xd4*w4.x + xd5*w5.x;
            acc.y += xd0*w0.y + xd1*w1.y + xd2*w2.y + xd3*w3.y + xd4*w4.y + xd5*w5.y;
            acc.z += xd0*w0.z + xd1*w1.z + xd2*w2.z + xd3*w3.z + xd4*w4.z + xd5*w5.z;
            acc.w += xd0*w0.w + xd1*w1.w + xd2*w2.w + xd3*w3.w + xd4*w4.w + xd5*w5.w;
            float4 dl;
            dl.x = (acc.x>20.f)? acc.x : __logf(1.f+__expf(acc.x));
            dl.y = (acc.y>20.f)? acc.y : __logf(1.f+__expf(acc.y));
            dl.z = (acc.z>20.f)? acc.z : __logf(1.f+__expf(acc.z));
            dl.w = (acc.w>20.f)? acc.w : __logf(1.f+__expf(acc.w));
            *(float4*)&delta[(row0+r)*C_ + c] = dl;
        }
    }
}

// ---------------- K4: qk MFMA + elu+1 + rope-k + MFMA kv reduce + kmean ----------------
__global__ __launch_bounds__(256) void k_qk_kv(const float* __restrict__ lin,
    const unsigned short* __restrict__ wbf, const float* __restrict__ qkb,
    const float2* __restrict__ ctab, float* __restrict__ qo,
    float* __restrict__ kvacc)
{
    __shared__ unsigned short A[64*128];
    __shared__ float KR[64*105];
    __shared__ float kmsum[96];
    int t = threadIdx.x;
    size_t row0 = (size_t)blockIdx.x * 64;
    int b = (int)(row0 >> 14);
    int l0 = (int)(row0 & 16383);
    for (int p = t; p < 64*48; p += 256){
        int r = p/48, c = (p - r*48)*2;
        float2 xy = *(const float2*)&lin[(row0 + r)*C_ + c];
        *(unsigned*)&A[r*128 + (c ^ ((r&7)<<3))] = pack2(xy.x, xy.y);
    }
    if (t < 96) kmsum[t] = 0.f;
    __syncthreads();
    int w=t>>6, l=t&63, lr=l&15, lh=l>>4;
    int arow = w*16+lr; int asw=(arow&7)<<3;
    bf16x8 af[3];
    #pragma unroll
    for (int kf=0;kf<3;kf++)
        af[kf] = *(const bf16x8*)&A[arow*128 + ((kf*32 + lh*8) ^ asw)];
    #pragma unroll 2
    for (int nt=0; nt<12; nt++){
        f32x4 acc={0.f,0.f,0.f,0.f};
        #pragma unroll
        for (int kf=0;kf<3;kf++){
            bf16x8 bfr=*(const bf16x8*)(wbf + ((size_t)((WOFF2 + kf*12 + nt)*64 + l))*8);
            acc = MFMA16(af[kf], bfr, acc);
        }
        int colg = nt*16 + lr;
        float bias = qkb[colg];
        float vv[4];
        #pragma unroll
        for (int j=0;j<4;j++){
            float v = acc[j] + bias;
            vv[j] = (v>0.f)? v+1.f : __expf(v);
        }
        if (nt < 6){
            float* dp = qo + (row0 + w*16 + lh*4)*C_ + colg;
            #pragma unroll
            for (int j=0;j<4;j++) dp[(size_t)j*C_] = vv[j];
        } else {
            int ck = colg - 96;
            atomicAdd(&kmsum[ck], vv[0]+vv[1]+vv[2]+vv[3]);
            float pv[4];
            #pragma unroll
            for (int j=0;j<4;j++) pv[j] = __shfl_xor(vv[j], 1);
            int p = ck >> 1;
            #pragma unroll
            for (int j=0;j<4;j++){
                int rl = l0 + w*16 + lh*4 + j;
                int hp = rl>>7, wp = rl&127;
                float2 cssn = (p<24)? ctab[hp*24+p] : ctab[wp*24+(p-24)];
                float kr = (ck&1)? (pv[j]*cssn.y + vv[j]*cssn.x)
                                 : (vv[j]*cssn.x - pv[j]*cssn.y);
                KR[(w*16+lh*4+j)*105 + ck] = kr;
            }
        }
    }
    __syncthreads();
    // phase 2: kv[h] = KR^T (16x64) @ V (64x16) via MFMA, all 4 waves
    for (int h = w; h < 6; h += 4){
        f32x4 acc = {0.f,0.f,0.f,0.f};
        #pragma unroll
        for (int kk=0; kk<2; kk++){
            union { bf16x8 v; unsigned short u[8]; } afu, bfu;
            #pragma unroll
            for (int j=0;j<8;j++){
                int rr = kk*32 + lh*8 + j;
                afu.u[j] = f2bf(KR[rr*105 + h*16 + lr]);
                bfu.u[j] = A[rr*128 + ((h*16+lr) ^ ((rr&7)<<3))];
            }
            acc = MFMA16(afu.v, bfu.v, acc);
        }
        #pragma unroll
        for (int i=0;i<4;i++)
            atomicAdd(&kvacc[b*1536 + h*256 + (lh*4+i)*16 + lr], acc[i]);
    }
    if (t < 96) atomicAdd(&kvacc[3072 + b*96 + t], kmsum[t]);
}

// ---------------- K5: attention output, 4 channels/thread, float4 ----------------
__global__ __launch_bounds__(384) void k_attnout(const float* __restrict__ qbuf,
    const float* __restrict__ vbuf, const float* __restrict__ kvacc,
    const float2* __restrict__ ctab, const float* __restrict__ lw9,
    const float* __restrict__ lb, float* __restrict__ aout)
{
    __shared__ float kvs[1536];
    __shared__ float kms[96];
    int t = threadIdx.x;
    size_t row0 = (size_t)blockIdx.x * 16;
    int b = (int)(row0 >> 14);
    const float invL = 1.f/16384.f;
    for (int i=t; i<1536; i+=384) kvs[i] = kvacc[b*1536+i]*invL;
    if (t < 96) kms[t] = kvacc[3072+b*96+t]*invL;
    __syncthreads();
    int r = t/24, c4 = t%24;
    int c = c4*4;
    int lrow = (int)(row0 & 16383) + r;
    int hp = lrow>>7, wp = lrow&127;
    size_t row = row0 + r;
    float4 q4 = *(const float4*)&qbuf[row*C_ + c];
    int p0 = c>>1, p1 = p0+1;
    float2 cs0 = (p0<24)? ctab[hp*24+p0] : ctab[wp*24+(p0-24)];
    float2 cs1 = (p1<24)? ctab[hp*24+p1] : ctab[wp*24+(p1-24)];
    float4 qr;
    qr.x = q4.x*cs0.x - q4.y*cs0.y;
    qr.y = q4.x*cs0.y + q4.y*cs0.x;
    qr.z = q4.z*cs1.x - q4.w*cs1.y;
    qr.w = q4.z*cs1.y + q4.w*cs1.x;
    int h = c4>>2, j = c4&3;
    int dbase = j*4;
    float zp = q4.x*kms[h*16+dbase]   + q4.y*kms[h*16+dbase+1]
             + q4.z*kms[h*16+dbase+2] + q4.w*kms[h*16+dbase+3];
    zp += __shfl_xor(zp,1);
    zp += __shfl_xor(zp,2);
    float zd = 1.f/(zp + 1e-6f);
    float4 o = {0.f,0.f,0.f,0.f};
    #pragma unroll
    for (int g=0; g<4; g++){
        float4 qg;
        if (g==0) qg = qr;
        else {
            qg.x=__shfl_xor(qr.x,g); qg.y=__shfl_xor(qr.y,g);
            qg.z=__shfl_xor(qr.z,g); qg.w=__shfl_xor(qr.w,g);
        }
        int db = ((j^g)<<2);
        const float* kp = &kvs[h*256 + db*16 + j*4];
        #pragma unroll
        for (int i=0;i<4;i++){
            float qi = (i==0)?qg.x:(i==1)?qg.y:(i==2)?qg.z:qg.w;
            float4 kv4 = *(const float4*)&kp[i*16];
            o.x += qi*kv4.x; o.y += qi*kv4.y;
            o.z += qi*kv4.z; o.w += qi*kv4.w;
        }
    }
    float4 acc = *(const float4*)&lb[c];
    #pragma unroll
    for (int kh=0; kh<3; kh++){
        int hh = hp + kh - 1;
        if ((unsigned)hh < 128u){
            int base_row = (b<<14) + (hh<<7);
            #pragma unroll
            for (int kw=0; kw<3; kw++){
                int wq = wp + kw - 1;
                if ((unsigned)wq < 128u){
                    float4 v = *(const float4*)&vbuf[(size_t)(base_row + wq)*C_ + c];
                    float4 wt = *(const float4*)&lw9[(kh*3+kw)*96 + c];
                    acc.x += v.x*wt.x; acc.y += v.y*wt.y;
                    acc.z += v.z*wt.z; acc.w += v.w*wt.w;
                }
            }
        }
    }
    float4 res;
    res.x = o.x*zd + acc.x; res.y = o.y*zd + acc.y;
    res.z = o.z*zd + acc.z; res.w = o.w*zd + acc.w;
    *(float4*)&aout[row*C_ + c] = res;
}

// ---------------- K6a: scan pass1 — per-chunk aggregates, 4 states/thread ----------------
__global__ __launch_bounds__(384) void k_scan1(const float* __restrict__ delta,
    const float* __restrict__ xs, const float* __restrict__ BC,
    const float* __restrict__ A_log, float* __restrict__ Ap, float* __restrict__ Be)
{
    int t = threadIdx.x; int nq = t&3, c = t>>2;
    int blk = blockIdx.x; int b = blk>>9, ch = blk&(NCH_-1);
    float4 a4 = *(const float4*)&A_log[c*16 + nq*4];
    float a0=-__expf(a4.x), a1=-__expf(a4.y), a2=-__expf(a4.z), a3=-__expf(a4.w);
    float ap0=1.f,ap1=1.f,ap2=1.f,ap3=1.f;
    float be0=0.f,be1=0.f,be2=0.f,be3=0.f;
    size_t base = ((size_t)b<<14) + ch*CHL_;
    for (int i=0;i<CHL_;i++){
        size_t row = base + i;
        float dl = delta[row*C_+c];
        float u  = xs[row*C_+c];
        float du = dl*u;
        float4 bc = *(const float4*)&BC[row*32 + nq*4];
        float e0=__expf(dl*a0), e1=__expf(dl*a1), e2=__expf(dl*a2), e3=__expf(dl*a3);
        ap0*=e0; be0=be0*e0+du*bc.x;
        ap1*=e1; be1=be1*e1+du*bc.y;
        ap2*=e2; be2=be2*e2+du*bc.z;
        ap3*=e3; be3=be3*e3+du*bc.w;
    }
    size_t o = (size_t)blk*1536 + c*16 + nq*4;
    float4 apv={ap0,ap1,ap2,ap3}, bev={be0,be1,be2,be3};
    *(float4*)&Ap[o] = apv;
    *(float4*)&Be[o] = bev;
}

// ---------------- K6b: group aggregates (16 chunks/group) ----------------
__global__ __launch_bounds__(384) void k_scan2a(const float* __restrict__ Ap,
    const float* __restrict__ Be, float* __restrict__ GA, float* __restrict__ GB)
{
    int t = threadIdx.x; int blk = blockIdx.x;  // B*NG
    int b = blk>>5, g = blk&(NG_-1);
    int idx = (t>>2)*16 + (t&3)*4;
    float4 A = {1.f,1.f,1.f,1.f}, Bv = {0.f,0.f,0.f,0.f};
    for (int j=0;j<16;j++){
        size_t o = ((size_t)(b*NCH_ + g*16 + j))*1536 + idx;
        float4 a = *(const float4*)&Ap[o];
        float4 bb = *(const float4*)&Be[o];
        Bv.x=a.x*Bv.x+bb.x; Bv.y=a.y*Bv.y+bb.y; Bv.z=a.z*Bv.z+bb.z; Bv.w=a.w*Bv.w+bb.w;
        A.x*=a.x; A.y*=a.y; A.z*=a.z; A.w*=a.w;
    }
    size_t o = (size_t)blk*1536 + idx;
    *(float4*)&GA[o] = A;
    *(float4*)&GB[o] = Bv;
}

// ---------------- K6c: sequential over NG groups ----------------
__global__ __launch_bounds__(256) void k_scan2b(const float* __restrict__ GA,
    const float* __restrict__ GB, float* __restrict__ Gin)
{
    int t = blockIdx.x*256 + threadIdx.x;  // 3072
    int b = t/1536, m = t%1536;
    float h = 0.f;
    for (int g=0; g<NG_; g++){
        size_t o = ((size_t)(b*NG_+g))*1536 + m;
        Gin[o] = h;
        h = GA[o]*h + GB[o];
    }
}

// ---------------- K6d: within-group chunk-incoming states ----------------
__global__ __launch_bounds__(384) void k_scan2c(const float* __restrict__ Ap,
    const float* __restrict__ Be, const float* __restrict__ Gin,
    float* __restrict__ Hin)
{
    int t = threadIdx.x; int blk = blockIdx.x;  // B*NG
    int b = blk>>5, g = blk&(NG_-1);
    int idx = (t>>2)*16 + (t&3)*4;
    float4 h = *(const float4*)&Gin[(size_t)blk*1536 + idx];
    for (int j=0;j<16;j++){
        size_t o = ((size_t)(b*NCH_ + g*16 + j))*1536 + idx;
        *(float4*)&Hin[o] = h;
        float4 a = *(const float4*)&Ap[o];
        float4 bb = *(const float4*)&Be[o];
        h.x=a.x*h.x+bb.x; h.y=a.y*h.y+bb.y; h.z=a.z*h.z+bb.z; h.w=a.w*h.w+bb.w;
    }
}

// ---------------- K6e: scan pass3 — replay + emit y ----------------
__global__ __launch_bounds__(384) void k_scan3(const float* __restrict__ delta,
    const float* __restrict__ xs, const float* __restrict__ BC,
    const float* __restrict__ A_log, const float* __restrict__ Dv,
    const float* __restrict__ Hin, float* __restrict__ y)
{
    int t = threadIdx.x; int nq = t&3, c = t>>2;
    int blk = blockIdx.x; int b = blk>>9, ch = blk&(NCH_-1);
    float4 a4 = *(const float4*)&A_log[c*16 + nq*4];
    float a0=-__expf(a4.x), a1=-__expf(a4.y), a2=-__expf(a4.z), a3=-__expf(a4.w);
    float4 h = *(const float4*)&Hin[(size_t)blk*1536 + c*16 + nq*4];
    float Dc = Dv[c];
    size_t base = ((size_t)b<<14) + ch*CHL_;
    for (int i=0;i<CHL_;i++){
        size_t row = base + i;
        float dl = delta[row*C_+c];
        float u  = xs[row*C_+c];
        float du = dl*u;
        float4 bcB = *(const float4*)&BC[row*32 + nq*4];
        float4 bcC = *(const float4*)&BC[row*32 + 16 + nq*4];
        float e0=__expf(dl*a0), e1=__expf(dl*a1), e2=__expf(dl*a2), e3=__expf(dl*a3);
        h.x=h.x*e0+du*bcB.x; h.y=h.y*e1+du*bcB.y;
        h.z=h.z*e2+du*bcB.z; h.w=h.w*e3+du*bcB.w;
        float yv = h.x*bcC.x + h.y*bcC.y + h.z*bcC.z + h.w*bcC.w;
        yv += __shfl_xor(yv,1);
        yv += __shfl_xor(yv,2);
        if (nq == 0) y[row*C_+c] = yv + Dc*u;
    }
}

// ---------------- K7: combine (3 chained GEMMs) + LN + MLP, fused, 8 waves ----------------
__global__ __launch_bounds__(512) void k_combine_mlp(const float* __restrict__ y,
    const float* __restrict__ zs, const float* __restrict__ aout,
    const unsigned short* __restrict__ wbf, const float* __restrict__ pob,
    const float* __restrict__ outb, const float* __restrict__ hs,
    const float* __restrict__ gg, const float* __restrict__ bb,
    const float* __restrict__ f1b, const float* __restrict__ f2b,
    float* __restrict__ outr)
{
    __shared__ __attribute__((aligned(16))) char POOL[65536];
    __shared__ float LNS[64][2], LNS2[64][2];
    unsigned short* Y  = (unsigned short*)POOL;            // 64*192 (24 KB)
    unsigned short* AZ = (unsigned short*)(POOL + 24576);  // 64*128 (16 KB)
    unsigned short* C2 = (unsigned short*)(POOL + 40960);  // 64*192 (24 KB)
    unsigned short* AT = (unsigned short*)POOL;            // 64*128 (16 KB) phase B
    unsigned short* HID= (unsigned short*)(POOL + 16384);  // 64*384 (48 KB) phase B
    int t=threadIdx.x;
    size_t row0=(size_t)blockIdx.x*64;
    for (int p=t;p<64*48;p+=512){
        int r=p/48, c=(p-r*48)*2;
        size_t g=(row0+r)*C_+c;
        float2 yv=*(const float2*)&y[g];
        float2 zv=*(const float2*)&zs[g];
        float2 av=*(const float2*)&aout[g];
        int sw=(r&7)<<3;
        *(unsigned*)&Y[r*192 + (c^sw)] = pack2(yv.x,yv.y);
        *(unsigned*)&Y[r*192 + ((96+c)^sw)] = pack2(zv.x,zv.y);
        *(unsigned*)&AZ[r*128 + (c^sw)] = pack2(av.x*zv.x, av.y*zv.y);
    }
    __syncthreads();
    int w=t>>6, l=t&63, lr=l&15, lh=l>>4;
    int rt=w>>1, hf=w&1;
    int arow=rt*16+lr; int asw=(arow&7)<<3;
    bf16x8 af1[6], af2[3];
    #pragma unroll
    for (int kf=0;kf<6;kf++) af1[kf]=*(const bf16x8*)&Y[arow*192 + ((kf*32+lh*8)^asw)];
    #pragma unroll
    for (int kf=0;kf<3;kf++) af2[kf]=*(const bf16x8*)&AZ[arow*128 + ((kf*32+lh*8)^asw)];
    #pragma unroll
    for (int q=0;q<3;q++){
        int nt = hf*3 + q;
        f32x4 a1={0.f,0.f,0.f,0.f}, a2={0.f,0.f,0.f,0.f};
        #pragma unroll
        for (int kf=0;kf<6;kf++){
            bf16x8 b=*(const bf16x8*)(wbf+((size_t)((WOFF3+kf*6+nt)*64+l))*8);
            a1=MFMA16(af1[kf],b,a1);
        }
        #pragma unroll
        for (int kf=0;kf<3;kf++){
            bf16x8 b=*(const bf16x8*)(wbf+((size_t)((WOFF4+kf*6+nt)*64+l))*8);
            a2=MFMA16(af2[kf],b,a2);
        }
        int col=nt*16+lr;
        float pb=pob[col];
        #pragma unroll
        for (int j=0;j<4;j++){
            int row=rt*16+lh*4+j;
            int sw2=(row&7)<<3;
            C2[row*192 + (col^sw2)] = f2bf(a1[j]);
            C2[row*192 + ((96+col)^sw2)] = f2bf(a2[j]+pb);
        }
    }
    __syncthreads();
    bf16x8 af3[6];
    #pragma unroll
    for (int kf=0;kf<6;kf++) af3[kf]=*(const bf16x8*)&C2[arow*192 + ((kf*32+lh*8)^asw)];
    // out-stack GEMM + residual, 3 nts per wave, outputs in registers
    float outv[3][4];
    #pragma unroll
    for (int q=0;q<3;q++){
        int nt = hf*3 + q;
        f32x4 acc={0.f,0.f,0.f,0.f};
        #pragma unroll
        for (int kf=0;kf<6;kf++){
            bf16x8 b=*(const bf16x8*)(wbf+((size_t)((WOFF5+kf*6+nt)*64+l))*8);
            acc=MFMA16(af3[kf],b,acc);
        }
        int col=nt*16+lr;
        float ob=outb[col];
        #pragma unroll
        for (int j=0;j<4;j++){
            size_t row=row0+rt*16+lh*4+j;
            outv[q][j] = acc[j] + ob + hs[row*C_+col];
        }
    }
    // LN partials: sum this wave's 48 cols per row, reduce across 16 lanes
    float s_[4], s2_[4];
    #pragma unroll
    for (int j=0;j<4;j++){
        float s=0.f, s2=0.f;
        #pragma unroll
        for (int q=0;q<3;q++){ float v=outv[q][j]; s+=v; s2+=v*v; }
        s_[j]=s; s2_[j]=s2;
    }
    #pragma unroll
    for (int m=1;m<16;m<<=1){
        #pragma unroll
        for (int j=0;j<4;j++){
            s_[j]  += __shfl_xor(s_[j],  m);
            s2_[j] += __shfl_xor(s2_[j], m);
        }
    }
    if (lr==0){
        #pragma unroll
        for (int j=0;j<4;j++){
            int row = rt*16+lh*4+j;
            LNS[row][hf]  = s_[j];
            LNS2[row][hf] = s2_[j];
        }
    }
    __syncthreads();   // LN partials visible; phase A LDS reads done -> AT overwrites Y
    #pragma unroll
    for (int j=0;j<4;j++){
        int row = rt*16+lh*4+j;
        float s  = LNS[row][0]  + LNS[row][1];
        float s2 = LNS2[row][0] + LNS2[row][1];
        float mn = s*(1.f/C_);
        float rs = rsqrtf(s2*(1.f/C_) - mn*mn + 1e-5f);
        int sw2 = (row&7)<<3;
        #pragma unroll
        for (int q=0;q<3;q++){
            int col = (hf*3+q)*16+lr;
            AT[row*128 + (col^sw2)] = f2bf((outv[q][j]-mn)*rs*gg[col]+bb[col]);
        }
    }
    __syncthreads();
    // fc1 + gelu: 12 nts per wave
    {
        bf16x8 af[3];
        #pragma unroll
        for(int kf=0;kf<3;kf++) af[kf]=*(const bf16x8*)&AT[arow*128+((kf*32+lh*8)^asw)];
        #pragma unroll 2
        for(int q=0;q<12;q++){
            int nt = hf*12 + q;
            f32x4 acc={0.f,0.f,0.f,0.f};
            #pragma unroll
            for(int kf=0;kf<3;kf++){
                bf16x8 b=*(const bf16x8*)(wbf+((size_t)((WOFF6+kf*24+nt)*64+l))*8);
                acc=MFMA16(af[kf],b,acc);
            }
            int col=nt*16+lr;
            float bias=f1b[col];
            #pragma unroll
            for(int j=0;j<4;j++){
                int row=rt*16+lh*4+j;
                HID[row*384 + (col^((row&7)<<3))] = f2bf(gelu_fast(acc[j]+bias));
            }
        }
    }
    __syncthreads();
    // fc2 + final residual write: 3 nts per wave
    {
        bf16x8 afh[12];
        #pragma unroll
        for(int kf=0;kf<12;kf++) afh[kf]=*(const bf16x8*)&HID[arow*384+((kf*32+lh*8)^asw)];
        #pragma unroll
        for(int q=0;q<3;q++){
            int nt = hf*3 + q;
            f32x4 acc={0.f,0.f,0.f,0.f};
            #pragma unroll
            for(int kf=0;kf<12;kf++){
                bf16x8 b=*(const bf16x8*)(wbf+((size_t)((WOFF7+kf*6+nt)*64+l))*8);
                acc=MFMA16(afh[kf],b,acc);
            }
            int col=nt*16+lr;
            float bias=f2b[col];
            #pragma unroll
            for(int j=0;j<4;j++){
                size_t row=row0+rt*16+lh*4+j;
                outr[row*C_+col] = outv[q][j] + acc[j] + bias;
            }
        }
    }
}

extern "C" void kernel_launch(void* const* d_in, const int* in_sizes, int n_in,
                              void* d_out, int out_size, void* d_ws, size_t ws_size,
                              hipStream_t stream)
{
    const float* hs        = (const float*)d_in[0];
    const float* norm_in_g = (const float*)d_in[1];
    const float* norm_in_b = (const float*)d_in[2];
    const float* in_proj_w = (const float*)d_in[3];
    const float* dw_w      = (const float*)d_in[4];
    const float* dw_b      = (const float*)d_in[5];
    const float* qk_w      = (const float*)d_in[6];
    const float* qk_b      = (const float*)d_in[7];
    const float* lepe_w    = (const float*)d_in[8];
    const float* lepe_b    = (const float*)d_in[9];
    const float* conv_x_w  = (const float*)d_in[10];
    const float* conv_z_w  = (const float*)d_in[11];
    const float* x_proj_w  = (const float*)d_in[12];
    const float* dt_proj_w = (const float*)d_in[13];
    const float* dt_proj_b = (const float*)d_in[14];
    const float* A_log     = (const float*)d_in[15];
    const float* Dv        = (const float*)d_in[16];
    const float* out_proj_w= (const float*)d_in[17];
    const float* proj_out_w= (const float*)d_in[18];
    const float* proj_out_b= (const float*)d_in[19];
    const float* out_w     = (const float*)d_in[20];
    const float* out_b     = (const float*)d_in[21];
    const float* norm_mlp_g= (const float*)d_in[22];
    const float* norm_mlp_b= (const float*)d_in[23];
    const float* fc1_w     = (const float*)d_in[24];
    const float* fc1_b     = (const float*)d_in[25];
    const float* fc2_w     = (const float*)d_in[26];
    const float* fc2_b     = (const float*)d_in[27];

    float* ws = (float*)d_ws;
    size_t o = 0;
    float* xx    = ws + o; o += (size_t)BL_*C_;   // -> qbuf after conv1d_xdbl
    float* zz    = ws + o; o += (size_t)BL_*C_;   // -> ybuf after conv1d_xdbl
    float* wwb   = ws + o; o += (size_t)BL_*C_;   // -> aout after dwconv2d
    float* lin_x = ws + o; o += (size_t)BL_*C_;
    float* xs    = ws + o; o += (size_t)BL_*C_;
    float* zs    = ws + o; o += (size_t)BL_*C_;
    float* delta = ws + o; o += (size_t)BL_*C_;
    float* BC    = ws + o; o += (size_t)BL_*32;
    float* Ap    = ws + o; o += (size_t)B_*NCH_*1536;
    float* Be    = ws + o; o += (size_t)B_*NCH_*1536;
    float* Hin   = ws + o; o += (size_t)B_*NCH_*1536;
    float* GA    = ws + o; o += (size_t)B_*NG_*1536;
    float* GB    = ws + o; o += (size_t)B_*NG_*1536;
    float* Gin   = ws + o; o += (size_t)B_*NG_*1536;
    float* kvacc = ws + o; o += 3264;
    float2* ctab = (float2*)(ws + o); o += 6144;
    float* wt9   = ws + o; o += 864;
    float* lw9   = ws + o; o += 864;
    float* wxT   = ws + o; o += 384;
    float* wzT   = ws + o; o += 384;
    unsigned short* wbf = (unsigned short*)(ws + o);

    float* qbuf = xx;
    float* ybuf = zz;
    float* aout = wwb;
    float* outr = (float*)d_out;

    k_setup<<<dim3(72,8), 64, 0, stream>>>(in_proj_w, qk_w, out_proj_w, proj_out_w,
                                           out_w, fc1_w, fc2_w, dw_w, lepe_w,
                                           x_proj_w, conv_x_w, conv_z_w,
                                           wbf, ctab, wt9, lw9, kvacc, wxT, wzT);
    k_ln_inproj_m<<<BL_/64, 256, 0, stream>>>(hs, norm_in_g, norm_in_b, wbf, xx, zz, wwb);
    k_dwconv2d<<<(BL_*24)/256, 256, 0, stream>>>(wwb, wt9, dw_b, lin_x);
    k_conv1d_xdbl<<<BL_/64, 256, 0, stream>>>(xx, zz, wxT, wzT, wbf,
                                              dt_proj_w, dt_proj_b, xs, zs, delta, BC);
    k_qk_kv<<<BL_/64, 256, 0, stream>>>(lin_x, wbf, qk_b, ctab, qbuf, kvacc);
    k_attnout<<<BL_/16, 384, 0, stream>>>(qbuf, lin_x, kvacc, ctab, lw9, lepe_b, aout);
    k_scan1<<<B_*NCH_, 384, 0, stream>>>(delta, xs, BC, A_log, Ap, Be);
    k_scan2a<<<B_*NG_, 384, 0, stream>>>(Ap, Be, GA, GB);
    k_scan2b<<<12, 256, 0, stream>>>(GA, GB, Gin);
    k_scan2c<<<B_*NG_, 384, 0, stream>>>(Ap, Be, Gin, Hin);
    k_scan3<<<B_*NCH_, 384, 0, stream>>>(delta, xs, BC, A_log, Dv, Hin, ybuf);
    k_combine_mlp<<<BL_/64, 512, 0, stream>>>(ybuf, zs, aout, wbf, proj_out_b,
                                              out_b, hs, norm_mlp_g, norm_mlp_b,
                                              fc1_b, fc2_b, outr);
}

// Round 8
// 191.807 us; speedup vs baseline: 3.6535x; 1.0596x over previous
//
#include <hip/hip_runtime.h>
#include <hip/hip_bf16.h>
#include <math.h>

#define B_ 2
#define H_ 128
#define W_ 128
#define C_ 96
#define L_ (H_*W_)
#define BL_ (B_*L_)
#define NH_ 6
#define NPROJ_ 38
#define MLPH_ 384
#define NCH_ 512
#define CHL_ (L_/NCH_)
#define NG_ 32

typedef __attribute__((ext_vector_type(8))) short bf16x8;
typedef __attribute__((ext_vector_type(4))) float f32x4;
typedef __attribute__((ext_vector_type(4))) unsigned short us4v;

#define MFMA16(a,b,c) __builtin_amdgcn_mfma_f32_16x16x32_bf16(a,b,c,0,0,0)

// weight fragment table (each frag = 64 lanes * 8 bf16 = 512 elems)
#define WOFF1 0      // in_proj  96x288 : 3*18 = 54
#define WOFF2 54     // qk_w     96x192 : 3*12 = 36
#define WOFF3 90     // out_proj 192x96 : 6*6  = 36
#define WOFF4 126    // proj_out 96x96  : 3*6  = 18
#define WOFF5 144    // out_w    192x96 : 6*6  = 36
#define WOFF6 180    // fc1      96x384 : 3*24 = 72
#define WOFF7 252    // fc2      384x96 : 12*6 = 72
#define WOFF8 324    // x_proj   96x38(->48 pad) : 3*3 = 9
#define WFRAGS 333

__device__ __forceinline__ float siluf(float x){ return x / (1.f + __expf(-x)); }
__device__ __forceinline__ unsigned short f2bf(float x){
    __hip_bfloat16 h = __float2bfloat16(x);
    return *reinterpret_cast<unsigned short*>(&h);
}
__device__ __forceinline__ unsigned pack2(float a, float b){
    return (unsigned)f2bf(a) | ((unsigned)f2bf(b) << 16);
}
__device__ __forceinline__ float bf2f(unsigned short u){
    return __uint_as_float((unsigned)u << 16);
}
__device__ __forceinline__ float gelu_fast(float x){
    float u_ = 0.7978845608f*x*(1.f + 0.044715f*x*x);
    float au = fabsf(u_);
    float e = __expf(-2.f*au);
    float th = (1.f - e)/(1.f + e);
    th = copysignf(th, u_);
    return 0.5f*x*(1.f + th);
}

// ---------------- K0: setup — weight prep + rope table + misc transposes ----------------
__global__ __launch_bounds__(64) void k_setup(const float* __restrict__ w1,
    const float* __restrict__ w2, const float* __restrict__ w3,
    const float* __restrict__ w4, const float* __restrict__ w5,
    const float* __restrict__ w6, const float* __restrict__ w7,
    const float* __restrict__ dww, const float* __restrict__ lw,
    const float* __restrict__ xpw, const float* __restrict__ cxw,
    const float* __restrict__ czw,
    unsigned short* __restrict__ dst, float2* __restrict__ ctab,
    float* __restrict__ wt9, float* __restrict__ lw9, float* __restrict__ kvacc,
    float* __restrict__ wxT, float* __restrict__ wzT)
{
    int m = blockIdx.y;
    int l = threadIdx.x;
    if (m < 7){
        const float* srcs[7] = {w1,w2,w3,w4,w5,w6,w7};
        const int Ks[7]   = {96,96,192,96,192,96,384};
        const int Ns[7]   = {288,192,96,96,96,384,96};
        const int offs[7] = {WOFF1,WOFF2,WOFF3,WOFF4,WOFF5,WOFF6,WOFF7};
        int f = blockIdx.x;
        int nnt = Ns[m] >> 4, nkf = Ks[m] >> 5;
        if (f >= nnt*nkf) return;
        int kf = f / nnt, nt = f - kf*nnt;
        const float* s = srcs[m];
        unsigned short* d = dst + ((size_t)(offs[m] + f)*64 + l)*8;
        int krow = kf*32 + (l>>4)*8;
        int col  = nt*16 + (l&15);
        #pragma unroll
        for (int j=0;j<8;j++) d[j] = f2bf(s[(size_t)(krow+j)*Ns[m] + col]);
    } else {
        int x = blockIdx.x;
        if (x == 0){
            for (int i=l; i<128*24; i+=64){
                int pos = i/24, p = i%24;
                float th = powf(10000.f, -(float)p/24.f);
                float sn, cs; sincosf((float)pos*th, &sn, &cs);
                ctab[i] = make_float2(cs, sn);
            }
        } else if (x == 1){
            for (int i=l; i<3264; i+=64) kvacc[i] = 0.f;
        } else if (x == 2){
            for (int i=l; i<864; i+=64){
                int c = i/9, tap = i%9;
                wt9[tap*96 + c] = dww[i];
                lw9[tap*96 + c] = lw[i];
            }
        } else if (x == 3){
            for (int f=0; f<9; f++){
                int kf=f/3, nt=f%3;
                unsigned short* d = dst + ((size_t)(WOFF8 + f)*64 + l)*8;
                int krow = kf*32 + (l>>4)*8;
                int col  = nt*16 + (l&15);
                #pragma unroll
                for (int j=0;j<8;j++){
                    float v = (col < NPROJ_) ? xpw[(size_t)(krow+j)*NPROJ_ + col] : 0.f;
                    d[j] = f2bf(v);
                }
            }
        } else if (x == 4){
            for (int i=l; i<384; i+=64){
                int j = i/96, c = i%96;
                wxT[i] = cxw[c*4 + j];
                wzT[i] = czw[c*4 + j];
            }
        }
    }
}

// ---------------- K1: LayerNorm + in_proj (96 -> 288) MFMA, bf16 outputs ----------------
__global__ __launch_bounds__(256) void k_ln_inproj_m(const float* __restrict__ hs,
    const float* __restrict__ gg, const float* __restrict__ bb,
    const unsigned short* __restrict__ wbf,
    unsigned short* __restrict__ xx, unsigned short* __restrict__ zz,
    unsigned short* __restrict__ ww)
{
    __shared__ unsigned short A[64*128];
    int t = threadIdx.x;
    size_t row0 = (size_t)blockIdx.x * 64;
    {
        int r = t >> 2, q = t & 3;
        const float* src = hs + (row0 + r)*C_ + q*24;
        float v[24];
        float s=0.f, s2=0.f;
        #pragma unroll
        for (int i=0;i<24;i++){ float x=src[i]; v[i]=x; s+=x; s2+=x*x; }
        s += __shfl_xor(s,1); s2 += __shfl_xor(s2,1);
        s += __shfl_xor(s,2); s2 += __shfl_xor(s2,2);
        float mn = s*(1.f/C_);
        float rs = rsqrtf(s2*(1.f/C_) - mn*mn + 1e-5f);
        int base = r*128, sw = (r&7)<<3;
        #pragma unroll
        for (int i=0;i<24;i+=2){
            int c = q*24 + i;
            float a0 = (v[i]  -mn)*rs*gg[c]   + bb[c];
            float a1 = (v[i+1]-mn)*rs*gg[c+1] + bb[c+1];
            *(unsigned*)&A[base + (c ^ sw)] = pack2(a0,a1);
        }
    }
    __syncthreads();
    int w = t>>6, l = t&63, lr = l&15, lh = l>>4;
    int arow = w*16 + lr;
    int abase = arow*128, asw = (arow&7)<<3;
    bf16x8 af[3];
    #pragma unroll
    for (int kf=0;kf<3;kf++)
        af[kf] = *(const bf16x8*)&A[abase + ((kf*32 + lh*8) ^ asw)];
    #pragma unroll 2
    for (int nt=0; nt<18; nt++){
        f32x4 acc = {0.f,0.f,0.f,0.f};
        #pragma unroll
        for (int kf=0;kf<3;kf++){
            bf16x8 bf_ = *(const bf16x8*)(wbf + ((size_t)((WOFF1 + kf*18 + nt)*64 + l))*8);
            acc = MFMA16(af[kf], bf_, acc);
        }
        unsigned short* base_;
        if (nt < 6) base_ = xx; else if (nt < 12) base_ = zz; else base_ = ww;
        int col = (nt%6)*16 + lr;
        unsigned short* dst = base_ + (row0 + w*16 + lh*4)*C_ + col;
        #pragma unroll
        for (int j=0;j<4;j++) dst[(size_t)j*C_] = f2bf(acc[j]);
    }
}

// ---------------- K2: depthwise 3x3 conv + silu on ww (bf16 in/out) ----------------
__global__ __launch_bounds__(256) void k_dwconv2d(const unsigned short* __restrict__ wwb,
    const float* __restrict__ wt9, const float* __restrict__ dwb,
    unsigned short* __restrict__ out)
{
    int gid = blockIdx.x*256 + threadIdx.x;   // BL*24
    int row = gid/24, c4 = gid%24; int c = c4*4;
    int b = row >> 14;
    int ll = row & (L_-1);
    int h = ll >> 7, wq = ll & 127;
    float a0=0.f,a1=0.f,a2=0.f,a3=0.f;
    #pragma unroll
    for (int kh=0; kh<3; kh++){
        int hh = h + kh - 1;
        if ((unsigned)hh < 128u){
            int base_row = (b<<14) + (hh<<7);
            #pragma unroll
            for (int kw=0; kw<3; kw++){
                int wp = wq + kw - 1;
                if ((unsigned)wp < 128u){
                    us4v v = *(const us4v*)&wwb[(size_t)(base_row + wp)*C_ + c];
                    float4 wt = *(const float4*)&wt9[(kh*3+kw)*96 + c];
                    a0 += bf2f(v[0])*wt.x; a1 += bf2f(v[1])*wt.y;
                    a2 += bf2f(v[2])*wt.z; a3 += bf2f(v[3])*wt.w;
                }
            }
        }
    }
    float4 bv = *(const float4*)&dwb[c];
    us4v o;
    o[0]=f2bf(siluf(a0+bv.x)); o[1]=f2bf(siluf(a1+bv.y));
    o[2]=f2bf(siluf(a2+bv.z)); o[3]=f2bf(siluf(a3+bv.w));
    *(us4v*)&out[(size_t)row*C_ + c] = o;
}

// ---------------- K3: conv1d+silu + x_proj MFMA + dt_proj/softplus ----------------
__global__ __launch_bounds__(256) void k_conv1d_xdbl(const unsigned short* __restrict__ xxb,
    const unsigned short* __restrict__ zzb, const float* __restrict__ wxT,
    const float* __restrict__ wzT, const unsigned short* __restrict__ wbf,
    const float* __restrict__ dtw, const float* __restrict__ dtb,
    float* __restrict__ xs, unsigned short* __restrict__ zb,
    float* __restrict__ delta, float* __restrict__ BC)
{
    __shared__ unsigned short A[64*128];   // silu(conv1d(x)) bf16, swizzled A-tile
    __shared__ float XD[64][8];            // dt part of x_dbl (cols 0..5)
    __shared__ float dtws[6][96];
    int t = threadIdx.x;
    size_t row0 = (size_t)blockIdx.x * 64;
    int b = (int)(row0 >> 14);
    int l0 = (int)(row0 & 16383);
    for (int i=t; i<576; i+=256) dtws[i/96][i%96] = dtw[i];
    for (int p=t; p<64*24; p+=256){
        int r = p/24, cq = p - r*24, c = cq*4;
        int l = l0 + r;
        float ax0=0.f,ax1=0.f,ax2=0.f,ax3=0.f;
        float az0=0.f,az1=0.f,az2=0.f,az3=0.f;
        #pragma unroll
        for (int j=0;j<4;j++){
            int lq = l - 1 + j;
            if ((unsigned)lq < (unsigned)L_){
                size_t off = ((size_t)(b<<14) + lq)*C_ + c;
                us4v xv = *(const us4v*)&xxb[off];
                us4v zv = *(const us4v*)&zzb[off];
                float4 wx4 = *(const float4*)&wxT[j*96 + c];
                float4 wz4 = *(const float4*)&wzT[j*96 + c];
                ax0 += bf2f(xv[0])*wx4.x; ax1 += bf2f(xv[1])*wx4.y;
                ax2 += bf2f(xv[2])*wx4.z; ax3 += bf2f(xv[3])*wx4.w;
                az0 += bf2f(zv[0])*wz4.x; az1 += bf2f(zv[1])*wz4.y;
                az2 += bf2f(zv[2])*wz4.z; az3 += bf2f(zv[3])*wz4.w;
            }
        }
        ax0=siluf(ax0); ax1=siluf(ax1); ax2=siluf(ax2); ax3=siluf(ax3);
        az0=siluf(az0); az1=siluf(az1); az2=siluf(az2); az3=siluf(az3);
        float4 xo={ax0,ax1,ax2,ax3};
        *(float4*)&xs[(row0+r)*C_ + c] = xo;
        us4v zo; zo[0]=f2bf(az0); zo[1]=f2bf(az1); zo[2]=f2bf(az2); zo[3]=f2bf(az3);
        *(us4v*)&zb[(row0+r)*C_ + c] = zo;
        int sw = (r&7)<<3;
        uint2 pk = { pack2(ax0,ax1), pack2(ax2,ax3) };
        *(uint2*)&A[r*128 + (c ^ sw)] = pk;
    }
    __syncthreads();
    int w=t>>6, l=t&63, lr=l&15, lh=l>>4;
    int arow = w*16+lr, asw=(arow&7)<<3;
    bf16x8 af[3];
    #pragma unroll
    for (int kf=0;kf<3;kf++)
        af[kf] = *(const bf16x8*)&A[arow*128 + ((kf*32 + lh*8) ^ asw)];
    #pragma unroll
    for (int nt=0; nt<3; nt++){
        f32x4 acc={0.f,0.f,0.f,0.f};
        #pragma unroll
        for (int kf=0;kf<3;kf++){
            bf16x8 bfr=*(const bf16x8*)(wbf + ((size_t)((WOFF8 + kf*3 + nt)*64 + l))*8);
            acc = MFMA16(af[kf], bfr, acc);
        }
        int col = nt*16 + lr;
        #pragma unroll
        for (int j=0;j<4;j++){
            int row = w*16 + lh*4 + j;
            if (col < 6) XD[row][col] = acc[j];
            else if (col < NPROJ_) BC[(row0+row)*32 + (col-6)] = acc[j];
        }
    }
    __syncthreads();
    {
        int r = t>>2, q = t&3;
        float xd0=XD[r][0], xd1=XD[r][1], xd2=XD[r][2];
        float xd3=XD[r][3], xd4=XD[r][4], xd5=XD[r][5];
        #pragma unroll
        for (int g=0; g<6; g++){
            int c = q*24 + g*4;
            float4 acc = *(const float4*)&dtb[c];
            float4 w0 = *(const float4*)&dtws[0][c];
            float4 w1 = *(const float4*)&dtws[1][c];
            float4 w2 = *(const float4*)&dtws[2][c];
            float4 w3 = *(const float4*)&dtws[3][c];
            float4 w4 = *(const float4*)&dtws[4][c];
            float4 w5 = *(const float4*)&dtws[5][c];
            acc.x += xd0*w0.x + xd1*w1.x + xd2*w2.x + xd3*w3.x + xd4*w4.x + xd5*w5.x;
            acc.y += xd0*w0.y + xd1*w1.y + xd2*w2.y + xd3*w3.y + xd4*w4.y + xd5*w5.y;
            acc.z += xd0*w0.z + xd1*w1.z + xd2*w2.z + xd3*w3.z + xd4*w4.z + xd5*w5.z;
            acc.w += xd0*w0.w + xd1*w1.w + xd2*w2.w + xd3*w3.w + xd4*w4.w + xd5*w5.w;
            float4 dl;
            dl.x = (acc.x>20.f)? acc.x : __logf(1.f+__expf(acc.x));
            dl.y = (acc.y>20.f)? acc.y : __logf(1.f+__expf(acc.y));
            dl.z = (acc.z>20.f)? acc.z : __logf(1.f+__expf(acc.z));
            dl.w = (acc.w>20.f)? acc.w : __logf(1.f+__expf(acc.w));
            *(float4*)&delta[(row0+r)*C_ + c] = dl;
        }
    }
}

// ---------------- K4: qk MFMA + elu+1 + rope-k + MFMA kv reduce + kmean ----------------
__global__ __launch_bounds__(256) void k_qk_kv(const unsigned short* __restrict__ lin,
    const unsigned short* __restrict__ wbf, const float* __restrict__ qkb,
    const float2* __restrict__ ctab, unsigned short* __restrict__ qo,
    float* __restrict__ kvacc)
{
    __shared__ unsigned short A[64*128];
    __shared__ float KR[64*105];
    __shared__ float kmsum[96];
    int t = threadIdx.x;
    size_t row0 = (size_t)blockIdx.x * 64;
    int b = (int)(row0 >> 14);
    int l0 = (int)(row0 & 16383);
    for (int p = t; p < 64*12; p += 256){
        int r = p/12, c = (p - r*12)*8;
        int sw = (r&7)<<3;
        *(uint4*)&A[r*128 + (c ^ sw)] = *(const uint4*)&lin[(row0+r)*C_ + c];
    }
    if (t < 96) kmsum[t] = 0.f;
    __syncthreads();
    int w=t>>6, l=t&63, lr=l&15, lh=l>>4;
    int arow = w*16+lr; int asw=(arow&7)<<3;
    bf16x8 af[3];
    #pragma unroll
    for (int kf=0;kf<3;kf++)
        af[kf] = *(const bf16x8*)&A[arow*128 + ((kf*32 + lh*8) ^ asw)];
    #pragma unroll 2
    for (int nt=0; nt<12; nt++){
        f32x4 acc={0.f,0.f,0.f,0.f};
        #pragma unroll
        for (int kf=0;kf<3;kf++){
            bf16x8 bfr=*(const bf16x8*)(wbf + ((size_t)((WOFF2 + kf*12 + nt)*64 + l))*8);
            acc = MFMA16(af[kf], bfr, acc);
        }
        int colg = nt*16 + lr;
        float bias = qkb[colg];
        float vv[4];
        #pragma unroll
        for (int j=0;j<4;j++){
            float v = acc[j] + bias;
            vv[j] = (v>0.f)? v+1.f : __expf(v);
        }
        if (nt < 6){
            unsigned short* dp = qo + (row0 + w*16 + lh*4)*C_ + colg;
            #pragma unroll
            for (int j=0;j<4;j++) dp[(size_t)j*C_] = f2bf(vv[j]);
        } else {
            int ck = colg - 96;
            atomicAdd(&kmsum[ck], vv[0]+vv[1]+vv[2]+vv[3]);
            float pv[4];
            #pragma unroll
            for (int j=0;j<4;j++) pv[j] = __shfl_xor(vv[j], 1);
            int p = ck >> 1;
            #pragma unroll
            for (int j=0;j<4;j++){
                int rl = l0 + w*16 + lh*4 + j;
                int hp = rl>>7, wp = rl&127;
                float2 cssn = (p<24)? ctab[hp*24+p] : ctab[wp*24+(p-24)];
                float kr = (ck&1)? (pv[j]*cssn.y + vv[j]*cssn.x)
                                 : (vv[j]*cssn.x - pv[j]*cssn.y);
                KR[(w*16+lh*4+j)*105 + ck] = kr;
            }
        }
    }
    __syncthreads();
    // phase 2: kv[h] = KR^T (16x64) @ V (64x16) via MFMA, all 4 waves
    for (int h = w; h < 6; h += 4){
        f32x4 acc = {0.f,0.f,0.f,0.f};
        #pragma unroll
        for (int kk=0; kk<2; kk++){
            union { bf16x8 v; unsigned short u[8]; } afu, bfu;
            #pragma unroll
            for (int j=0;j<8;j++){
                int rr = kk*32 + lh*8 + j;
                afu.u[j] = f2bf(KR[rr*105 + h*16 + lr]);
                bfu.u[j] = A[rr*128 + ((h*16+lr) ^ ((rr&7)<<3))];
            }
            acc = MFMA16(afu.v, bfu.v, acc);
        }
        #pragma unroll
        for (int i=0;i<4;i++)
            atomicAdd(&kvacc[b*1536 + h*256 + (lh*4+i)*16 + lr], acc[i]);
    }
    if (t < 96) atomicAdd(&kvacc[3072 + b*96 + t], kmsum[t]);
}

// ---------------- K5: attention output -> az = (attn+lepe)*z, bf16 ----------------
__global__ __launch_bounds__(384) void k_attnout(const unsigned short* __restrict__ qb,
    const unsigned short* __restrict__ vb, const unsigned short* __restrict__ zb,
    const float* __restrict__ kvacc, const float2* __restrict__ ctab,
    const float* __restrict__ lw9, const float* __restrict__ lb,
    unsigned short* __restrict__ azb)
{
    __shared__ float kvs[1536];
    __shared__ float kms[96];
    int t = threadIdx.x;
    size_t row0 = (size_t)blockIdx.x * 16;
    int b = (int)(row0 >> 14);
    const float invL = 1.f/16384.f;
    for (int i=t; i<1536; i+=384) kvs[i] = kvacc[b*1536+i]*invL;
    if (t < 96) kms[t] = kvacc[3072+b*96+t]*invL;
    __syncthreads();
    int r = t/24, c4 = t%24;
    int c = c4*4;
    int lrow = (int)(row0 & 16383) + r;
    int hp = lrow>>7, wp = lrow&127;
    size_t row = row0 + r;
    us4v qu = *(const us4v*)&qb[row*C_ + c];
    float q0=bf2f(qu[0]), q1=bf2f(qu[1]), q2=bf2f(qu[2]), q3=bf2f(qu[3]);
    int p0 = c>>1, p1 = p0+1;
    float2 cs0 = (p0<24)? ctab[hp*24+p0] : ctab[wp*24+(p0-24)];
    float2 cs1 = (p1<24)? ctab[hp*24+p1] : ctab[wp*24+(p1-24)];
    float4 qr;
    qr.x = q0*cs0.x - q1*cs0.y;
    qr.y = q0*cs0.y + q1*cs0.x;
    qr.z = q2*cs1.x - q3*cs1.y;
    qr.w = q2*cs1.y + q3*cs1.x;
    int h = c4>>2, j = c4&3;
    int dbase = j*4;
    float zp = q0*kms[h*16+dbase]   + q1*kms[h*16+dbase+1]
             + q2*kms[h*16+dbase+2] + q3*kms[h*16+dbase+3];
    zp += __shfl_xor(zp,1);
    zp += __shfl_xor(zp,2);
    float zd = 1.f/(zp + 1e-6f);
    float4 o = {0.f,0.f,0.f,0.f};
    #pragma unroll
    for (int g=0; g<4; g++){
        float4 qg;
        if (g==0) qg = qr;
        else {
            qg.x=__shfl_xor(qr.x,g); qg.y=__shfl_xor(qr.y,g);
            qg.z=__shfl_xor(qr.z,g); qg.w=__shfl_xor(qr.w,g);
        }
        int db = ((j^g)<<2);
        const float* kp = &kvs[h*256 + db*16 + j*4];
        #pragma unroll
        for (int i=0;i<4;i++){
            float qi = (i==0)?qg.x:(i==1)?qg.y:(i==2)?qg.z:qg.w;
            float4 kv4 = *(const float4*)&kp[i*16];
            o.x += qi*kv4.x; o.y += qi*kv4.y;
            o.z += qi*kv4.z; o.w += qi*kv4.w;
        }
    }
    float4 acc = *(const float4*)&lb[c];
    #pragma unroll
    for (int kh=0; kh<3; kh++){
        int hh = hp + kh - 1;
        if ((unsigned)hh < 128u){
            int base_row = (b<<14) + (hh<<7);
            #pragma unroll
            for (int kw=0; kw<3; kw++){
                int wq = wp + kw - 1;
                if ((unsigned)wq < 128u){
                    us4v v = *(const us4v*)&vb[(size_t)(base_row + wq)*C_ + c];
                    float4 wt = *(const float4*)&lw9[(kh*3+kw)*96 + c];
                    acc.x += bf2f(v[0])*wt.x; acc.y += bf2f(v[1])*wt.y;
                    acc.z += bf2f(v[2])*wt.z; acc.w += bf2f(v[3])*wt.w;
                }
            }
        }
    }
    us4v zu = *(const us4v*)&zb[row*C_ + c];
    us4v res;
    res[0] = f2bf((o.x*zd + acc.x)*bf2f(zu[0]));
    res[1] = f2bf((o.y*zd + acc.y)*bf2f(zu[1]));
    res[2] = f2bf((o.z*zd + acc.z)*bf2f(zu[2]));
    res[3] = f2bf((o.w*zd + acc.w)*bf2f(zu[3]));
    *(us4v*)&azb[row*C_ + c] = res;
}

// ---------------- K6a: scan pass1 — per-chunk aggregates, 4 states/thread ----------------
__global__ __launch_bounds__(384) void k_scan1(const float* __restrict__ delta,
    const float* __restrict__ xs, const float* __restrict__ BC,
    const float* __restrict__ A_log, float* __restrict__ Ap, float* __restrict__ Be)
{
    int t = threadIdx.x; int nq = t&3, c = t>>2;
    int blk = blockIdx.x; int b = blk>>9, ch = blk&(NCH_-1);
    float4 a4 = *(const float4*)&A_log[c*16 + nq*4];
    float a0=-__expf(a4.x), a1=-__expf(a4.y), a2=-__expf(a4.z), a3=-__expf(a4.w);
    float ap0=1.f,ap1=1.f,ap2=1.f,ap3=1.f;
    float be0=0.f,be1=0.f,be2=0.f,be3=0.f;
    size_t base = ((size_t)b<<14) + ch*CHL_;
    for (int i=0;i<CHL_;i++){
        size_t row = base + i;
        float dl = delta[row*C_+c];
        float u  = xs[row*C_+c];
        float du = dl*u;
        float4 bc = *(const float4*)&BC[row*32 + nq*4];
        float e0=__expf(dl*a0), e1=__expf(dl*a1), e2=__expf(dl*a2), e3=__expf(dl*a3);
        ap0*=e0; be0=be0*e0+du*bc.x;
        ap1*=e1; be1=be1*e1+du*bc.y;
        ap2*=e2; be2=be2*e2+du*bc.z;
        ap3*=e3; be3=be3*e3+du*bc.w;
    }
    size_t o = (size_t)blk*1536 + c*16 + nq*4;
    float4 apv={ap0,ap1,ap2,ap3}, bev={be0,be1,be2,be3};
    *(float4*)&Ap[o] = apv;
    *(float4*)&Be[o] = bev;
}

// ---------------- K6b: group aggregates (16 chunks/group) ----------------
__global__ __launch_bounds__(384) void k_scan2a(const float* __restrict__ Ap,
    const float* __restrict__ Be, float* __restrict__ GA, float* __restrict__ GB)
{
    int t = threadIdx.x; int blk = blockIdx.x;  // B*NG
    int b = blk>>5, g = blk&(NG_-1);
    int idx = (t>>2)*16 + (t&3)*4;
    float4 A = {1.f,1.f,1.f,1.f}, Bv = {0.f,0.f,0.f,0.f};
    for (int j=0;j<16;j++){
        size_t o = ((size_t)(b*NCH_ + g*16 + j))*1536 + idx;
        float4 a = *(const float4*)&Ap[o];
        float4 bb = *(const float4*)&Be[o];
        Bv.x=a.x*Bv.x+bb.x; Bv.y=a.y*Bv.y+bb.y; Bv.z=a.z*Bv.z+bb.z; Bv.w=a.w*Bv.w+bb.w;
        A.x*=a.x; A.y*=a.y; A.z*=a.z; A.w*=a.w;
    }
    size_t o = (size_t)blk*1536 + idx;
    *(float4*)&GA[o] = A;
    *(float4*)&GB[o] = Bv;
}

// ---------------- K6c: sequential over NG groups ----------------
__global__ __launch_bounds__(256) void k_scan2b(const float* __restrict__ GA,
    const float* __restrict__ GB, float* __restrict__ Gin)
{
    int t = blockIdx.x*256 + threadIdx.x;  // 3072
    int b = t/1536, m = t%1536;
    float h = 0.f;
    for (int g=0; g<NG_; g++){
        size_t o = ((size_t)(b*NG_+g))*1536 + m;
        Gin[o] = h;
        h = GA[o]*h + GB[o];
    }
}

// ---------------- K6d: within-group chunk-incoming states ----------------
__global__ __launch_bounds__(384) void k_scan2c(const float* __restrict__ Ap,
    const float* __restrict__ Be, const float* __restrict__ Gin,
    float* __restrict__ Hin)
{
    int t = threadIdx.x; int blk = blockIdx.x;  // B*NG
    int b = blk>>5, g = blk&(NG_-1);
    int idx = (t>>2)*16 + (t&3)*4;
    float4 h = *(const float4*)&Gin[(size_t)blk*1536 + idx];
    for (int j=0;j<16;j++){
        size_t o = ((size_t)(b*NCH_ + g*16 + j))*1536 + idx;
        *(float4*)&Hin[o] = h;
        float4 a = *(const float4*)&Ap[o];
        float4 bb = *(const float4*)&Be[o];
        h.x=a.x*h.x+bb.x; h.y=a.y*h.y+bb.y; h.z=a.z*h.z+bb.z; h.w=a.w*h.w+bb.w;
    }
}

// ---------------- K6e: scan pass3 — replay + emit y (bf16) ----------------
__global__ __launch_bounds__(384) void k_scan3(const float* __restrict__ delta,
    const float* __restrict__ xs, const float* __restrict__ BC,
    const float* __restrict__ A_log, const float* __restrict__ Dv,
    const float* __restrict__ Hin, unsigned short* __restrict__ y)
{
    int t = threadIdx.x; int nq = t&3, c = t>>2;
    int blk = blockIdx.x; int b = blk>>9, ch = blk&(NCH_-1);
    float4 a4 = *(const float4*)&A_log[c*16 + nq*4];
    float a0=-__expf(a4.x), a1=-__expf(a4.y), a2=-__expf(a4.z), a3=-__expf(a4.w);
    float4 h = *(const float4*)&Hin[(size_t)blk*1536 + c*16 + nq*4];
    float Dc = Dv[c];
    size_t base = ((size_t)b<<14) + ch*CHL_;
    for (int i=0;i<CHL_;i++){
        size_t row = base + i;
        float dl = delta[row*C_+c];
        float u  = xs[row*C_+c];
        float du = dl*u;
        float4 bcB = *(const float4*)&BC[row*32 + nq*4];
        float4 bcC = *(const float4*)&BC[row*32 + 16 + nq*4];
        float e0=__expf(dl*a0), e1=__expf(dl*a1), e2=__expf(dl*a2), e3=__expf(dl*a3);
        h.x=h.x*e0+du*bcB.x; h.y=h.y*e1+du*bcB.y;
        h.z=h.z*e2+du*bcB.z; h.w=h.w*e3+du*bcB.w;
        float yv = h.x*bcC.x + h.y*bcC.y + h.z*bcC.z + h.w*bcC.w;
        yv += __shfl_xor(yv,1);
        yv += __shfl_xor(yv,2);
        if (nq == 0) y[row*C_+c] = f2bf(yv + Dc*u);
    }
}

// ---------------- K7: combine + LN + MLP, fused, global bf16 A-fragments ----------------
__global__ __launch_bounds__(512) void k_combine_mlp(const unsigned short* __restrict__ yb,
    const unsigned short* __restrict__ zb, const unsigned short* __restrict__ azb,
    const unsigned short* __restrict__ wbf, const float* __restrict__ pob,
    const float* __restrict__ outb, const float* __restrict__ hs,
    const float* __restrict__ gg, const float* __restrict__ bb,
    const float* __restrict__ f1b, const float* __restrict__ f2b,
    float* __restrict__ outr)
{
    __shared__ __attribute__((aligned(16))) char POOL[65536];
    __shared__ float LNS[64][2], LNS2[64][2];
    unsigned short* C2 = (unsigned short*)POOL;            // 0..24576 phase A
    unsigned short* AT = (unsigned short*)POOL;            // 0..16384 phase B
    unsigned short* HID= (unsigned short*)(POOL + 16384);  // 16384..65536 phase B
    int t=threadIdx.x;
    size_t row0=(size_t)blockIdx.x*64;
    int w=t>>6, l=t&63, lr=l&15, lh=l>>4;
    int rt=w>>1, hf=w&1;
    int arow=rt*16+lr; int asw=(arow&7)<<3;
    size_t gbase = (row0+arow)*C_;
    bf16x8 af1[6], af2[3];
    #pragma unroll
    for (int kf=0;kf<3;kf++){
        af1[kf]   = *(const bf16x8*)&yb[gbase + kf*32 + lh*8];
        af1[3+kf] = *(const bf16x8*)&zb[gbase + kf*32 + lh*8];
        af2[kf]   = *(const bf16x8*)&azb[gbase + kf*32 + lh*8];
    }
    #pragma unroll
    for (int q=0;q<3;q++){
        int nt = hf*3 + q;
        f32x4 a1={0.f,0.f,0.f,0.f}, a2={0.f,0.f,0.f,0.f};
        #pragma unroll
        for (int kf=0;kf<6;kf++){
            bf16x8 b=*(const bf16x8*)(wbf+((size_t)((WOFF3+kf*6+nt)*64+l))*8);
            a1=MFMA16(af1[kf],b,a1);
        }
        #pragma unroll
        for (int kf=0;kf<3;kf++){
            bf16x8 b=*(const bf16x8*)(wbf+((size_t)((WOFF4+kf*6+nt)*64+l))*8);
            a2=MFMA16(af2[kf],b,a2);
        }
        int col=nt*16+lr;
        float pb=pob[col];
        #pragma unroll
        for (int j=0;j<4;j++){
            int row=rt*16+lh*4+j;
            int sw2=(row&7)<<3;
            C2[row*192 + (col^sw2)] = f2bf(a1[j]);
            C2[row*192 + ((96+col)^sw2)] = f2bf(a2[j]+pb);
        }
    }
    __syncthreads();   // b1: C2 complete
    bf16x8 af3[6];
    #pragma unroll
    for (int kf=0;kf<6;kf++) af3[kf]=*(const bf16x8*)&C2[arow*192 + ((kf*32+lh*8)^asw)];
    float outv[3][4];
    #pragma unroll
    for (int q=0;q<3;q++){
        int nt = hf*3 + q;
        f32x4 acc={0.f,0.f,0.f,0.f};
        #pragma unroll
        for (int kf=0;kf<6;kf++){
            bf16x8 b=*(const bf16x8*)(wbf+((size_t)((WOFF5+kf*6+nt)*64+l))*8);
            acc=MFMA16(af3[kf],b,acc);
        }
        int col=nt*16+lr;
        float ob=outb[col];
        #pragma unroll
        for (int j=0;j<4;j++){
            size_t row=row0+rt*16+lh*4+j;
            outv[q][j] = acc[j] + ob + hs[row*C_+col];
        }
    }
    // LN partials
    float s_[4], s2_[4];
    #pragma unroll
    for (int j=0;j<4;j++){
        float s=0.f, s2=0.f;
        #pragma unroll
        for (int q=0;q<3;q++){ float v=outv[q][j]; s+=v; s2+=v*v; }
        s_[j]=s; s2_[j]=s2;
    }
    #pragma unroll
    for (int m=1;m<16;m<<=1){
        #pragma unroll
        for (int j=0;j<4;j++){
            s_[j]  += __shfl_xor(s_[j],  m);
            s2_[j] += __shfl_xor(s2_[j], m);
        }
    }
    if (lr==0){
        #pragma unroll
        for (int j=0;j<4;j++){
            int row = rt*16+lh*4+j;
            LNS[row][hf]  = s_[j];
            LNS2[row][hf] = s2_[j];
        }
    }
    __syncthreads();   // b2: af3 consumed, LNS visible
    #pragma unroll
    for (int j=0;j<4;j++){
        int row = rt*16+lh*4+j;
        float s  = LNS[row][0]  + LNS[row][1];
        float s2 = LNS2[row][0] + LNS2[row][1];
        float mn = s*(1.f/C_);
        float rs = rsqrtf(s2*(1.f/C_) - mn*mn + 1e-5f);
        int sw2 = (row&7)<<3;
        #pragma unroll
        for (int q=0;q<3;q++){
            int col = (hf*3+q)*16+lr;
            AT[row*128 + (col^sw2)] = f2bf((outv[q][j]-mn)*rs*gg[col]+bb[col]);
        }
    }
    __syncthreads();   // b3: AT complete
    {
        bf16x8 af[3];
        #pragma unroll
        for(int kf=0;kf<3;kf++) af[kf]=*(const bf16x8*)&AT[arow*128+((kf*32+lh*8)^asw)];
        #pragma unroll 2
        for(int q=0;q<12;q++){
            int nt = hf*12 + q;
            f32x4 acc={0.f,0.f,0.f,0.f};
            #pragma unroll
            for(int kf=0;kf<3;kf++){
                bf16x8 b=*(const bf16x8*)(wbf+((size_t)((WOFF6+kf*24+nt)*64+l))*8);
                acc=MFMA16(af[kf],b,acc);
            }
            int col=nt*16+lr;
            float bias=f1b[col];
            #pragma unroll
            for(int j=0;j<4;j++){
                int row=rt*16+lh*4+j;
                HID[row*384 + (col^((row&7)<<3))] = f2bf(gelu_fast(acc[j]+bias));
            }
        }
    }
    __syncthreads();   // b4: HID complete
    {
        bf16x8 afh[12];
        #pragma unroll
        for(int kf=0;kf<12;kf++) afh[kf]=*(const bf16x8*)&HID[arow*384+((kf*32+lh*8)^asw)];
        #pragma unroll
        for(int q=0;q<3;q++){
            int nt = hf*3 + q;
            f32x4 acc={0.f,0.f,0.f,0.f};
            #pragma unroll
            for(int kf=0;kf<12;kf++){
                bf16x8 b=*(const bf16x8*)(wbf+((size_t)((WOFF7+kf*6+nt)*64+l))*8);
                acc=MFMA16(afh[kf],b,acc);
            }
            int col=nt*16+lr;
            float bias=f2b[col];
            #pragma unroll
            for(int j=0;j<4;j++){
                size_t row=row0+rt*16+lh*4+j;
                outr[row*C_+col] = outv[q][j] + acc[j] + bias;
            }
        }
    }
}

extern "C" void kernel_launch(void* const* d_in, const int* in_sizes, int n_in,
                              void* d_out, int out_size, void* d_ws, size_t ws_size,
                              hipStream_t stream)
{
    const float* hs        = (const float*)d_in[0];
    const float* norm_in_g = (const float*)d_in[1];
    const float* norm_in_b = (const float*)d_in[2];
    const float* in_proj_w = (const float*)d_in[3];
    const float* dw_w      = (const float*)d_in[4];
    const float* dw_b      = (const float*)d_in[5];
    const float* qk_w      = (const float*)d_in[6];
    const float* qk_b      = (const float*)d_in[7];
    const float* lepe_w    = (const float*)d_in[8];
    const float* lepe_b    = (const float*)d_in[9];
    const float* conv_x_w  = (const float*)d_in[10];
    const float* conv_z_w  = (const float*)d_in[11];
    const float* x_proj_w  = (const float*)d_in[12];
    const float* dt_proj_w = (const float*)d_in[13];
    const float* dt_proj_b = (const float*)d_in[14];
    const float* A_log     = (const float*)d_in[15];
    const float* Dv        = (const float*)d_in[16];
    const float* out_proj_w= (const float*)d_in[17];
    const float* proj_out_w= (const float*)d_in[18];
    const float* proj_out_b= (const float*)d_in[19];
    const float* out_w     = (const float*)d_in[20];
    const float* out_b     = (const float*)d_in[21];
    const float* norm_mlp_g= (const float*)d_in[22];
    const float* norm_mlp_b= (const float*)d_in[23];
    const float* fc1_w     = (const float*)d_in[24];
    const float* fc1_b     = (const float*)d_in[25];
    const float* fc2_w     = (const float*)d_in[26];
    const float* fc2_b     = (const float*)d_in[27];

    float* ws = (float*)d_ws;
    size_t o = 0;
    const size_t USH = (size_t)BL_*C_/2;   // one bf16 buffer in float units
    unsigned short* xxb  = (unsigned short*)(ws + o); o += USH;  // -> qb after conv1d
    unsigned short* zzb  = (unsigned short*)(ws + o); o += USH;  // -> yb after conv1d
    unsigned short* wwb  = (unsigned short*)(ws + o); o += USH;  // -> azb after dwconv
    unsigned short* linb = (unsigned short*)(ws + o); o += USH;
    unsigned short* zbuf = (unsigned short*)(ws + o); o += USH;
    float* xs    = ws + o; o += (size_t)BL_*C_;
    float* delta = ws + o; o += (size_t)BL_*C_;
    float* BC    = ws + o; o += (size_t)BL_*32;
    float* Ap    = ws + o; o += (size_t)B_*NCH_*1536;
    float* Be    = ws + o; o += (size_t)B_*NCH_*1536;
    float* Hin   = ws + o; o += (size_t)B_*NCH_*1536;
    float* GA    = ws + o; o += (size_t)B_*NG_*1536;
    float* GB    = ws + o; o += (size_t)B_*NG_*1536;
    float* Gin   = ws + o; o += (size_t)B_*NG_*1536;
    float* kvacc = ws + o; o += 3264;
    float2* ctab = (float2*)(ws + o); o += 6144;
    float* wt9   = ws + o; o += 864;
    float* lw9   = ws + o; o += 864;
    float* wxT   = ws + o; o += 384;
    float* wzT   = ws + o; o += 384;
    unsigned short* wbf = (unsigned short*)(ws + o);

    unsigned short* qb  = xxb;   // conv1d consumed xxb before qk_kv writes qb
    unsigned short* yb  = zzb;   // conv1d consumed zzb before scan3 writes yb
    unsigned short* azb = wwb;   // dwconv consumed wwb before attnout writes azb
    float* outr = (float*)d_out;

    k_setup<<<dim3(72,8), 64, 0, stream>>>(in_proj_w, qk_w, out_proj_w, proj_out_w,
                                           out_w, fc1_w, fc2_w, dw_w, lepe_w,
                                           x_proj_w, conv_x_w, conv_z_w,
                                           wbf, ctab, wt9, lw9, kvacc, wxT, wzT);
    k_ln_inproj_m<<<BL_/64, 256, 0, stream>>>(hs, norm_in_g, norm_in_b, wbf,
                                              xxb, zzb, wwb);
    k_dwconv2d<<<(BL_*24)/256, 256, 0, stream>>>(wwb, wt9, dw_b, linb);
    k_conv1d_xdbl<<<BL_/64, 256, 0, stream>>>(xxb, zzb, wxT, wzT, wbf,
                                              dt_proj_w, dt_proj_b, xs, zbuf, delta, BC);
    k_qk_kv<<<BL_/64, 256, 0, stream>>>(linb, wbf, qk_b, ctab, qb, kvacc);
    k_attnout<<<BL_/16, 384, 0, stream>>>(qb, linb, zbuf, kvacc, ctab, lw9, lepe_b, azb);
    k_scan1<<<B_*NCH_, 384, 0, stream>>>(delta, xs, BC, A_log, Ap, Be);
    k_scan2a<<<B_*NG_, 384, 0, stream>>>(Ap, Be, GA, GB);
    k_scan2b<<<12, 256, 0, stream>>>(GA, GB, Gin);
    k_scan2c<<<B_*NG_, 384, 0, stream>>>(Ap, Be, Gin, Hin);
    k_scan3<<<B_*NCH_, 384, 0, stream>>>(delta, xs, BC, A_log, Dv, Hin, yb);
    k_combine_mlp<<<BL_/64, 512, 0, stream>>>(yb, zbuf, azb, wbf, proj_out_b,
                                              out_b, hs, norm_mlp_g, norm_mlp_b,
                                              fc1_b, fc2_b, outr);
}

// Round 9
// 185.455 us; speedup vs baseline: 3.7786x; 1.0342x over previous
//
#include <hip/hip_runtime.h>
#include <hip/hip_bf16.h>
#include <hip/hip_fp16.h>
#include <math.h>

#define B_ 2
#define H_ 128
#define W_ 128
#define C_ 96
#define L_ (H_*W_)
#define BL_ (B_*L_)
#define NH_ 6
#define NPROJ_ 38
#define MLPH_ 384
#define NCH_ 512
#define CHL_ (L_/NCH_)
#define NG_ 32

typedef __attribute__((ext_vector_type(8))) short bf16x8;
typedef __attribute__((ext_vector_type(4))) float f32x4;
typedef __attribute__((ext_vector_type(4))) unsigned short us4v;

#define MFMA16(a,b,c) __builtin_amdgcn_mfma_f32_16x16x32_bf16(a,b,c,0,0,0)

// weight fragment table (each frag = 64 lanes * 8 bf16 = 512 elems)
#define WOFF1 0      // in_proj  96x288 : 3*18 = 54
#define WOFF2 54     // qk_w     96x192 : 3*12 = 36
#define WOFF3 90     // out_proj 192x96 : 6*6  = 36
#define WOFF4 126    // proj_out 96x96  : 3*6  = 18
#define WOFF5 144    // out_w    192x96 : 6*6  = 36
#define WOFF6 180    // fc1      96x384 : 3*24 = 72
#define WOFF7 252    // fc2      384x96 : 12*6 = 72
#define WOFF8 324    // x_proj   96x38(->48 pad) : 3*3 = 9
#define WFRAGS 333

__device__ __forceinline__ float siluf(float x){ return x / (1.f + __expf(-x)); }
__device__ __forceinline__ unsigned short f2bf(float x){
    __hip_bfloat16 h = __float2bfloat16(x);
    return *reinterpret_cast<unsigned short*>(&h);
}
__device__ __forceinline__ unsigned pack2(float a, float b){
    return (unsigned)f2bf(a) | ((unsigned)f2bf(b) << 16);
}
__device__ __forceinline__ float bf2f(unsigned short u){
    return __uint_as_float((unsigned)u << 16);
}
__device__ __forceinline__ unsigned short f2h(float x){
    __half h = __float2half(x);
    return *reinterpret_cast<unsigned short*>(&h);
}
__device__ __forceinline__ float h2f(unsigned short u){
    __half h = *reinterpret_cast<__half*>(&u);
    return __half2float(h);
}
__device__ __forceinline__ float gelu_fast(float x){
    float u_ = 0.7978845608f*x*(1.f + 0.044715f*x*x);
    float au = fabsf(u_);
    float e = __expf(-2.f*au);
    float th = (1.f - e)/(1.f + e);
    th = copysignf(th, u_);
    return 0.5f*x*(1.f + th);
}

// ---------------- K0: setup — weight prep + rope table + misc transposes ----------------
__global__ __launch_bounds__(64) void k_setup(const float* __restrict__ w1,
    const float* __restrict__ w2, const float* __restrict__ w3,
    const float* __restrict__ w4, const float* __restrict__ w5,
    const float* __restrict__ w6, const float* __restrict__ w7,
    const float* __restrict__ dww, const float* __restrict__ lw,
    const float* __restrict__ xpw, const float* __restrict__ cxw,
    const float* __restrict__ czw,
    unsigned short* __restrict__ dst, float2* __restrict__ ctab,
    float* __restrict__ wt9, float* __restrict__ lw9, float* __restrict__ kvacc,
    float* __restrict__ wxT, float* __restrict__ wzT)
{
    int m = blockIdx.y;
    int l = threadIdx.x;
    if (m < 7){
        const float* srcs[7] = {w1,w2,w3,w4,w5,w6,w7};
        const int Ks[7]   = {96,96,192,96,192,96,384};
        const int Ns[7]   = {288,192,96,96,96,384,96};
        const int offs[7] = {WOFF1,WOFF2,WOFF3,WOFF4,WOFF5,WOFF6,WOFF7};
        int f = blockIdx.x;
        int nnt = Ns[m] >> 4, nkf = Ks[m] >> 5;
        if (f >= nnt*nkf) return;
        int kf = f / nnt, nt = f - kf*nnt;
        const float* s = srcs[m];
        unsigned short* d = dst + ((size_t)(offs[m] + f)*64 + l)*8;
        int krow = kf*32 + (l>>4)*8;
        int col  = nt*16 + (l&15);
        #pragma unroll
        for (int j=0;j<8;j++) d[j] = f2bf(s[(size_t)(krow+j)*Ns[m] + col]);
    } else {
        int x = blockIdx.x;
        if (x == 0){
            for (int i=l; i<128*24; i+=64){
                int pos = i/24, p = i%24;
                float th = powf(10000.f, -(float)p/24.f);
                float sn, cs; sincosf((float)pos*th, &sn, &cs);
                ctab[i] = make_float2(cs, sn);
            }
        } else if (x == 1){
            for (int i=l; i<3264; i+=64) kvacc[i] = 0.f;
        } else if (x == 2){
            for (int i=l; i<864; i+=64){
                int c = i/9, tap = i%9;
                wt9[tap*96 + c] = dww[i];
                lw9[tap*96 + c] = lw[i];
            }
        } else if (x == 3){
            for (int f=0; f<9; f++){
                int kf=f/3, nt=f%3;
                unsigned short* d = dst + ((size_t)(WOFF8 + f)*64 + l)*8;
                int krow = kf*32 + (l>>4)*8;
                int col  = nt*16 + (l&15);
                #pragma unroll
                for (int j=0;j<8;j++){
                    float v = (col < NPROJ_) ? xpw[(size_t)(krow+j)*NPROJ_ + col] : 0.f;
                    d[j] = f2bf(v);
                }
            }
        } else if (x == 4){
            for (int i=l; i<384; i+=64){
                int j = i/96, c = i%96;
                wxT[i] = cxw[c*4 + j];
                wzT[i] = czw[c*4 + j];
            }
        }
    }
}

// ---------------- K1: LayerNorm + in_proj (96 -> 288) MFMA, bf16 outputs ----------------
__global__ __launch_bounds__(256) void k_ln_inproj_m(const float* __restrict__ hs,
    const float* __restrict__ gg, const float* __restrict__ bb,
    const unsigned short* __restrict__ wbf,
    unsigned short* __restrict__ xx, unsigned short* __restrict__ zz,
    unsigned short* __restrict__ ww)
{
    __shared__ unsigned short A[64*128];
    int t = threadIdx.x;
    size_t row0 = (size_t)blockIdx.x * 64;
    {
        int r = t >> 2, q = t & 3;
        const float* src = hs + (row0 + r)*C_ + q*24;
        float v[24];
        float s=0.f, s2=0.f;
        #pragma unroll
        for (int i=0;i<24;i++){ float x=src[i]; v[i]=x; s+=x; s2+=x*x; }
        s += __shfl_xor(s,1); s2 += __shfl_xor(s2,1);
        s += __shfl_xor(s,2); s2 += __shfl_xor(s2,2);
        float mn = s*(1.f/C_);
        float rs = rsqrtf(s2*(1.f/C_) - mn*mn + 1e-5f);
        int base = r*128, sw = (r&7)<<3;
        #pragma unroll
        for (int i=0;i<24;i+=2){
            int c = q*24 + i;
            float a0 = (v[i]  -mn)*rs*gg[c]   + bb[c];
            float a1 = (v[i+1]-mn)*rs*gg[c+1] + bb[c+1];
            *(unsigned*)&A[base + (c ^ sw)] = pack2(a0,a1);
        }
    }
    __syncthreads();
    int w = t>>6, l = t&63, lr = l&15, lh = l>>4;
    int arow = w*16 + lr;
    int abase = arow*128, asw = (arow&7)<<3;
    bf16x8 af[3];
    #pragma unroll
    for (int kf=0;kf<3;kf++)
        af[kf] = *(const bf16x8*)&A[abase + ((kf*32 + lh*8) ^ asw)];
    #pragma unroll 2
    for (int nt=0; nt<18; nt++){
        f32x4 acc = {0.f,0.f,0.f,0.f};
        #pragma unroll
        for (int kf=0;kf<3;kf++){
            bf16x8 bf_ = *(const bf16x8*)(wbf + ((size_t)((WOFF1 + kf*18 + nt)*64 + l))*8);
            acc = MFMA16(af[kf], bf_, acc);
        }
        unsigned short* base_;
        if (nt < 6) base_ = xx; else if (nt < 12) base_ = zz; else base_ = ww;
        int col = (nt%6)*16 + lr;
        unsigned short* dst = base_ + (row0 + w*16 + lh*4)*C_ + col;
        #pragma unroll
        for (int j=0;j<4;j++) dst[(size_t)j*C_] = f2bf(acc[j]);
    }
}

// ---------------- K2: depthwise 3x3 conv + silu on ww (bf16 in/out) ----------------
__global__ __launch_bounds__(256) void k_dwconv2d(const unsigned short* __restrict__ wwb,
    const float* __restrict__ wt9, const float* __restrict__ dwb,
    unsigned short* __restrict__ out)
{
    int gid = blockIdx.x*256 + threadIdx.x;   // BL*24
    int row = gid/24, c4 = gid%24; int c = c4*4;
    int b = row >> 14;
    int ll = row & (L_-1);
    int h = ll >> 7, wq = ll & 127;
    float a0=0.f,a1=0.f,a2=0.f,a3=0.f;
    #pragma unroll
    for (int kh=0; kh<3; kh++){
        int hh = h + kh - 1;
        if ((unsigned)hh < 128u){
            int base_row = (b<<14) + (hh<<7);
            #pragma unroll
            for (int kw=0; kw<3; kw++){
                int wp = wq + kw - 1;
                if ((unsigned)wp < 128u){
                    us4v v = *(const us4v*)&wwb[(size_t)(base_row + wp)*C_ + c];
                    float4 wt = *(const float4*)&wt9[(kh*3+kw)*96 + c];
                    a0 += bf2f(v[0])*wt.x; a1 += bf2f(v[1])*wt.y;
                    a2 += bf2f(v[2])*wt.z; a3 += bf2f(v[3])*wt.w;
                }
            }
        }
    }
    float4 bv = *(const float4*)&dwb[c];
    us4v o;
    o[0]=f2bf(siluf(a0+bv.x)); o[1]=f2bf(siluf(a1+bv.y));
    o[2]=f2bf(siluf(a2+bv.z)); o[3]=f2bf(siluf(a3+bv.w));
    *(us4v*)&out[(size_t)row*C_ + c] = o;
}

// ---------------- K3: conv1d+silu + x_proj MFMA + dt_proj + fused chunk-scan ----------------
__global__ __launch_bounds__(384) void k_conv1d_xdbl(const unsigned short* __restrict__ xxb,
    const unsigned short* __restrict__ zzb, const float* __restrict__ wxT,
    const float* __restrict__ wzT, const unsigned short* __restrict__ wbf,
    const float* __restrict__ dtw, const float* __restrict__ dtb,
    const float* __restrict__ A_log,
    unsigned short* __restrict__ xsb, unsigned short* __restrict__ zb,
    unsigned short* __restrict__ dlh, float* __restrict__ BC,
    float* __restrict__ Ap, float* __restrict__ Be)
{
    __shared__ unsigned short A[64*128];   // silu(conv1d(x)) bf16, swizzled (u source)
    __shared__ float XD[64][8];            // dt part of x_dbl (cols 0..5)
    __shared__ float dtws[6][96];
    __shared__ float sdl[64][96];          // delta fp32
    __shared__ float sbc[64][32];          // B,C rows
    int t = threadIdx.x;
    size_t row0 = (size_t)blockIdx.x * 64;
    int b = (int)(row0 >> 14);
    int l0 = (int)(row0 & 16383);
    for (int i=t; i<576; i+=384) dtws[i/96][i%96] = dtw[i];
    // phase 1: conv1d + silu
    for (int p=t; p<64*24; p+=384){
        int r = p/24, cq = p - r*24, c = cq*4;
        int l = l0 + r;
        float ax0=0.f,ax1=0.f,ax2=0.f,ax3=0.f;
        float az0=0.f,az1=0.f,az2=0.f,az3=0.f;
        #pragma unroll
        for (int j=0;j<4;j++){
            int lq = l - 1 + j;
            if ((unsigned)lq < (unsigned)L_){
                size_t off = ((size_t)(b<<14) + lq)*C_ + c;
                us4v xv = *(const us4v*)&xxb[off];
                us4v zv = *(const us4v*)&zzb[off];
                float4 wx4 = *(const float4*)&wxT[j*96 + c];
                float4 wz4 = *(const float4*)&wzT[j*96 + c];
                ax0 += bf2f(xv[0])*wx4.x; ax1 += bf2f(xv[1])*wx4.y;
                ax2 += bf2f(xv[2])*wx4.z; ax3 += bf2f(xv[3])*wx4.w;
                az0 += bf2f(zv[0])*wz4.x; az1 += bf2f(zv[1])*wz4.y;
                az2 += bf2f(zv[2])*wz4.z; az3 += bf2f(zv[3])*wz4.w;
            }
        }
        ax0=siluf(ax0); ax1=siluf(ax1); ax2=siluf(ax2); ax3=siluf(ax3);
        az0=siluf(az0); az1=siluf(az1); az2=siluf(az2); az3=siluf(az3);
        us4v xo; xo[0]=f2bf(ax0); xo[1]=f2bf(ax1); xo[2]=f2bf(ax2); xo[3]=f2bf(ax3);
        *(us4v*)&xsb[(row0+r)*C_ + c] = xo;
        us4v zo; zo[0]=f2bf(az0); zo[1]=f2bf(az1); zo[2]=f2bf(az2); zo[3]=f2bf(az3);
        *(us4v*)&zb[(row0+r)*C_ + c] = zo;
        int sw = (r&7)<<3;
        *(us4v*)&A[r*128 + (c ^ sw)] = xo;
    }
    __syncthreads();
    // phase 2: x_proj via MFMA (waves 0..3)
    int w=t>>6, l=t&63, lr=l&15, lh=l>>4;
    if (w < 4){
        int arow = w*16+lr, asw=(arow&7)<<3;
        bf16x8 af[3];
        #pragma unroll
        for (int kf=0;kf<3;kf++)
            af[kf] = *(const bf16x8*)&A[arow*128 + ((kf*32 + lh*8) ^ asw)];
        #pragma unroll
        for (int nt=0; nt<3; nt++){
            f32x4 acc={0.f,0.f,0.f,0.f};
            #pragma unroll
            for (int kf=0;kf<3;kf++){
                bf16x8 bfr=*(const bf16x8*)(wbf + ((size_t)((WOFF8 + kf*3 + nt)*64 + l))*8);
                acc = MFMA16(af[kf], bfr, acc);
            }
            int col = nt*16 + lr;
            #pragma unroll
            for (int j=0;j<4;j++){
                int row = w*16 + lh*4 + j;
                if (col < 6) XD[row][col] = acc[j];
                else if (col < NPROJ_){
                    BC[(row0+row)*32 + (col-6)] = acc[j];
                    sbc[row][col-6] = acc[j];
                }
            }
        }
    }
    __syncthreads();
    // phase 3: dt_proj (K=6) + softplus -> sdl (fp32 LDS) + dlh (fp16 global)
    if (t < 256){
        int r = t>>2, q = t&3;
        float xd0=XD[r][0], xd1=XD[r][1], xd2=XD[r][2];
        float xd3=XD[r][3], xd4=XD[r][4], xd5=XD[r][5];
        #pragma unroll
        for (int g=0; g<6; g++){
            int c = q*24 + g*4;
            float4 acc = *(const float4*)&dtb[c];
            float4 w0 = *(const float4*)&dtws[0][c];
            float4 w1 = *(const float4*)&dtws[1][c];
            float4 w2 = *(const float4*)&dtws[2][c];
            float4 w3 = *(const float4*)&dtws[3][c];
            float4 w4 = *(const float4*)&dtws[4][c];
            float4 w5 = *(const float4*)&dtws[5][c];
            acc.x += xd0*w0.x + xd1*w1.x + xd2*w2.x + xd3*w3.x + xd4*w4.x + xd5*w5.x;
            acc.y += xd0*w0.y + xd1*w1.y + xd2*w2.y + xd3*w3.y + xd4*w4.y + xd5*w5.y;
            acc.z += xd0*w0.z + xd1*w1.z + xd2*w2.z + xd3*w3.z + xd4*w4.z + xd5*w5.z;
            acc.w += xd0*w0.w + xd1*w1.w + xd2*w2.w + xd3*w3.w + xd4*w4.w + xd5*w5.w;
            float4 dl;
            dl.x = (acc.x>20.f)? acc.x : __logf(1.f+__expf(acc.x));
            dl.y = (acc.y>20.f)? acc.y : __logf(1.f+__expf(acc.y));
            dl.z = (acc.z>20.f)? acc.z : __logf(1.f+__expf(acc.z));
            dl.w = (acc.w>20.f)? acc.w : __logf(1.f+__expf(acc.w));
            sdl[r][c]=dl.x; sdl[r][c+1]=dl.y; sdl[r][c+2]=dl.z; sdl[r][c+3]=dl.w;
            us4v dh; dh[0]=f2h(dl.x); dh[1]=f2h(dl.y); dh[2]=f2h(dl.z); dh[3]=f2h(dl.w);
            *(us4v*)&dlh[(row0+r)*C_ + c] = dh;
        }
    }
    __syncthreads();
    // phase 4: chunk-local scan aggregates (2 chunks of 32 rows), thread=(c, n-quad)
    {
        int c = t>>2, nq = t&3;
        float4 a4 = *(const float4*)&A_log[c*16 + nq*4];
        float a0=-__expf(a4.x), a1=-__expf(a4.y), a2=-__expf(a4.z), a3=-__expf(a4.w);
        int chbase = b*NCH_ + (l0>>5);
        int csw_c = c;  // column in A-tile
        #pragma unroll
        for (int chunk=0; chunk<2; chunk++){
            float ap0=1.f,ap1=1.f,ap2=1.f,ap3=1.f;
            float be0=0.f,be1=0.f,be2=0.f,be3=0.f;
            for (int i=0;i<CHL_;i++){
                int row = chunk*CHL_ + i;
                float dl = sdl[row][c];
                float u = bf2f(A[row*128 + (csw_c ^ ((row&7)<<3))]);
                float du = dl*u;
                float4 bc = *(const float4*)&sbc[row][nq*4];
                float e0=__expf(dl*a0), e1=__expf(dl*a1), e2=__expf(dl*a2), e3=__expf(dl*a3);
                ap0*=e0; be0=be0*e0+du*bc.x;
                ap1*=e1; be1=be1*e1+du*bc.y;
                ap2*=e2; be2=be2*e2+du*bc.z;
                ap3*=e3; be3=be3*e3+du*bc.w;
            }
            size_t o = (size_t)(chbase+chunk)*1536 + c*16 + nq*4;
            float4 apv={ap0,ap1,ap2,ap3}, bev={be0,be1,be2,be3};
            *(float4*)&Ap[o] = apv;
            *(float4*)&Be[o] = bev;
        }
    }
}

// ---------------- K4: qk MFMA + elu+1 + rope-k + MFMA kv reduce + kmean ----------------
__global__ __launch_bounds__(256) void k_qk_kv(const unsigned short* __restrict__ lin,
    const unsigned short* __restrict__ wbf, const float* __restrict__ qkb,
    const float2* __restrict__ ctab, unsigned short* __restrict__ qo,
    float* __restrict__ kvacc)
{
    __shared__ unsigned short A[64*128];
    __shared__ float KR[64*105];
    __shared__ float kmsum[96];
    int t = threadIdx.x;
    size_t row0 = (size_t)blockIdx.x * 64;
    int b = (int)(row0 >> 14);
    int l0 = (int)(row0 & 16383);
    for (int p = t; p < 64*12; p += 256){
        int r = p/12, c = (p - r*12)*8;
        int sw = (r&7)<<3;
        *(uint4*)&A[r*128 + (c ^ sw)] = *(const uint4*)&lin[(row0+r)*C_ + c];
    }
    if (t < 96) kmsum[t] = 0.f;
    __syncthreads();
    int w=t>>6, l=t&63, lr=l&15, lh=l>>4;
    int arow = w*16+lr; int asw=(arow&7)<<3;
    bf16x8 af[3];
    #pragma unroll
    for (int kf=0;kf<3;kf++)
        af[kf] = *(const bf16x8*)&A[arow*128 + ((kf*32 + lh*8) ^ asw)];
    #pragma unroll 2
    for (int nt=0; nt<12; nt++){
        f32x4 acc={0.f,0.f,0.f,0.f};
        #pragma unroll
        for (int kf=0;kf<3;kf++){
            bf16x8 bfr=*(const bf16x8*)(wbf + ((size_t)((WOFF2 + kf*12 + nt)*64 + l))*8);
            acc = MFMA16(af[kf], bfr, acc);
        }
        int colg = nt*16 + lr;
        float bias = qkb[colg];
        float vv[4];
        #pragma unroll
        for (int j=0;j<4;j++){
            float v = acc[j] + bias;
            vv[j] = (v>0.f)? v+1.f : __expf(v);
        }
        if (nt < 6){
            unsigned short* dp = qo + (row0 + w*16 + lh*4)*C_ + colg;
            #pragma unroll
            for (int j=0;j<4;j++) dp[(size_t)j*C_] = f2bf(vv[j]);
        } else {
            int ck = colg - 96;
            atomicAdd(&kmsum[ck], vv[0]+vv[1]+vv[2]+vv[3]);
            float pv[4];
            #pragma unroll
            for (int j=0;j<4;j++) pv[j] = __shfl_xor(vv[j], 1);
            int p = ck >> 1;
            #pragma unroll
            for (int j=0;j<4;j++){
                int rl = l0 + w*16 + lh*4 + j;
                int hp = rl>>7, wp = rl&127;
                float2 cssn = (p<24)? ctab[hp*24+p] : ctab[wp*24+(p-24)];
                float kr = (ck&1)? (pv[j]*cssn.y + vv[j]*cssn.x)
                                 : (vv[j]*cssn.x - pv[j]*cssn.y);
                KR[(w*16+lh*4+j)*105 + ck] = kr;
            }
        }
    }
    __syncthreads();
    // phase 2: kv[h] = KR^T (16x64) @ V (64x16) via MFMA, all 4 waves
    for (int h = w; h < 6; h += 4){
        f32x4 acc = {0.f,0.f,0.f,0.f};
        #pragma unroll
        for (int kk=0; kk<2; kk++){
            union { bf16x8 v; unsigned short u[8]; } afu, bfu;
            #pragma unroll
            for (int j=0;j<8;j++){
                int rr = kk*32 + lh*8 + j;
                afu.u[j] = f2bf(KR[rr*105 + h*16 + lr]);
                bfu.u[j] = A[rr*128 + ((h*16+lr) ^ ((rr&7)<<3))];
            }
            acc = MFMA16(afu.v, bfu.v, acc);
        }
        #pragma unroll
        for (int i=0;i<4;i++)
            atomicAdd(&kvacc[b*1536 + h*256 + (lh*4+i)*16 + lr], acc[i]);
    }
    if (t < 96) atomicAdd(&kvacc[3072 + b*96 + t], kmsum[t]);
}

// ---------------- K5: attention output -> az = (attn+lepe)*z, bf16 ----------------
__global__ __launch_bounds__(384) void k_attnout(const unsigned short* __restrict__ qb,
    const unsigned short* __restrict__ vb, const unsigned short* __restrict__ zb,
    const float* __restrict__ kvacc, const float2* __restrict__ ctab,
    const float* __restrict__ lw9, const float* __restrict__ lb,
    unsigned short* __restrict__ azb)
{
    __shared__ float kvs[1536];
    __shared__ float kms[96];
    int t = threadIdx.x;
    size_t row0 = (size_t)blockIdx.x * 16;
    int b = (int)(row0 >> 14);
    const float invL = 1.f/16384.f;
    for (int i=t; i<1536; i+=384) kvs[i] = kvacc[b*1536+i]*invL;
    if (t < 96) kms[t] = kvacc[3072+b*96+t]*invL;
    __syncthreads();
    int r = t/24, c4 = t%24;
    int c = c4*4;
    int lrow = (int)(row0 & 16383) + r;
    int hp = lrow>>7, wp = lrow&127;
    size_t row = row0 + r;
    us4v qu = *(const us4v*)&qb[row*C_ + c];
    float q0=bf2f(qu[0]), q1=bf2f(qu[1]), q2=bf2f(qu[2]), q3=bf2f(qu[3]);
    int p0 = c>>1, p1 = p0+1;
    float2 cs0 = (p0<24)? ctab[hp*24+p0] : ctab[wp*24+(p0-24)];
    float2 cs1 = (p1<24)? ctab[hp*24+p1] : ctab[wp*24+(p1-24)];
    float4 qr;
    qr.x = q0*cs0.x - q1*cs0.y;
    qr.y = q0*cs0.y + q1*cs0.x;
    qr.z = q2*cs1.x - q3*cs1.y;
    qr.w = q2*cs1.y + q3*cs1.x;
    int h = c4>>2, j = c4&3;
    int dbase = j*4;
    float zp = q0*kms[h*16+dbase]   + q1*kms[h*16+dbase+1]
             + q2*kms[h*16+dbase+2] + q3*kms[h*16+dbase+3];
    zp += __shfl_xor(zp,1);
    zp += __shfl_xor(zp,2);
    float zd = 1.f/(zp + 1e-6f);
    float4 o = {0.f,0.f,0.f,0.f};
    #pragma unroll
    for (int g=0; g<4; g++){
        float4 qg;
        if (g==0) qg = qr;
        else {
            qg.x=__shfl_xor(qr.x,g); qg.y=__shfl_xor(qr.y,g);
            qg.z=__shfl_xor(qr.z,g); qg.w=__shfl_xor(qr.w,g);
        }
        int db = ((j^g)<<2);
        const float* kp = &kvs[h*256 + db*16 + j*4];
        #pragma unroll
        for (int i=0;i<4;i++){
            float qi = (i==0)?qg.x:(i==1)?qg.y:(i==2)?qg.z:qg.w;
            float4 kv4 = *(const float4*)&kp[i*16];
            o.x += qi*kv4.x; o.y += qi*kv4.y;
            o.z += qi*kv4.z; o.w += qi*kv4.w;
        }
    }
    float4 acc = *(const float4*)&lb[c];
    #pragma unroll
    for (int kh=0; kh<3; kh++){
        int hh = hp + kh - 1;
        if ((unsigned)hh < 128u){
            int base_row = (b<<14) + (hh<<7);
            #pragma unroll
            for (int kw=0; kw<3; kw++){
                int wq = wp + kw - 1;
                if ((unsigned)wq < 128u){
                    us4v v = *(const us4v*)&vb[(size_t)(base_row + wq)*C_ + c];
                    float4 wt = *(const float4*)&lw9[(kh*3+kw)*96 + c];
                    acc.x += bf2f(v[0])*wt.x; acc.y += bf2f(v[1])*wt.y;
                    acc.z += bf2f(v[2])*wt.z; acc.w += bf2f(v[3])*wt.w;
                }
            }
        }
    }
    us4v zu = *(const us4v*)&zb[row*C_ + c];
    us4v res;
    res[0] = f2bf((o.x*zd + acc.x)*bf2f(zu[0]));
    res[1] = f2bf((o.y*zd + acc.y)*bf2f(zu[1]));
    res[2] = f2bf((o.z*zd + acc.z)*bf2f(zu[2]));
    res[3] = f2bf((o.w*zd + acc.w)*bf2f(zu[3]));
    *(us4v*)&azb[row*C_ + c] = res;
}

// ---------------- K6b: group aggregates (16 chunks/group) ----------------
__global__ __launch_bounds__(384) void k_scan2a(const float* __restrict__ Ap,
    const float* __restrict__ Be, float* __restrict__ GA, float* __restrict__ GB)
{
    int t = threadIdx.x; int blk = blockIdx.x;  // B*NG
    int b = blk>>5, g = blk&(NG_-1);
    int idx = (t>>2)*16 + (t&3)*4;
    float4 A = {1.f,1.f,1.f,1.f}, Bv = {0.f,0.f,0.f,0.f};
    for (int j=0;j<16;j++){
        size_t o = ((size_t)(b*NCH_ + g*16 + j))*1536 + idx;
        float4 a = *(const float4*)&Ap[o];
        float4 bb = *(const float4*)&Be[o];
        Bv.x=a.x*Bv.x+bb.x; Bv.y=a.y*Bv.y+bb.y; Bv.z=a.z*Bv.z+bb.z; Bv.w=a.w*Bv.w+bb.w;
        A.x*=a.x; A.y*=a.y; A.z*=a.z; A.w*=a.w;
    }
    size_t o = (size_t)blk*1536 + idx;
    *(float4*)&GA[o] = A;
    *(float4*)&GB[o] = Bv;
}

// ---------------- K6c: sequential over NG groups ----------------
__global__ __launch_bounds__(256) void k_scan2b(const float* __restrict__ GA,
    const float* __restrict__ GB, float* __restrict__ Gin)
{
    int t = blockIdx.x*256 + threadIdx.x;  // 3072
    int b = t/1536, m = t%1536;
    float h = 0.f;
    for (int g=0; g<NG_; g++){
        size_t o = ((size_t)(b*NG_+g))*1536 + m;
        Gin[o] = h;
        h = GA[o]*h + GB[o];
    }
}

// ---------------- K6d: within-group chunk-incoming states ----------------
__global__ __launch_bounds__(384) void k_scan2c(const float* __restrict__ Ap,
    const float* __restrict__ Be, const float* __restrict__ Gin,
    float* __restrict__ Hin)
{
    int t = threadIdx.x; int blk = blockIdx.x;  // B*NG
    int b = blk>>5, g = blk&(NG_-1);
    int idx = (t>>2)*16 + (t&3)*4;
    float4 h = *(const float4*)&Gin[(size_t)blk*1536 + idx];
    for (int j=0;j<16;j++){
        size_t o = ((size_t)(b*NCH_ + g*16 + j))*1536 + idx;
        *(float4*)&Hin[o] = h;
        float4 a = *(const float4*)&Ap[o];
        float4 bb = *(const float4*)&Be[o];
        h.x=a.x*h.x+bb.x; h.y=a.y*h.y+bb.y; h.z=a.z*h.z+bb.z; h.w=a.w*h.w+bb.w;
    }
}

// ---------------- K6e: scan pass3 — replay + emit y (bf16; fp16 delta, bf16 u) ----------------
__global__ __launch_bounds__(384) void k_scan3(const unsigned short* __restrict__ dlh,
    const unsigned short* __restrict__ xsb, const float* __restrict__ BC,
    const float* __restrict__ A_log, const float* __restrict__ Dv,
    const float* __restrict__ Hin, unsigned short* __restrict__ y)
{
    int t = threadIdx.x; int nq = t&3, c = t>>2;
    int blk = blockIdx.x; int b = blk>>9, ch = blk&(NCH_-1);
    float4 a4 = *(const float4*)&A_log[c*16 + nq*4];
    float a0=-__expf(a4.x), a1=-__expf(a4.y), a2=-__expf(a4.z), a3=-__expf(a4.w);
    float4 h = *(const float4*)&Hin[(size_t)blk*1536 + c*16 + nq*4];
    float Dc = Dv[c];
    size_t base = ((size_t)b<<14) + ch*CHL_;
    for (int i=0;i<CHL_;i++){
        size_t row = base + i;
        float dl = h2f(dlh[row*C_+c]);
        float u  = bf2f(xsb[row*C_+c]);
        float du = dl*u;
        float4 bcB = *(const float4*)&BC[row*32 + nq*4];
        float4 bcC = *(const float4*)&BC[row*32 + 16 + nq*4];
        float e0=__expf(dl*a0), e1=__expf(dl*a1), e2=__expf(dl*a2), e3=__expf(dl*a3);
        h.x=h.x*e0+du*bcB.x; h.y=h.y*e1+du*bcB.y;
        h.z=h.z*e2+du*bcB.z; h.w=h.w*e3+du*bcB.w;
        float yv = h.x*bcC.x + h.y*bcC.y + h.z*bcC.z + h.w*bcC.w;
        yv += __shfl_xor(yv,1);
        yv += __shfl_xor(yv,2);
        if (nq == 0) y[row*C_+c] = f2bf(yv + Dc*u);
    }
}

// ---------------- K7: combine + LN + MLP, fused, global bf16 A-fragments ----------------
__global__ __launch_bounds__(512) void k_combine_mlp(const unsigned short* __restrict__ yb,
    const unsigned short* __restrict__ zb, const unsigned short* __restrict__ azb,
    const unsigned short* __restrict__ wbf, const float* __restrict__ pob,
    const float* __restrict__ outb, const float* __restrict__ hs,
    const float* __restrict__ gg, const float* __restrict__ bb,
    const float* __restrict__ f1b, const float* __restrict__ f2b,
    float* __restrict__ outr)
{
    __shared__ __attribute__((aligned(16))) char POOL[65536];
    __shared__ float LNS[64][2], LNS2[64][2];
    unsigned short* C2 = (unsigned short*)POOL;            // 0..24576 phase A
    unsigned short* AT = (unsigned short*)POOL;            // 0..16384 phase B
    unsigned short* HID= (unsigned short*)(POOL + 16384);  // 16384..65536 phase B
    int t=threadIdx.x;
    size_t row0=(size_t)blockIdx.x*64;
    int w=t>>6, l=t&63, lr=l&15, lh=l>>4;
    int rt=w>>1, hf=w&1;
    int arow=rt*16+lr; int asw=(arow&7)<<3;
    size_t gbase = (row0+arow)*C_;
    bf16x8 af1[6], af2[3];
    #pragma unroll
    for (int kf=0;kf<3;kf++){
        af1[kf]   = *(const bf16x8*)&yb[gbase + kf*32 + lh*8];
        af1[3+kf] = *(const bf16x8*)&zb[gbase + kf*32 + lh*8];
        af2[kf]   = *(const bf16x8*)&azb[gbase + kf*32 + lh*8];
    }
    #pragma unroll
    for (int q=0;q<3;q++){
        int nt = hf*3 + q;
        f32x4 a1={0.f,0.f,0.f,0.f}, a2={0.f,0.f,0.f,0.f};
        #pragma unroll
        for (int kf=0;kf<6;kf++){
            bf16x8 b=*(const bf16x8*)(wbf+((size_t)((WOFF3+kf*6+nt)*64+l))*8);
            a1=MFMA16(af1[kf],b,a1);
        }
        #pragma unroll
        for (int kf=0;kf<3;kf++){
            bf16x8 b=*(const bf16x8*)(wbf+((size_t)((WOFF4+kf*6+nt)*64+l))*8);
            a2=MFMA16(af2[kf],b,a2);
        }
        int col=nt*16+lr;
        float pb=pob[col];
        #pragma unroll
        for (int j=0;j<4;j++){
            int row=rt*16+lh*4+j;
            int sw2=(row&7)<<3;
            C2[row*192 + (col^sw2)] = f2bf(a1[j]);
            C2[row*192 + ((96+col)^sw2)] = f2bf(a2[j]+pb);
        }
    }
    __syncthreads();   // b1: C2 complete
    bf16x8 af3[6];
    #pragma unroll
    for (int kf=0;kf<6;kf++) af3[kf]=*(const bf16x8*)&C2[arow*192 + ((kf*32+lh*8)^asw)];
    float outv[3][4];
    #pragma unroll
    for (int q=0;q<3;q++){
        int nt = hf*3 + q;
        f32x4 acc={0.f,0.f,0.f,0.f};
        #pragma unroll
        for (int kf=0;kf<6;kf++){
            bf16x8 b=*(const bf16x8*)(wbf+((size_t)((WOFF5+kf*6+nt)*64+l))*8);
            acc=MFMA16(af3[kf],b,acc);
        }
        int col=nt*16+lr;
        float ob=outb[col];
        #pragma unroll
        for (int j=0;j<4;j++){
            size_t row=row0+rt*16+lh*4+j;
            outv[q][j] = acc[j] + ob + hs[row*C_+col];
        }
    }
    // LN partials
    float s_[4], s2_[4];
    #pragma unroll
    for (int j=0;j<4;j++){
        float s=0.f, s2=0.f;
        #pragma unroll
        for (int q=0;q<3;q++){ float v=outv[q][j]; s+=v; s2+=v*v; }
        s_[j]=s; s2_[j]=s2;
    }
    #pragma unroll
    for (int m=1;m<16;m<<=1){
        #pragma unroll
        for (int j=0;j<4;j++){
            s_[j]  += __shfl_xor(s_[j],  m);
            s2_[j] += __shfl_xor(s2_[j], m);
        }
    }
    if (lr==0){
        #pragma unroll
        for (int j=0;j<4;j++){
            int row = rt*16+lh*4+j;
            LNS[row][hf]  = s_[j];
            LNS2[row][hf] = s2_[j];
        }
    }
    __syncthreads();   // b2: af3 consumed, LNS visible
    #pragma unroll
    for (int j=0;j<4;j++){
        int row = rt*16+lh*4+j;
        float s  = LNS[row][0]  + LNS[row][1];
        float s2 = LNS2[row][0] + LNS2[row][1];
        float mn = s*(1.f/C_);
        float rs = rsqrtf(s2*(1.f/C_) - mn*mn + 1e-5f);
        int sw2 = (row&7)<<3;
        #pragma unroll
        for (int q=0;q<3;q++){
            int col = (hf*3+q)*16+lr;
            AT[row*128 + (col^sw2)] = f2bf((outv[q][j]-mn)*rs*gg[col]+bb[col]);
        }
    }
    __syncthreads();   // b3: AT complete
    {
        bf16x8 af[3];
        #pragma unroll
        for(int kf=0;kf<3;kf++) af[kf]=*(const bf16x8*)&AT[arow*128+((kf*32+lh*8)^asw)];
        #pragma unroll 2
        for(int q=0;q<12;q++){
            int nt = hf*12 + q;
            f32x4 acc={0.f,0.f,0.f,0.f};
            #pragma unroll
            for(int kf=0;kf<3;kf++){
                bf16x8 b=*(const bf16x8*)(wbf+((size_t)((WOFF6+kf*24+nt)*64+l))*8);
                acc=MFMA16(af[kf],b,acc);
            }
            int col=nt*16+lr;
            float bias=f1b[col];
            #pragma unroll
            for(int j=0;j<4;j++){
                int row=rt*16+lh*4+j;
                HID[row*384 + (col^((row&7)<<3))] = f2bf(gelu_fast(acc[j]+bias));
            }
        }
    }
    __syncthreads();   // b4: HID complete
    {
        bf16x8 afh[12];
        #pragma unroll
        for(int kf=0;kf<12;kf++) afh[kf]=*(const bf16x8*)&HID[arow*384+((kf*32+lh*8)^asw)];
        #pragma unroll
        for(int q=0;q<3;q++){
            int nt = hf*3 + q;
            f32x4 acc={0.f,0.f,0.f,0.f};
            #pragma unroll
            for(int kf=0;kf<12;kf++){
                bf16x8 b=*(const bf16x8*)(wbf+((size_t)((WOFF7+kf*6+nt)*64+l))*8);
                acc=MFMA16(afh[kf],b,acc);
            }
            int col=nt*16+lr;
            float bias=f2b[col];
            #pragma unroll
            for(int j=0;j<4;j++){
                size_t row=row0+rt*16+lh*4+j;
                outr[row*C_+col] = outv[q][j] + acc[j] + bias;
            }
        }
    }
}

extern "C" void kernel_launch(void* const* d_in, const int* in_sizes, int n_in,
                              void* d_out, int out_size, void* d_ws, size_t ws_size,
                              hipStream_t stream)
{
    const float* hs        = (const float*)d_in[0];
    const float* norm_in_g = (const float*)d_in[1];
    const float* norm_in_b = (const float*)d_in[2];
    const float* in_proj_w = (const float*)d_in[3];
    const float* dw_w      = (const float*)d_in[4];
    const float* dw_b      = (const float*)d_in[5];
    const float* qk_w      = (const float*)d_in[6];
    const float* qk_b      = (const float*)d_in[7];
    const float* lepe_w    = (const float*)d_in[8];
    const float* lepe_b    = (const float*)d_in[9];
    const float* conv_x_w  = (const float*)d_in[10];
    const float* conv_z_w  = (const float*)d_in[11];
    const float* x_proj_w  = (const float*)d_in[12];
    const float* dt_proj_w = (const float*)d_in[13];
    const float* dt_proj_b = (const float*)d_in[14];
    const float* A_log     = (const float*)d_in[15];
    const float* Dv        = (const float*)d_in[16];
    const float* out_proj_w= (const float*)d_in[17];
    const float* proj_out_w= (const float*)d_in[18];
    const float* proj_out_b= (const float*)d_in[19];
    const float* out_w     = (const float*)d_in[20];
    const float* out_b     = (const float*)d_in[21];
    const float* norm_mlp_g= (const float*)d_in[22];
    const float* norm_mlp_b= (const float*)d_in[23];
    const float* fc1_w     = (const float*)d_in[24];
    const float* fc1_b     = (const float*)d_in[25];
    const float* fc2_w     = (const float*)d_in[26];
    const float* fc2_b     = (const float*)d_in[27];

    float* ws = (float*)d_ws;
    size_t o = 0;
    const size_t USH = (size_t)BL_*C_/2;   // one bf16/fp16 buffer in float units
    unsigned short* xxb  = (unsigned short*)(ws + o); o += USH;  // -> qb after conv1d
    unsigned short* zzb  = (unsigned short*)(ws + o); o += USH;  // -> yb after conv1d
    unsigned short* wwb  = (unsigned short*)(ws + o); o += USH;  // -> azb after dwconv
    unsigned short* linb = (unsigned short*)(ws + o); o += USH;
    unsigned short* zbuf = (unsigned short*)(ws + o); o += USH;
    unsigned short* xsb  = (unsigned short*)(ws + o); o += USH;
    unsigned short* dlh  = (unsigned short*)(ws + o); o += USH;
    float* BC    = ws + o; o += (size_t)BL_*32;
    float* Ap    = ws + o; o += (size_t)B_*NCH_*1536;
    float* Be    = ws + o; o += (size_t)B_*NCH_*1536;
    float* Hin   = ws + o; o += (size_t)B_*NCH_*1536;
    float* GA    = ws + o; o += (size_t)B_*NG_*1536;
    float* GB    = ws + o; o += (size_t)B_*NG_*1536;
    float* Gin   = ws + o; o += (size_t)B_*NG_*1536;
    float* kvacc = ws + o; o += 3264;
    float2* ctab = (float2*)(ws + o); o += 6144;
    float* wt9   = ws + o; o += 864;
    float* lw9   = ws + o; o += 864;
    float* wxT   = ws + o; o += 384;
    float* wzT   = ws + o; o += 384;
    unsigned short* wbf = (unsigned short*)(ws + o);

    unsigned short* qb  = xxb;   // conv1d consumed xxb before qk_kv writes qb
    unsigned short* yb  = zzb;   // conv1d consumed zzb before scan3 writes yb
    unsigned short* azb = wwb;   // dwconv consumed wwb before attnout writes azb
    float* outr = (float*)d_out;

    k_setup<<<dim3(72,8), 64, 0, stream>>>(in_proj_w, qk_w, out_proj_w, proj_out_w,
                                           out_w, fc1_w, fc2_w, dw_w, lepe_w,
                                           x_proj_w, conv_x_w, conv_z_w,
                                           wbf, ctab, wt9, lw9, kvacc, wxT, wzT);
    k_ln_inproj_m<<<BL_/64, 256, 0, stream>>>(hs, norm_in_g, norm_in_b, wbf,
                                              xxb, zzb, wwb);
    k_dwconv2d<<<(BL_*24)/256, 256, 0, stream>>>(wwb, wt9, dw_b, linb);
    k_conv1d_xdbl<<<BL_/64, 384, 0, stream>>>(xxb, zzb, wxT, wzT, wbf,
                                              dt_proj_w, dt_proj_b, A_log,
                                              xsb, zbuf, dlh, BC, Ap, Be);
    k_qk_kv<<<BL_/64, 256, 0, stream>>>(linb, wbf, qk_b, ctab, qb, kvacc);
    k_attnout<<<BL_/16, 384, 0, stream>>>(qb, linb, zbuf, kvacc, ctab, lw9, lepe_b, azb);
    k_scan2a<<<B_*NG_, 384, 0, stream>>>(Ap, Be, GA, GB);
    k_scan2b<<<12, 256, 0, stream>>>(GA, GB, Gin);
    k_scan2c<<<B_*NG_, 384, 0, stream>>>(Ap, Be, Gin, Hin);
    k_scan3<<<B_*NCH_, 384, 0, stream>>>(dlh, xsb, BC, A_log, Dv, Hin, yb);
    k_combine_mlp<<<BL_/64, 512, 0, stream>>>(yb, zbuf, azb, wbf, proj_out_b,
                                              out_b, hs, norm_mlp_g, norm_mlp_b,
                                              fc1_b, fc2_b, outr);
}